// Round 4
// baseline (345.929 us; speedup 1.0000x reference)
//
#include <hip/hip_runtime.h>

// MaskAttention: B=2,S=3144,C=256,H=8,HD=32, mask-softmax attention with vh=kh,
// LePE 5x5 depthwise conv on v[:,8:], output projection.
// I/O: ALL float32. Internal: bf16 MFMA, f32 accum.
//
// softmax(qk + log(m+eps)) == normalize((m+eps)*exp(qk)); |qk| is tiny, so fixed
// shift M=0 -> no online max; k-range partials additive => split-K.
//
// R4 changes vs R3 (k_flash 139us, latency-stalled: VALUBusy 31%, duty ~13%):
//  - k/v register prefetch ACROSS the counted fence: tile t+1's 12 k/v loads
//    and 4 mask global_load_lds all issue BEFORE s_waitcnt vmcnt(16); the 16
//    newest ops stay in flight through tile t's compute. Compute has zero
//    exposed VMEM latency. This is R2's pipeline minus its poison pills:
//    no inline-asm ds_read (mask read stays compiler-visible), no
//    __launch_bounds__ min-waves, raw arrays not structs (R3-proven codegen).
//  - everything else byte-identical to R3.

#define S_LEN 3144
#define SP    3200            // S padded to 64 (50 k-tiles; 0..48 fully valid)
#define HEADS 8
#define HD    32
#define BATCH 2
#define MROWS (BATCH*S_LEN)   // 6288
#define NPIX  3136            // 56*56
#define SCALE_F 0.17677669529663687f   // 32^-0.5
#define KQ_SC   0.25504472665352026f   // SCALE_F * log2(e)

typedef __bf16 bf16x8  __attribute__((ext_vector_type(8)));
typedef __bf16 bf16x4  __attribute__((ext_vector_type(4)));
typedef float  floatx4 __attribute__((ext_vector_type(4)));
typedef short  shortx4 __attribute__((ext_vector_type(4)));

static __device__ __forceinline__ float bf2f(unsigned int h) {
  union { unsigned int u; float f; } v; v.u = h << 16; return v.f;
}
static __device__ __forceinline__ unsigned short f2bf(float f) {
  union { __bf16 b; unsigned short u; } v; v.b = (__bf16)f; return v.u;
}
static __device__ __forceinline__ bf16x8 ldcvt8(const float* __restrict__ p) {
  float4 a = *(const float4*)p;
  float4 b = *(const float4*)(p + 4);
  bf16x8 r;
  r[0]=(__bf16)a.x; r[1]=(__bf16)a.y; r[2]=(__bf16)a.z; r[3]=(__bf16)a.w;
  r[4]=(__bf16)b.x; r[5]=(__bf16)b.y; r[6]=(__bf16)b.z; r[7]=(__bf16)b.w;
  return r;
}

#define GLOBAL_AS __attribute__((address_space(1)))
#define LDS_AS    __attribute__((address_space(3)))
static __device__ __forceinline__ void gload_lds16(const void* g, void* l) {
  __builtin_amdgcn_global_load_lds((const GLOBAL_AS void*)g, (LDS_AS void*)l, 16, 0, 0);
}

#define FENCE16() asm volatile("s_waitcnt vmcnt(16)" ::: "memory")
#define FENCE0()  asm volatile("s_waitcnt vmcnt(0)" ::: "memory")

// ---------------- K0: one-time f32 -> bf16 conversion (x, wq, wk, wv) ----------------
__global__ __launch_bounds__(256) void k_cvt(
    const float* __restrict__ x, const float* __restrict__ wq,
    const float* __restrict__ wk, const float* __restrict__ wv,
    unsigned short* __restrict__ xb, unsigned short* __restrict__ w3b)
{
  const int i = blockIdx.x * 256 + threadIdx.x;   // unit of 8 floats
  const int NX = MROWS * 32;                      // 201216
  const int NW = 8192;                            // 65536/8
  const float* src;
  unsigned short* dst;
  if (i < NX) { src = x + (size_t)i * 8; dst = xb + (size_t)i * 8; }
  else {
    const int j = i - NX;
    if (j >= 3 * NW) return;
    src = (j < NW) ? wq + (size_t)j * 8
        : (j < 2 * NW) ? wk + (size_t)(j - NW) * 8
                       : wv + (size_t)(j - 2 * NW) * 8;
    dst = w3b + (size_t)j * 8;
  }
  bf16x8 v = ldcvt8(src);
  *(bf16x8*)dst = v;
}

// ---------------- K1: fused q/k/v projection (bf16 in -> bf16 out) ----------------
// Grid (100, 12): blockIdx.x = bsel*50 + stile. Pad rows (s>=S_LEN) store 0.
__global__ __launch_bounds__(256) void k_qkv(
    const unsigned short* __restrict__ xb, const unsigned short* __restrict__ w3b,
    const float* __restrict__ bqp, const float* __restrict__ bkp,
    const float* __restrict__ bvp,
    unsigned short* __restrict__ qws, unsigned short* __restrict__ kws,
    unsigned short* __restrict__ vfrag, unsigned short* __restrict__ vstage)
{
  __shared__ unsigned short lds_t[64 * 65];   // transpose staging (k blocks only)
  const int lane = threadIdx.x & 63;
  const int wid  = threadIdx.x >> 6;
  const int c    = lane & 15, quad = lane >> 4;
  const int bsel  = blockIdx.x / 50;
  const int stile = blockIdx.x % 50;
  const int srow0 = stile * 64;
  const int ncol = blockIdx.y * 64;           // 0..767
  const int wsel = ncol >> 8;
  const int col0 = ncol & 255;

  const float* bptr = (wsel == 0) ? bqp : (wsel == 1) ? bkp : bvp;

  const int srow = srow0 + wid * 16 + c;
  const int arow = bsel * S_LEN + ((srow < S_LEN) ? srow : 0);  // clamp pad rows
  const unsigned short* ap = xb  + (size_t)arow * 256 + quad * 8;
  const unsigned short* bp = w3b + (size_t)(ncol + c) * 256 + quad * 8;

  floatx4 acc[4];
#pragma unroll
  for (int ct = 0; ct < 4; ++ct) acc[ct] = (floatx4){0.f, 0.f, 0.f, 0.f};

#pragma unroll
  for (int ks = 0; ks < 8; ++ks) {
    bf16x8 af = *(const bf16x8*)(ap + ks * 32);
#pragma unroll
    for (int ct = 0; ct < 4; ++ct) {
      bf16x8 bf = *(const bf16x8*)(bp + (size_t)ct * 16 * 256 + ks * 32);
      acc[ct] = __builtin_amdgcn_mfma_f32_16x16x32_bf16(af, bf, acc[ct], 0, 0, 0);
    }
  }

#pragma unroll
  for (int ct = 0; ct < 4; ++ct) {
    const int col = col0 + ct * 16 + c;
    const float bias = bptr[col];
#pragma unroll
    for (int r = 0; r < 4; ++r) {
      const int s = srow0 + wid * 16 + quad * 4 + r;   // 0..3199 within batch
      const int valid = (s < S_LEN);
      const float v = acc[ct][r] + bias;
      if (wsel == 0) {
        qws[(((size_t)(bsel * HEADS + (col >> 5))) * SP + s) * HD + (col & 31)] =
            valid ? f2bf(v) : (unsigned short)0;
      } else if (wsel == 1) {
        // QK-side copy carries log2e; V-side copy (lds_t->vfrag) does NOT.
        kws[(((size_t)(bsel * HEADS + (col >> 5))) * SP + s) * HD + (col & 31)] =
            valid ? f2bf(v * KQ_SC) : (unsigned short)0;
        lds_t[(ct * 16 + c) * 65 + (wid * 16 + quad * 4 + r)] =
            valid ? f2bf(v * SCALE_F) : (unsigned short)0;
      } else {
        if (valid) vstage[(size_t)(bsel * S_LEN + s) * 256 + col] = f2bf(v);
      }
    }
  }

  if (wsel == 1) {
    // vfrag: PV A-operand fragments in exact MFMA lane order.
    __syncthreads();
    const int tid = threadIdx.x;
#pragma unroll
    for (int j = 0; j < 4; ++j) {
      const int grp  = j * 4 + (tid >> 6);   // 0..15, wave-uniform
      const int l    = tid & 63;
      const int ct2  = grp & 3;
      const int half = (grp >> 2) & 1;
      const int hsel = grp >> 3;
      const int cc = l & 15, qq = l >> 4;
      const int cl = hsel * 32 + half * 16 + cc;
      const int rb = ct2 * 16 + qq * 4;
      union { shortx4 s4; unsigned short u[4]; } pk;
#pragma unroll
      for (int e = 0; e < 4; ++e) pk.u[e] = lds_t[cl * 65 + rb + e];
      const int hglob = (col0 >> 5) + hsel;
      const size_t off =
          ((((size_t)(bsel * HEADS + hglob) * 50 + stile) * 4 + ct2) * 2 + half) * 64 + l;
      *(shortx4*)(vfrag + off * 4) = pk.s4;
    }
  }
}

// ---------------- K2: LePE 5x5 depthwise conv on v[:,8:] ----------------
__global__ __launch_bounds__(256) void k_lepe(const unsigned short* __restrict__ vws,
                                              const float* __restrict__ cw,
                                              const float* __restrict__ cb,
                                              unsigned short* __restrict__ lepe)
{
  int idx = blockIdx.x * 256 + threadIdx.x;
  if (idx >= BATCH * NPIX * 32) return;
  const int cg = idx & 31;
  const int p  = (idx >> 5) % NPIX;
  const int b  = idx / (NPIX * 32);
  const int y  = p / 56, xx = p - y * 56;

  float acc[8];
  {
    float4 b0 = *(const float4*)(cb + cg * 8);
    float4 b1 = *(const float4*)(cb + cg * 8 + 4);
    acc[0]=b0.x; acc[1]=b0.y; acc[2]=b0.z; acc[3]=b0.w;
    acc[4]=b1.x; acc[5]=b1.y; acc[6]=b1.z; acc[7]=b1.w;
  }
#pragma unroll
  for (int dy = -2; dy <= 2; ++dy) {
    const int yy = y + dy;
    if ((unsigned)yy >= 56u) continue;
#pragma unroll
    for (int dx = -2; dx <= 2; ++dx) {
      const int xs = xx + dx;
      if ((unsigned)xs >= 56u) continue;
      uint4 vv = *(const uint4*)(vws + (size_t)(b * S_LEN + 8 + yy * 56 + xs) * 256 + cg * 8);
      const float* wp = cw + (size_t)((dy + 2) * 5 + (dx + 2)) * 256 + cg * 8;
      float4 w0 = *(const float4*)wp;
      float4 w1 = *(const float4*)(wp + 4);
      unsigned int va[4] = {vv.x, vv.y, vv.z, vv.w};
      acc[0] += bf2f(va[0] & 0xFFFFu) * w0.x;  acc[1] += bf2f(va[0] >> 16) * w0.y;
      acc[2] += bf2f(va[1] & 0xFFFFu) * w0.z;  acc[3] += bf2f(va[1] >> 16) * w0.w;
      acc[4] += bf2f(va[2] & 0xFFFFu) * w1.x;  acc[5] += bf2f(va[2] >> 16) * w1.y;
      acc[6] += bf2f(va[3] & 0xFFFFu) * w1.z;  acc[7] += bf2f(va[3] >> 16) * w1.w;
    }
  }
  unsigned int o[4];
#pragma unroll
  for (int j = 0; j < 4; ++j)
    o[j] = (unsigned int)f2bf(acc[2*j]) | ((unsigned int)f2bf(acc[2*j+1]) << 16);
  *((uint4*)(lepe + (size_t)(b * NPIX + p) * 256 + cg * 8)) = make_uint4(o[0], o[1], o[2], o[3]);
}

// ---------------- K3: flash attention, split-K (8 waves), reg+LDS double-buffer ----
static __device__ __forceinline__ void kv_load(
    const unsigned short* __restrict__ kb, const unsigned short* __restrict__ vb,
    int t, int c, int quad, int lane,
    bf16x8 (&kf)[4], shortx4 (&v0)[4], shortx4 (&v1)[4])
{
  const int k0 = t * 64;
  const unsigned short* tb = vb + (size_t)t * 2048;
#pragma unroll
  for (int ct = 0; ct < 4; ++ct) {
    kf[ct] = *(const bf16x8*)(kb + (size_t)(k0 + ct * 16 + c) * HD + quad * 8);
    v0[ct] = *(const shortx4*)(tb + (ct * 2 + 0) * 256 + lane * 4);
    v1[ct] = *(const shortx4*)(tb + (ct * 2 + 1) * 256 + lane * 4);
  }
}

template<bool TAIL>
static __device__ __forceinline__ void tile_compute(
    int k0, const bf16x8 (&kf)[4], const shortx4 (&v0)[4], const shortx4 (&v1)[4],
    const float* __restrict__ mb, int c, int quad, const bf16x8 qf,
    floatx4& o0, floatx4& o1, float& l_run)
{
  floatx4 s[4];
#pragma unroll
  for (int ct = 0; ct < 4; ++ct)
    s[ct] = __builtin_amdgcn_mfma_f32_16x16x32_bf16(kf[ct], qf,
               (floatx4){0.f,0.f,0.f,0.f}, 0, 0, 0);
  float ls = 0.f;
  shortx4 pf[4];
#pragma unroll
  for (int ct = 0; ct < 4; ++ct) {
    const float4 mv = *(const float4*)(mb + c * 64 + (((ct * 4 + quad) ^ c) * 4));
    float pr[4];
    pr[0] = (mv.x + 1e-6f) * __builtin_amdgcn_exp2f(s[ct][0]);
    pr[1] = (mv.y + 1e-6f) * __builtin_amdgcn_exp2f(s[ct][1]);
    pr[2] = (mv.z + 1e-6f) * __builtin_amdgcn_exp2f(s[ct][2]);
    pr[3] = (mv.w + 1e-6f) * __builtin_amdgcn_exp2f(s[ct][3]);
    if (TAIL) {
      const int kk = k0 + ct * 16 + quad * 4;
#pragma unroll
      for (int r = 0; r < 4; ++r) if (kk + r >= S_LEN) pr[r] = 0.f;
    }
    ls += (pr[0] + pr[1]) + (pr[2] + pr[3]);
    union { bf16x4 b4; shortx4 s4; } u;
    u.b4[0]=(__bf16)pr[0]; u.b4[1]=(__bf16)pr[1]; u.b4[2]=(__bf16)pr[2]; u.b4[3]=(__bf16)pr[3];
    pf[ct] = u.s4;
  }
  l_run += ls;
#pragma unroll
  for (int ct = 0; ct < 4; ++ct) {
    o0 = __builtin_amdgcn_mfma_f32_16x16x16bf16_1k(v0[ct], pf[ct], o0, 0, 0, 0);
    o1 = __builtin_amdgcn_mfma_f32_16x16x16bf16_1k(v1[ct], pf[ct], o1, 0, 0, 0);
  }
}

static __device__ __forceinline__ void stage_mask(
    const float* const (&msrc)[4], const int (&goff4)[4], int k0, float* dst)
{
#pragma unroll
  for (int i = 0; i < 4; ++i)
    gload_lds16(msrc[i] + (k0 + goff4[i]), dst + i * 256);
}

static __device__ __forceinline__ void stage_mask_tail(
    const float* const (&msrc)[4], const int (&goff4)[4], int k0, float* dst)
{
#pragma unroll
  for (int i = 0; i < 4; ++i) {
    int kk = k0 + goff4[i];
    if (kk > S_LEN - 4) kk = S_LEN - 4;   // stay in-bounds; zeroed in softmax
    gload_lds16(msrc[i] + kk, dst + i * 256);
  }
}

__global__ __launch_bounds__(512) void k_flash(
    const unsigned short* __restrict__ qws,
    const unsigned short* __restrict__ kws,
    const unsigned short* __restrict__ vfrag,
    const float* __restrict__ mask,
    const unsigned short* __restrict__ lepe,
    unsigned short* __restrict__ attn)
{
  // Per-wave 8KB region: 2 x 4KB mask dbuf during the loop; first 576 floats
  // reused as reduction scratch AFTER the wave's loop.
  __shared__ __align__(16) float smem[8][2048];
  const int lane = threadIdx.x & 63;
  const int wid  = threadIdx.x >> 6;          // 0..7
  const int c    = lane & 15, quad = lane >> 4;
  const int u    = blockIdx.x;               // 0..3199
  const int xcd  = u & 7;
  const int slot = u >> 3;                   // 0..399
  const int h    = slot & 7;
  const int p    = (slot >> 3) * 8 + xcd;    // 0..399 = b*200 + strip
  const int b    = p / 200;
  const int strip = p - b * 200;
  const int qrow = strip * 16 + c;
  const size_t bh = (size_t)(b * HEADS + h);

  const bf16x8 qf = *(const bf16x8*)(qws + (bh * SP + qrow) * HD + quad * 8);
  const unsigned short* kb = kws + bh * SP * HD;
  const unsigned short* vb = vfrag + bh * (size_t)(50 * 2048);
  float* mt = &smem[wid][0];

  // Staging source precompute: instr i covers q-rows i*4..i*4+3; lane supplies
  // (row = i*4 + lane>>4, G' = lane&15), source granule G = G' ^ row.
  const float* msrc[4];
  int goff4[4];
#pragma unroll
  for (int i = 0; i < 4; ++i) {
    const int rq = i * 4 + (lane >> 4);
    int mr = strip * 16 + rq; if (mr >= S_LEN) mr = S_LEN - 1;
    msrc[i] = mask + ((size_t)b * S_LEN + mr) * S_LEN;
    goff4[i] = ((lane & 15) ^ rq) * 4;
  }

  float l_run = 0.f;
  floatx4 o0 = (floatx4){0.f,0.f,0.f,0.f};
  floatx4 o1 = (floatx4){0.f,0.f,0.f,0.f};

  // tiles: wave w -> t = w*6 .. w*6+5 (48 tiles); leftovers 48 -> wave0,
  // 49 (tail) -> wave1.
  const int tbase = wid * 6;
  const bool hasExtra = (wid < 2);

  bf16x8 kfA[4], kfB[4];
  shortx4 v0A[4], v1A[4], v0B[4], v1B[4];

  // prologue: tile tbase -> regs A + mask buf0
  stage_mask(msrc, goff4, tbase * 64, mt);
  kv_load(kb, vb, tbase, c, quad, lane, kfA, v0A, v1A);

#pragma unroll 1
  for (int jp = 0; jp < 3; ++jp) {
    const int j0 = 2 * jp;
    // even phase: prefetch tile j0+1 (regs B + mask buf1), fence, compute A(j0)
    stage_mask(msrc, goff4, (tbase + j0 + 1) * 64, mt + 1024);
    kv_load(kb, vb, tbase + j0 + 1, c, quad, lane, kfB, v0B, v1B);
    FENCE16();
    tile_compute<false>(0, kfA, v0A, v1A, mt, c, quad, qf, o0, o1, l_run);
    // odd phase: prefetch tile j0+2 / extra (regs A + mask buf0), compute B(j0+1)
    if (jp < 2) {
      stage_mask(msrc, goff4, (tbase + j0 + 2) * 64, mt);
      kv_load(kb, vb, tbase + j0 + 2, c, quad, lane, kfA, v0A, v1A);
      FENCE16();
    } else if (hasExtra) {
      if (wid == 0) stage_mask(msrc, goff4, 48 * 64, mt);
      else          stage_mask_tail(msrc, goff4, 49 * 64, mt);
      kv_load(kb, vb, 48 + wid, c, quad, lane, kfA, v0A, v1A);
      FENCE16();
    } else {
      FENCE0();
    }
    tile_compute<false>(0, kfB, v0B, v1B, mt + 1024, c, quad, qf, o0, o1, l_run);
  }
  if (hasExtra) {
    FENCE0();
    if (wid == 0)
      tile_compute<false>(48 * 64, kfA, v0A, v1A, mt, c, quad, qf, o0, o1, l_run);
    else
      tile_compute<true >(49 * 64, kfA, v0A, v1A, mt, c, quad, qf, o0, o1, l_run);
  }

  // ---- cross-wave reduction (smem reused: each wave writes only its region) ----
#pragma unroll
  for (int r = 0; r < 4; ++r) {
    smem[wid][lane * 9 + r]     = o0[r];
    smem[wid][lane * 9 + 4 + r] = o1[r];
  }
  smem[wid][lane * 9 + 8] = l_run;
  __syncthreads();

  if (wid == 0) {
#pragma unroll
    for (int w = 1; w < 8; ++w) {
#pragma unroll
      for (int r = 0; r < 4; ++r) {
        o0[r] += smem[w][lane * 9 + r];
        o1[r] += smem[w][lane * 9 + 4 + r];
      }
      l_run += smem[w][lane * 9 + 8];
    }
    l_run += __shfl_xor(l_run, 16);
    l_run += __shfl_xor(l_run, 32);
    const float rl = 1.f / l_run;

    if (qrow < S_LEN) {
      const size_t obase = ((size_t)b * S_LEN + qrow) * 256 + h * 32;
      const size_t lbase = (qrow >= 8) ? (((size_t)b * NPIX + (qrow - 8)) * 256 + h * 32) : 0;
#pragma unroll
      for (int mt2 = 0; mt2 < 2; ++mt2) {
        floatx4 ov = mt2 ? o1 : o0;
#pragma unroll
        for (int r = 0; r < 4; ++r) {
          const int d = mt2 * 16 + quad * 4 + r;
          float val = ov[r] * rl;
          if (qrow >= 8) val += bf2f(lepe[lbase + d]);
          attn[obase + d] = f2bf(val);
        }
      }
    }
  }
}

// ---------------- K4: output projection (attn bf16, wo/bo f32 -> f32 out) ----------------
__global__ __launch_bounds__(256) void k_oproj(
    const unsigned short* __restrict__ attn,
    const float* __restrict__ wop,
    const float* __restrict__ bop,
    float* __restrict__ out)
{
  const int lane = threadIdx.x & 63;
  const int wid  = threadIdx.x >> 6;
  const int c = lane & 15, quad = lane >> 4;
  const int row0 = blockIdx.x * 64 + wid * 16;
  const int col0 = blockIdx.y * 64;

  int arow = row0 + c; if (arow >= MROWS) arow = 0;
  const unsigned short* ap = attn + (size_t)arow * 256 + quad * 8;
  const float* bp = wop + (size_t)(col0 + c) * 256 + quad * 8;

  floatx4 acc[4];
#pragma unroll
  for (int ct = 0; ct < 4; ++ct) acc[ct] = (floatx4){0.f,0.f,0.f,0.f};
#pragma unroll
  for (int ks = 0; ks < 8; ++ks) {
    bf16x8 af = *(const bf16x8*)(ap + ks * 32);
#pragma unroll
    for (int ct = 0; ct < 4; ++ct) {
      bf16x8 bf = ldcvt8(bp + (size_t)ct * 16 * 256 + ks * 32);
      acc[ct] = __builtin_amdgcn_mfma_f32_16x16x32_bf16(af, bf, acc[ct], 0, 0, 0);
    }
  }
#pragma unroll
  for (int ct = 0; ct < 4; ++ct) {
    const int col = col0 + ct * 16 + c;
    const float bias = bop[col];
#pragma unroll
    for (int r = 0; r < 4; ++r) {
      const int row = row0 + quad * 4 + r;
      if (row >= MROWS) continue;
      out[(size_t)row * 256 + col] = acc[ct][r] + bias;
    }
  }
}

// ---------------- workspace layout (bytes), total 16,261,120 ----------------
#define QW_OFF 0u                        // 2*8*3200*32*2 = 3,276,800
#define KW_OFF 3276800u
#define VF_OFF 6553600u                  // vfrag, 3,276,800
#define LE_OFF 9830400u                  // w3b (384KB) until k_lepe overwrites with lepe
#define AT_OFF 13041664u                 // 6288*256*2    = 3,219,456

extern "C" void kernel_launch(void* const* d_in, const int* in_sizes, int n_in,
                              void* d_out, int out_size, void* d_ws, size_t ws_size,
                              hipStream_t stream) {
  const float* x    = (const float*)d_in[0];
  const float* mask = (const float*)d_in[1];
  const float* wq   = (const float*)d_in[2];
  const float* bq   = (const float*)d_in[3];
  const float* wk   = (const float*)d_in[4];
  const float* bk   = (const float*)d_in[5];
  const float* wv   = (const float*)d_in[6];
  const float* bv   = (const float*)d_in[7];
  const float* lw   = (const float*)d_in[8];
  const float* lb   = (const float*)d_in[9];
  const float* wo   = (const float*)d_in[10];
  const float* bo   = (const float*)d_in[11];

  char* ws = (char*)d_ws;
  unsigned short* qws = (unsigned short*)(ws + QW_OFF);
  unsigned short* kws = (unsigned short*)(ws + KW_OFF);
  unsigned short* vfr = (unsigned short*)(ws + VF_OFF);
  unsigned short* w3b = (unsigned short*)(ws + LE_OFF);   // dead before k_lepe
  unsigned short* lpe = (unsigned short*)(ws + LE_OFF);
  unsigned short* atb = (unsigned short*)(ws + AT_OFF);
  unsigned short* vst = (unsigned short*)d_out;             // low 3.22MB of d_out
  unsigned short* xb  = (unsigned short*)d_out + 1609728;   // high 3.22MB of d_out
  float*          outf = (float*)d_out;

  k_cvt<<<882, 256, 0, stream>>>(x, wq, wk, wv, xb, w3b);
  k_qkv<<<dim3(100, 12), 256, 0, stream>>>(xb, w3b, bq, bk, bv, qws, kws, vfr, vst);
  k_lepe<<<784, 256, 0, stream>>>(vst, lw, lb, lpe);
  k_flash<<<3200, 512, 0, stream>>>(qws, kws, vfr, mask, lpe, atb);
  k_oproj<<<dim3(99, 4), 256, 0, stream>>>(atb, wo, bo, outf);
}

// Round 5
// 337.658 us; speedup vs baseline: 1.0245x; 1.0245x over previous
//
#include <hip/hip_runtime.h>

// MaskAttention: B=2,S=3144,C=256,H=8,HD=32, mask-softmax attention with vh=kh,
// LePE 5x5 depthwise conv on v[:,8:], output projection.
// I/O: ALL float32. Internal: bf16 MFMA, f32 accum.
//
// softmax(qk + log(m+eps)) == normalize((m+eps)*exp(qk)); |qk| is tiny, so fixed
// shift M=0 -> no online max; k-range partials additive => split-K (2-way).
//
// R5 changes vs R4 (179us, failed cross-fence reg prefetch) / R3 (139us):
//  - k_flash restructured: block = (b,strip), 16 waves = 8 heads x 2 k-halves.
//    Each wave owns a complete k-half for its head: NO per-tile fences, NO LDS
//    mask staging, NO barriers in the loop. One pairwise cross-wave reduction
//    at the end (18KB LDS). 1024-thread blocks, 2 blocks/CU -> up to 32
//    waves/CU (was ~10): latency hidden by TLP, not by fragile sw pipelining.
//  - mask: direct per-lane float4 global loads (same 64B-segment density as
//    staged); tile sequence shared by 8 same-CU waves -> L1 dedup. Mask is
//    read ~once per strip instead of 8x (L2 traffic /8).
//  - XCD map: u=(j<<3)|xcd, b=xcd&1, strip=j*4+(xcd>>1) -> each XCD's k/vfrag
//    working set = one batch (3.2MB) fits its 4MB L2.
//  - k_cvt/k_qkv/k_lepe/k_oproj unchanged from R3/R4.

#define S_LEN 3144
#define SP    3200            // S padded to 64 (50 k-tiles; 0..48 fully valid)
#define HEADS 8
#define HD    32
#define BATCH 2
#define MROWS (BATCH*S_LEN)   // 6288
#define NPIX  3136            // 56*56
#define SCALE_F 0.17677669529663687f   // 32^-0.5
#define KQ_SC   0.25504472665352026f   // SCALE_F * log2(e)

typedef __bf16 bf16x8  __attribute__((ext_vector_type(8)));
typedef __bf16 bf16x4  __attribute__((ext_vector_type(4)));
typedef float  floatx4 __attribute__((ext_vector_type(4)));
typedef short  shortx4 __attribute__((ext_vector_type(4)));

static __device__ __forceinline__ float bf2f(unsigned int h) {
  union { unsigned int u; float f; } v; v.u = h << 16; return v.f;
}
static __device__ __forceinline__ unsigned short f2bf(float f) {
  union { __bf16 b; unsigned short u; } v; v.b = (__bf16)f; return v.u;
}
static __device__ __forceinline__ bf16x8 ldcvt8(const float* __restrict__ p) {
  float4 a = *(const float4*)p;
  float4 b = *(const float4*)(p + 4);
  bf16x8 r;
  r[0]=(__bf16)a.x; r[1]=(__bf16)a.y; r[2]=(__bf16)a.z; r[3]=(__bf16)a.w;
  r[4]=(__bf16)b.x; r[5]=(__bf16)b.y; r[6]=(__bf16)b.z; r[7]=(__bf16)b.w;
  return r;
}

// ---------------- K0: one-time f32 -> bf16 conversion (x, wq, wk, wv) ----------------
__global__ __launch_bounds__(256) void k_cvt(
    const float* __restrict__ x, const float* __restrict__ wq,
    const float* __restrict__ wk, const float* __restrict__ wv,
    unsigned short* __restrict__ xb, unsigned short* __restrict__ w3b)
{
  const int i = blockIdx.x * 256 + threadIdx.x;   // unit of 8 floats
  const int NX = MROWS * 32;                      // 201216
  const int NW = 8192;                            // 65536/8
  const float* src;
  unsigned short* dst;
  if (i < NX) { src = x + (size_t)i * 8; dst = xb + (size_t)i * 8; }
  else {
    const int j = i - NX;
    if (j >= 3 * NW) return;
    src = (j < NW) ? wq + (size_t)j * 8
        : (j < 2 * NW) ? wk + (size_t)(j - NW) * 8
                       : wv + (size_t)(j - 2 * NW) * 8;
    dst = w3b + (size_t)j * 8;
  }
  bf16x8 v = ldcvt8(src);
  *(bf16x8*)dst = v;
}

// ---------------- K1: fused q/k/v projection (bf16 in -> bf16 out) ----------------
// Grid (100, 12): blockIdx.x = bsel*50 + stile. Pad rows (s>=S_LEN) store 0.
__global__ __launch_bounds__(256) void k_qkv(
    const unsigned short* __restrict__ xb, const unsigned short* __restrict__ w3b,
    const float* __restrict__ bqp, const float* __restrict__ bkp,
    const float* __restrict__ bvp,
    unsigned short* __restrict__ qws, unsigned short* __restrict__ kws,
    unsigned short* __restrict__ vfrag, unsigned short* __restrict__ vstage)
{
  __shared__ unsigned short lds_t[64 * 65];   // transpose staging (k blocks only)
  const int lane = threadIdx.x & 63;
  const int wid  = threadIdx.x >> 6;
  const int c    = lane & 15, quad = lane >> 4;
  const int bsel  = blockIdx.x / 50;
  const int stile = blockIdx.x % 50;
  const int srow0 = stile * 64;
  const int ncol = blockIdx.y * 64;           // 0..767
  const int wsel = ncol >> 8;
  const int col0 = ncol & 255;

  const float* bptr = (wsel == 0) ? bqp : (wsel == 1) ? bkp : bvp;

  const int srow = srow0 + wid * 16 + c;
  const int arow = bsel * S_LEN + ((srow < S_LEN) ? srow : 0);  // clamp pad rows
  const unsigned short* ap = xb  + (size_t)arow * 256 + quad * 8;
  const unsigned short* bp = w3b + (size_t)(ncol + c) * 256 + quad * 8;

  floatx4 acc[4];
#pragma unroll
  for (int ct = 0; ct < 4; ++ct) acc[ct] = (floatx4){0.f, 0.f, 0.f, 0.f};

#pragma unroll
  for (int ks = 0; ks < 8; ++ks) {
    bf16x8 af = *(const bf16x8*)(ap + ks * 32);
#pragma unroll
    for (int ct = 0; ct < 4; ++ct) {
      bf16x8 bf = *(const bf16x8*)(bp + (size_t)ct * 16 * 256 + ks * 32);
      acc[ct] = __builtin_amdgcn_mfma_f32_16x16x32_bf16(af, bf, acc[ct], 0, 0, 0);
    }
  }

#pragma unroll
  for (int ct = 0; ct < 4; ++ct) {
    const int col = col0 + ct * 16 + c;
    const float bias = bptr[col];
#pragma unroll
    for (int r = 0; r < 4; ++r) {
      const int s = srow0 + wid * 16 + quad * 4 + r;   // 0..3199 within batch
      const int valid = (s < S_LEN);
      const float v = acc[ct][r] + bias;
      if (wsel == 0) {
        qws[(((size_t)(bsel * HEADS + (col >> 5))) * SP + s) * HD + (col & 31)] =
            valid ? f2bf(v) : (unsigned short)0;
      } else if (wsel == 1) {
        // QK-side copy carries log2e; V-side copy (lds_t->vfrag) does NOT.
        kws[(((size_t)(bsel * HEADS + (col >> 5))) * SP + s) * HD + (col & 31)] =
            valid ? f2bf(v * KQ_SC) : (unsigned short)0;
        lds_t[(ct * 16 + c) * 65 + (wid * 16 + quad * 4 + r)] =
            valid ? f2bf(v * SCALE_F) : (unsigned short)0;
      } else {
        if (valid) vstage[(size_t)(bsel * S_LEN + s) * 256 + col] = f2bf(v);
      }
    }
  }

  if (wsel == 1) {
    // vfrag: PV A-operand fragments in exact MFMA lane order.
    __syncthreads();
    const int tid = threadIdx.x;
#pragma unroll
    for (int j = 0; j < 4; ++j) {
      const int grp  = j * 4 + (tid >> 6);   // 0..15, wave-uniform
      const int l    = tid & 63;
      const int ct2  = grp & 3;
      const int half = (grp >> 2) & 1;
      const int hsel = grp >> 3;
      const int cc = l & 15, qq = l >> 4;
      const int cl = hsel * 32 + half * 16 + cc;
      const int rb = ct2 * 16 + qq * 4;
      union { shortx4 s4; unsigned short u[4]; } pk;
#pragma unroll
      for (int e = 0; e < 4; ++e) pk.u[e] = lds_t[cl * 65 + rb + e];
      const int hglob = (col0 >> 5) + hsel;
      const size_t off =
          ((((size_t)(bsel * HEADS + hglob) * 50 + stile) * 4 + ct2) * 2 + half) * 64 + l;
      *(shortx4*)(vfrag + off * 4) = pk.s4;
    }
  }
}

// ---------------- K2: LePE 5x5 depthwise conv on v[:,8:] ----------------
__global__ __launch_bounds__(256) void k_lepe(const unsigned short* __restrict__ vws,
                                              const float* __restrict__ cw,
                                              const float* __restrict__ cb,
                                              unsigned short* __restrict__ lepe)
{
  int idx = blockIdx.x * 256 + threadIdx.x;
  if (idx >= BATCH * NPIX * 32) return;
  const int cg = idx & 31;
  const int p  = (idx >> 5) % NPIX;
  const int b  = idx / (NPIX * 32);
  const int y  = p / 56, xx = p - y * 56;

  float acc[8];
  {
    float4 b0 = *(const float4*)(cb + cg * 8);
    float4 b1 = *(const float4*)(cb + cg * 8 + 4);
    acc[0]=b0.x; acc[1]=b0.y; acc[2]=b0.z; acc[3]=b0.w;
    acc[4]=b1.x; acc[5]=b1.y; acc[6]=b1.z; acc[7]=b1.w;
  }
#pragma unroll
  for (int dy = -2; dy <= 2; ++dy) {
    const int yy = y + dy;
    if ((unsigned)yy >= 56u) continue;
#pragma unroll
    for (int dx = -2; dx <= 2; ++dx) {
      const int xs = xx + dx;
      if ((unsigned)xs >= 56u) continue;
      uint4 vv = *(const uint4*)(vws + (size_t)(b * S_LEN + 8 + yy * 56 + xs) * 256 + cg * 8);
      const float* wp = cw + (size_t)((dy + 2) * 5 + (dx + 2)) * 256 + cg * 8;
      float4 w0 = *(const float4*)wp;
      float4 w1 = *(const float4*)(wp + 4);
      unsigned int va[4] = {vv.x, vv.y, vv.z, vv.w};
      acc[0] += bf2f(va[0] & 0xFFFFu) * w0.x;  acc[1] += bf2f(va[0] >> 16) * w0.y;
      acc[2] += bf2f(va[1] & 0xFFFFu) * w0.z;  acc[3] += bf2f(va[1] >> 16) * w0.w;
      acc[4] += bf2f(va[2] & 0xFFFFu) * w1.x;  acc[5] += bf2f(va[2] >> 16) * w1.y;
      acc[6] += bf2f(va[3] & 0xFFFFu) * w1.z;  acc[7] += bf2f(va[3] >> 16) * w1.w;
    }
  }
  unsigned int o[4];
#pragma unroll
  for (int j = 0; j < 4; ++j)
    o[j] = (unsigned int)f2bf(acc[2*j]) | ((unsigned int)f2bf(acc[2*j+1]) << 16);
  *((uint4*)(lepe + (size_t)(b * NPIX + p) * 256 + cg * 8)) = make_uint4(o[0], o[1], o[2], o[3]);
}

// ---------------- K3: flash attention, block=(b,strip), 16 waves = 8 heads x 2 k-halves ----
template<bool TAIL>
static __device__ __forceinline__ void proc_tile(
    int t, const unsigned short* __restrict__ kb,
    const unsigned short* __restrict__ vb,
    const float* __restrict__ mp,
    int c, int quad, int lane, const bf16x8 qf,
    floatx4& o0, floatx4& o1, float& l_run)
{
  const int k0 = t * 64;
  bf16x8 kf[4]; shortx4 v0[4], v1[4];
  const unsigned short* tb = vb + (size_t)t * 2048;
#pragma unroll
  for (int ct = 0; ct < 4; ++ct) {
    kf[ct] = *(const bf16x8*)(kb + (size_t)(k0 + ct * 16 + c) * HD + quad * 8);
    v0[ct] = *(const shortx4*)(tb + (ct * 2 + 0) * 256 + lane * 4);
    v1[ct] = *(const shortx4*)(tb + (ct * 2 + 1) * 256 + lane * 4);
  }
  floatx4 s[4];
#pragma unroll
  for (int ct = 0; ct < 4; ++ct)
    s[ct] = __builtin_amdgcn_mfma_f32_16x16x32_bf16(kf[ct], qf,
               (floatx4){0.f,0.f,0.f,0.f}, 0, 0, 0);
  float ls = 0.f;
  shortx4 pf[4];
#pragma unroll
  for (int ct = 0; ct < 4; ++ct) {
    int kk = k0 + ct * 16 + quad * 4;
    int kkl = kk;
    if (TAIL) { if (kkl > S_LEN - 4) kkl = S_LEN - 4; }  // keep mask row read in-bounds
    const float4 mv = *(const float4*)(mp + kkl);
    float pr[4];
    pr[0] = (mv.x + 1e-6f) * __builtin_amdgcn_exp2f(s[ct][0]);
    pr[1] = (mv.y + 1e-6f) * __builtin_amdgcn_exp2f(s[ct][1]);
    pr[2] = (mv.z + 1e-6f) * __builtin_amdgcn_exp2f(s[ct][2]);
    pr[3] = (mv.w + 1e-6f) * __builtin_amdgcn_exp2f(s[ct][3]);
    if (TAIL) {
#pragma unroll
      for (int r = 0; r < 4; ++r) if (kk + r >= S_LEN) pr[r] = 0.f;
    }
    ls += (pr[0] + pr[1]) + (pr[2] + pr[3]);
    union { bf16x4 b4; shortx4 s4; } u;
    u.b4[0]=(__bf16)pr[0]; u.b4[1]=(__bf16)pr[1]; u.b4[2]=(__bf16)pr[2]; u.b4[3]=(__bf16)pr[3];
    pf[ct] = u.s4;
  }
  l_run += ls;
#pragma unroll
  for (int ct = 0; ct < 4; ++ct) {
    o0 = __builtin_amdgcn_mfma_f32_16x16x16bf16_1k(v0[ct], pf[ct], o0, 0, 0, 0);
    o1 = __builtin_amdgcn_mfma_f32_16x16x16bf16_1k(v1[ct], pf[ct], o1, 0, 0, 0);
  }
}

__global__ __launch_bounds__(1024) void k_flash(
    const unsigned short* __restrict__ qws,
    const unsigned short* __restrict__ kws,
    const unsigned short* __restrict__ vfrag,
    const float* __restrict__ mask,
    const unsigned short* __restrict__ lepe,
    unsigned short* __restrict__ attn)
{
  __shared__ __align__(16) float red[8][64][9];   // khalf=1 partials: o0[4],o1[4],l
  const int lane = threadIdx.x & 63;
  const int wid  = threadIdx.x >> 6;          // 0..15
  const int h    = wid & 7;
  const int khalf = wid >> 3;                 // 0: tiles 0..24, 1: tiles 25..49
  const int c    = lane & 15, quad = lane >> 4;

  // u = (j<<3)|xcd; b = xcd&1, strip = j*4 + (xcd>>1): bijective on 0..399,
  // each XCD sees ONE batch (its k/vfrag panel = 3.2MB fits 4MB L2).
  const int u    = blockIdx.x;               // 0..399
  const int xcd  = u & 7;
  const int j    = u >> 3;                   // 0..49
  const int b    = xcd & 1;
  const int strip = j * 4 + (xcd >> 1);      // 0..199
  const int qrow = strip * 16 + c;
  const size_t bh = (size_t)(b * HEADS + h);

  const bf16x8 qf = *(const bf16x8*)(qws + (bh * SP + qrow) * HD + quad * 8);
  const unsigned short* kb = kws + bh * SP * HD;
  const unsigned short* vb = vfrag + bh * (size_t)(50 * 2048);
  const int mrow = (qrow < S_LEN) ? qrow : (S_LEN - 1);
  const float* mp = mask + ((size_t)b * S_LEN + mrow) * S_LEN;

  float l_run = 0.f;
  floatx4 o0 = (floatx4){0.f,0.f,0.f,0.f};
  floatx4 o1 = (floatx4){0.f,0.f,0.f,0.f};

  const int t0 = khalf * 25;
#pragma unroll 1
  for (int jt = 0; jt < 24; ++jt)
    proc_tile<false>(t0 + jt, kb, vb, mp, c, quad, lane, qf, o0, o1, l_run);
  if (khalf == 0)
    proc_tile<false>(24, kb, vb, mp, c, quad, lane, qf, o0, o1, l_run);
  else
    proc_tile<true >(49, kb, vb, mp, c, quad, lane, qf, o0, o1, l_run);

  // ---- pairwise cross-wave reduction: khalf=1 -> LDS, khalf=0 adds ----
  if (khalf) {
#pragma unroll
    for (int r = 0; r < 4; ++r) {
      red[h][lane][r]     = o0[r];
      red[h][lane][4 + r] = o1[r];
    }
    red[h][lane][8] = l_run;
  }
  __syncthreads();

  if (!khalf) {
#pragma unroll
    for (int r = 0; r < 4; ++r) {
      o0[r] += red[h][lane][r];
      o1[r] += red[h][lane][4 + r];
    }
    l_run += red[h][lane][8];
    l_run += __shfl_xor(l_run, 16);
    l_run += __shfl_xor(l_run, 32);
    const float rl = 1.f / l_run;

    if (qrow < S_LEN) {
      const size_t obase = ((size_t)b * S_LEN + qrow) * 256 + h * 32;
      const size_t lbase = (qrow >= 8) ? (((size_t)b * NPIX + (qrow - 8)) * 256 + h * 32) : 0;
#pragma unroll
      for (int mt2 = 0; mt2 < 2; ++mt2) {
        floatx4 ov = mt2 ? o1 : o0;
#pragma unroll
        for (int r = 0; r < 4; ++r) {
          const int d = mt2 * 16 + quad * 4 + r;
          float val = ov[r] * rl;
          if (qrow >= 8) val += bf2f(lepe[lbase + d]);
          attn[obase + d] = f2bf(val);
        }
      }
    }
  }
}

// ---------------- K4: output projection (attn bf16, wo/bo f32 -> f32 out) ----------------
__global__ __launch_bounds__(256) void k_oproj(
    const unsigned short* __restrict__ attn,
    const float* __restrict__ wop,
    const float* __restrict__ bop,
    float* __restrict__ out)
{
  const int lane = threadIdx.x & 63;
  const int wid  = threadIdx.x >> 6;
  const int c = lane & 15, quad = lane >> 4;
  const int row0 = blockIdx.x * 64 + wid * 16;
  const int col0 = blockIdx.y * 64;

  int arow = row0 + c; if (arow >= MROWS) arow = 0;
  const unsigned short* ap = attn + (size_t)arow * 256 + quad * 8;
  const float* bp = wop + (size_t)(col0 + c) * 256 + quad * 8;

  floatx4 acc[4];
#pragma unroll
  for (int ct = 0; ct < 4; ++ct) acc[ct] = (floatx4){0.f,0.f,0.f,0.f};
#pragma unroll
  for (int ks = 0; ks < 8; ++ks) {
    bf16x8 af = *(const bf16x8*)(ap + ks * 32);
#pragma unroll
    for (int ct = 0; ct < 4; ++ct) {
      bf16x8 bf = ldcvt8(bp + (size_t)ct * 16 * 256 + ks * 32);
      acc[ct] = __builtin_amdgcn_mfma_f32_16x16x32_bf16(af, bf, acc[ct], 0, 0, 0);
    }
  }
#pragma unroll
  for (int ct = 0; ct < 4; ++ct) {
    const int col = col0 + ct * 16 + c;
    const float bias = bop[col];
#pragma unroll
    for (int r = 0; r < 4; ++r) {
      const int row = row0 + quad * 4 + r;
      if (row >= MROWS) continue;
      out[(size_t)row * 256 + col] = acc[ct][r] + bias;
    }
  }
}

// ---------------- workspace layout (bytes), total 16,261,120 ----------------
#define QW_OFF 0u                        // 2*8*3200*32*2 = 3,276,800
#define KW_OFF 3276800u
#define VF_OFF 6553600u                  // vfrag, 3,276,800
#define LE_OFF 9830400u                  // w3b (384KB) until k_lepe overwrites with lepe
#define AT_OFF 13041664u                 // 6288*256*2    = 3,219,456

extern "C" void kernel_launch(void* const* d_in, const int* in_sizes, int n_in,
                              void* d_out, int out_size, void* d_ws, size_t ws_size,
                              hipStream_t stream) {
  const float* x    = (const float*)d_in[0];
  const float* mask = (const float*)d_in[1];
  const float* wq   = (const float*)d_in[2];
  const float* bq   = (const float*)d_in[3];
  const float* wk   = (const float*)d_in[4];
  const float* bk   = (const float*)d_in[5];
  const float* wv   = (const float*)d_in[6];
  const float* bv   = (const float*)d_in[7];
  const float* lw   = (const float*)d_in[8];
  const float* lb   = (const float*)d_in[9];
  const float* wo   = (const float*)d_in[10];
  const float* bo   = (const float*)d_in[11];

  char* ws = (char*)d_ws;
  unsigned short* qws = (unsigned short*)(ws + QW_OFF);
  unsigned short* kws = (unsigned short*)(ws + KW_OFF);
  unsigned short* vfr = (unsigned short*)(ws + VF_OFF);
  unsigned short* w3b = (unsigned short*)(ws + LE_OFF);   // dead before k_lepe
  unsigned short* lpe = (unsigned short*)(ws + LE_OFF);
  unsigned short* atb = (unsigned short*)(ws + AT_OFF);
  unsigned short* vst = (unsigned short*)d_out;             // low 3.22MB of d_out
  unsigned short* xb  = (unsigned short*)d_out + 1609728;   // high 3.22MB of d_out
  float*          outf = (float*)d_out;

  k_cvt<<<882, 256, 0, stream>>>(x, wq, wk, wv, xb, w3b);
  k_qkv<<<dim3(100, 12), 256, 0, stream>>>(xb, w3b, bq, bk, bv, qws, kws, vfr, vst);
  k_lepe<<<784, 256, 0, stream>>>(vst, lw, lb, lpe);
  k_flash<<<400, 1024, 0, stream>>>(qws, kws, vfr, mask, lpe, atb);
  k_oproj<<<dim3(99, 4), 256, 0, stream>>>(atb, wo, bo, outf);
}

// Round 6
// 326.743 us; speedup vs baseline: 1.0587x; 1.0334x over previous
//
#include <hip/hip_runtime.h>

// MaskAttention: B=2,S=3144,C=256,H=8,HD=32, mask-softmax attention with vh=kh,
// LePE 5x5 depthwise conv on v[:,8:], output projection.
// I/O: ALL float32. Internal: bf16 MFMA, f32 accum.
//
// softmax(qk + log(m+eps)) == normalize((m+eps)*exp(qk)); |qk| tiny -> fixed
// shift M=0, no online max; k-range partials additive => split-K.
//
// R6 theory: R1/R3/R5 all pinned at ~139-165us with mask HBM traffic at
// ~0.45-0.94 TB/s: the 16-rows-x-12.6KB-stride access pattern (16 scattered
// 64B granules per request) thrashes DRAM pages -> ~1TB/s effective ceiling.
// Fix: k_mprep relayout prepass -- read mask coalesced, write pm[(b,strip)][t]
// as CONTIGUOUS 4KB tile blocks pre-permuted into the exact (instr,lane)+XOR
// order the global_load_lds staging consumes, with log2(m+1e-6) folded in
// (softmax = exp2(s+lm); tail granules = -1e30 -> exp2 -> 0, TAIL path gone).
// k_flash keeps the R3-proven structure; its mask stream is now sequential.
// pm needs 82MB: runtime ws_size branch, R3 kernel kept verbatim as fallback.

#define S_LEN 3144
#define SP    3200            // S padded to 64 (50 k-tiles; 0..48 fully valid)
#define HEADS 8
#define HD    32
#define BATCH 2
#define MROWS (BATCH*S_LEN)   // 6288
#define NPIX  3136            // 56*56
#define SCALE_F 0.17677669529663687f   // 32^-0.5
#define KQ_SC   0.25504472665352026f   // SCALE_F * log2(e)

typedef __bf16 bf16x8  __attribute__((ext_vector_type(8)));
typedef __bf16 bf16x4  __attribute__((ext_vector_type(4)));
typedef float  floatx4 __attribute__((ext_vector_type(4)));
typedef short  shortx4 __attribute__((ext_vector_type(4)));

static __device__ __forceinline__ float bf2f(unsigned int h) {
  union { unsigned int u; float f; } v; v.u = h << 16; return v.f;
}
static __device__ __forceinline__ unsigned short f2bf(float f) {
  union { __bf16 b; unsigned short u; } v; v.b = (__bf16)f; return v.u;
}
static __device__ __forceinline__ bf16x8 ldcvt8(const float* __restrict__ p) {
  float4 a = *(const float4*)p;
  float4 b = *(const float4*)(p + 4);
  bf16x8 r;
  r[0]=(__bf16)a.x; r[1]=(__bf16)a.y; r[2]=(__bf16)a.z; r[3]=(__bf16)a.w;
  r[4]=(__bf16)b.x; r[5]=(__bf16)b.y; r[6]=(__bf16)b.z; r[7]=(__bf16)b.w;
  return r;
}

#define GLOBAL_AS __attribute__((address_space(1)))
#define LDS_AS    __attribute__((address_space(3)))
static __device__ __forceinline__ void gload_lds16(const void* g, void* l) {
  __builtin_amdgcn_global_load_lds((const GLOBAL_AS void*)g, (LDS_AS void*)l, 16, 0, 0);
}

#define FENCE4() asm volatile("s_waitcnt vmcnt(4)" ::: "memory")
#define FENCE0() asm volatile("s_waitcnt vmcnt(0)" ::: "memory")

// ---------------- K0: one-time f32 -> bf16 conversion (x, wq, wk, wv) ----------------
__global__ __launch_bounds__(256) void k_cvt(
    const float* __restrict__ x, const float* __restrict__ wq,
    const float* __restrict__ wk, const float* __restrict__ wv,
    unsigned short* __restrict__ xb, unsigned short* __restrict__ w3b)
{
  const int i = blockIdx.x * 256 + threadIdx.x;   // unit of 8 floats
  const int NX = MROWS * 32;                      // 201216
  const int NW = 8192;                            // 65536/8
  const float* src;
  unsigned short* dst;
  if (i < NX) { src = x + (size_t)i * 8; dst = xb + (size_t)i * 8; }
  else {
    const int j = i - NX;
    if (j >= 3 * NW) return;
    src = (j < NW) ? wq + (size_t)j * 8
        : (j < 2 * NW) ? wk + (size_t)(j - NW) * 8
                       : wv + (size_t)(j - 2 * NW) * 8;
    dst = w3b + (size_t)j * 8;
  }
  bf16x8 v = ldcvt8(src);
  *(bf16x8*)dst = v;
}

// ---------------- K0b: mask relayout prepass ----------------
// pm[(b*200+strip)*50 + t] = 4KB block in (instr i, lane l) order:
//   position (i,l) holds log2(mask[b][strip*16 + i*4 + (l>>4)][t*64 + ((l&15)^rq)*4 ..+3] + 1e-6)
// (rq = i*4 + (l>>4); XOR swizzle baked in so the LDS float4 readback is
// bank-spread). Tail granules (col >= S_LEN) = -1e30 -> exp2 -> 0.
__global__ __launch_bounds__(256) void k_mprep(const float* __restrict__ mask,
                                               float* __restrict__ pm)
{
  const int bs = blockIdx.x;            // 0..399 = b*200 + strip
  const int b  = bs / 200, strip = bs % 200;
  const int tid = threadIdx.x;
  const int i  = tid >> 6, l = tid & 63;
  const int rq = i * 4 + (l >> 4);      // row within strip, 0..15
  int mr = strip * 16 + rq; if (mr >= S_LEN) mr = S_LEN - 1;
  const int cg = ((l & 15) ^ rq) & 15;  // source granule (XOR swizzle)
  const float* src = mask + ((size_t)b * S_LEN + mr) * S_LEN;
  float* dst = pm + (size_t)bs * (50 * 1024) + tid * 4;
#pragma unroll 1
  for (int tt = 0; tt < 10; ++tt) {
    const int t = blockIdx.y * 10 + tt;
    const int c0 = t * 64 + cg * 4;     // multiple of 4; S_LEN%4==0 -> granule all-valid or all-invalid
    float4 o;
    if (c0 < S_LEN) {
      float4 mv = *(const float4*)(src + c0);
      o.x = __log2f(mv.x + 1e-6f);
      o.y = __log2f(mv.y + 1e-6f);
      o.z = __log2f(mv.z + 1e-6f);
      o.w = __log2f(mv.w + 1e-6f);
    } else {
      o = make_float4(-1e30f, -1e30f, -1e30f, -1e30f);
    }
    *(float4*)(dst + (size_t)t * 1024) = o;
  }
}

// ---------------- K1: fused q/k/v projection (bf16 in -> bf16 out) ----------------
// Grid (100, 12): blockIdx.x = bsel*50 + stile. Pad rows (s>=S_LEN) store 0.
__global__ __launch_bounds__(256) void k_qkv(
    const unsigned short* __restrict__ xb, const unsigned short* __restrict__ w3b,
    const float* __restrict__ bqp, const float* __restrict__ bkp,
    const float* __restrict__ bvp,
    unsigned short* __restrict__ qws, unsigned short* __restrict__ kws,
    unsigned short* __restrict__ vfrag, unsigned short* __restrict__ vstage)
{
  __shared__ unsigned short lds_t[64 * 65];   // transpose staging (k blocks only)
  const int lane = threadIdx.x & 63;
  const int wid  = threadIdx.x >> 6;
  const int c    = lane & 15, quad = lane >> 4;
  const int bsel  = blockIdx.x / 50;
  const int stile = blockIdx.x % 50;
  const int srow0 = stile * 64;
  const int ncol = blockIdx.y * 64;           // 0..767
  const int wsel = ncol >> 8;
  const int col0 = ncol & 255;

  const float* bptr = (wsel == 0) ? bqp : (wsel == 1) ? bkp : bvp;

  const int srow = srow0 + wid * 16 + c;
  const int arow = bsel * S_LEN + ((srow < S_LEN) ? srow : 0);  // clamp pad rows
  const unsigned short* ap = xb  + (size_t)arow * 256 + quad * 8;
  const unsigned short* bp = w3b + (size_t)(ncol + c) * 256 + quad * 8;

  floatx4 acc[4];
#pragma unroll
  for (int ct = 0; ct < 4; ++ct) acc[ct] = (floatx4){0.f, 0.f, 0.f, 0.f};

#pragma unroll
  for (int ks = 0; ks < 8; ++ks) {
    bf16x8 af = *(const bf16x8*)(ap + ks * 32);
#pragma unroll
    for (int ct = 0; ct < 4; ++ct) {
      bf16x8 bf = *(const bf16x8*)(bp + (size_t)ct * 16 * 256 + ks * 32);
      acc[ct] = __builtin_amdgcn_mfma_f32_16x16x32_bf16(af, bf, acc[ct], 0, 0, 0);
    }
  }

#pragma unroll
  for (int ct = 0; ct < 4; ++ct) {
    const int col = col0 + ct * 16 + c;
    const float bias = bptr[col];
#pragma unroll
    for (int r = 0; r < 4; ++r) {
      const int s = srow0 + wid * 16 + quad * 4 + r;   // 0..3199 within batch
      const int valid = (s < S_LEN);
      const float v = acc[ct][r] + bias;
      if (wsel == 0) {
        qws[(((size_t)(bsel * HEADS + (col >> 5))) * SP + s) * HD + (col & 31)] =
            valid ? f2bf(v) : (unsigned short)0;
      } else if (wsel == 1) {
        // QK-side copy carries log2e; V-side copy (lds_t->vfrag) does NOT.
        kws[(((size_t)(bsel * HEADS + (col >> 5))) * SP + s) * HD + (col & 31)] =
            valid ? f2bf(v * KQ_SC) : (unsigned short)0;
        lds_t[(ct * 16 + c) * 65 + (wid * 16 + quad * 4 + r)] =
            valid ? f2bf(v * SCALE_F) : (unsigned short)0;
      } else {
        if (valid) vstage[(size_t)(bsel * S_LEN + s) * 256 + col] = f2bf(v);
      }
    }
  }

  if (wsel == 1) {
    // vfrag: PV A-operand fragments in exact MFMA lane order.
    __syncthreads();
    const int tid = threadIdx.x;
#pragma unroll
    for (int j = 0; j < 4; ++j) {
      const int grp  = j * 4 + (tid >> 6);   // 0..15, wave-uniform
      const int l    = tid & 63;
      const int ct2  = grp & 3;
      const int half = (grp >> 2) & 1;
      const int hsel = grp >> 3;
      const int cc = l & 15, qq = l >> 4;
      const int cl = hsel * 32 + half * 16 + cc;
      const int rb = ct2 * 16 + qq * 4;
      union { shortx4 s4; unsigned short u[4]; } pk;
#pragma unroll
      for (int e = 0; e < 4; ++e) pk.u[e] = lds_t[cl * 65 + rb + e];
      const int hglob = (col0 >> 5) + hsel;
      const size_t off =
          ((((size_t)(bsel * HEADS + hglob) * 50 + stile) * 4 + ct2) * 2 + half) * 64 + l;
      *(shortx4*)(vfrag + off * 4) = pk.s4;
    }
  }
}

// ---------------- K2: LePE 5x5 depthwise conv on v[:,8:] ----------------
__global__ __launch_bounds__(256) void k_lepe(const unsigned short* __restrict__ vws,
                                              const float* __restrict__ cw,
                                              const float* __restrict__ cb,
                                              unsigned short* __restrict__ lepe)
{
  int idx = blockIdx.x * 256 + threadIdx.x;
  if (idx >= BATCH * NPIX * 32) return;
  const int cg = idx & 31;
  const int p  = (idx >> 5) % NPIX;
  const int b  = idx / (NPIX * 32);
  const int y  = p / 56, xx = p - y * 56;

  float acc[8];
  {
    float4 b0 = *(const float4*)(cb + cg * 8);
    float4 b1 = *(const float4*)(cb + cg * 8 + 4);
    acc[0]=b0.x; acc[1]=b0.y; acc[2]=b0.z; acc[3]=b0.w;
    acc[4]=b1.x; acc[5]=b1.y; acc[6]=b1.z; acc[7]=b1.w;
  }
#pragma unroll
  for (int dy = -2; dy <= 2; ++dy) {
    const int yy = y + dy;
    if ((unsigned)yy >= 56u) continue;
#pragma unroll
    for (int dx = -2; dx <= 2; ++dx) {
      const int xs = xx + dx;
      if ((unsigned)xs >= 56u) continue;
      uint4 vv = *(const uint4*)(vws + (size_t)(b * S_LEN + 8 + yy * 56 + xs) * 256 + cg * 8);
      const float* wp = cw + (size_t)((dy + 2) * 5 + (dx + 2)) * 256 + cg * 8;
      float4 w0 = *(const float4*)wp;
      float4 w1 = *(const float4*)(wp + 4);
      unsigned int va[4] = {vv.x, vv.y, vv.z, vv.w};
      acc[0] += bf2f(va[0] & 0xFFFFu) * w0.x;  acc[1] += bf2f(va[0] >> 16) * w0.y;
      acc[2] += bf2f(va[1] & 0xFFFFu) * w0.z;  acc[3] += bf2f(va[1] >> 16) * w0.w;
      acc[4] += bf2f(va[2] & 0xFFFFu) * w1.x;  acc[5] += bf2f(va[2] >> 16) * w1.y;
      acc[6] += bf2f(va[3] & 0xFFFFu) * w1.z;  acc[7] += bf2f(va[3] >> 16) * w1.w;
    }
  }
  unsigned int o[4];
#pragma unroll
  for (int j = 0; j < 4; ++j)
    o[j] = (unsigned int)f2bf(acc[2*j]) | ((unsigned int)f2bf(acc[2*j+1]) << 16);
  *((uint4*)(lepe + (size_t)(b * NPIX + p) * 256 + cg * 8)) = make_uint4(o[0], o[1], o[2], o[3]);
}

// ============ K3 (pre path): flash attention reading relayouted mask ============
static __device__ __forceinline__ void proc_tile_pre(
    int t, const unsigned short* __restrict__ kb,
    const unsigned short* __restrict__ vb,
    const float* __restrict__ mb,
    int c, int quad, int lane, const bf16x8 qf,
    floatx4& o0, floatx4& o1, float& l_run)
{
  const int k0 = t * 64;
  bf16x8 kf[4]; shortx4 v0[4], v1[4];
  const unsigned short* tb = vb + (size_t)t * 2048;
#pragma unroll
  for (int ct = 0; ct < 4; ++ct) {
    kf[ct] = *(const bf16x8*)(kb + (size_t)(k0 + ct * 16 + c) * HD + quad * 8);
    v0[ct] = *(const shortx4*)(tb + (ct * 2 + 0) * 256 + lane * 4);
    v1[ct] = *(const shortx4*)(tb + (ct * 2 + 1) * 256 + lane * 4);
  }
  floatx4 s[4];
#pragma unroll
  for (int ct = 0; ct < 4; ++ct)
    s[ct] = __builtin_amdgcn_mfma_f32_16x16x32_bf16(kf[ct], qf,
               (floatx4){0.f,0.f,0.f,0.f}, 0, 0, 0);
  float ls = 0.f;
  shortx4 pf[4];
#pragma unroll
  for (int ct = 0; ct < 4; ++ct) {
    const float4 mv = *(const float4*)(mb + c * 64 + (((ct * 4 + quad) ^ c) * 4));
    float pr[4];
    pr[0] = __builtin_amdgcn_exp2f(s[ct][0] + mv.x);
    pr[1] = __builtin_amdgcn_exp2f(s[ct][1] + mv.y);
    pr[2] = __builtin_amdgcn_exp2f(s[ct][2] + mv.z);
    pr[3] = __builtin_amdgcn_exp2f(s[ct][3] + mv.w);
    ls += (pr[0] + pr[1]) + (pr[2] + pr[3]);
    union { bf16x4 b4; shortx4 s4; } u;
    u.b4[0]=(__bf16)pr[0]; u.b4[1]=(__bf16)pr[1]; u.b4[2]=(__bf16)pr[2]; u.b4[3]=(__bf16)pr[3];
    pf[ct] = u.s4;
  }
  l_run += ls;
#pragma unroll
  for (int ct = 0; ct < 4; ++ct) {
    o0 = __builtin_amdgcn_mfma_f32_16x16x16bf16_1k(v0[ct], pf[ct], o0, 0, 0, 0);
    o1 = __builtin_amdgcn_mfma_f32_16x16x16bf16_1k(v1[ct], pf[ct], o1, 0, 0, 0);
  }
}

static __device__ __forceinline__ void stage_pre(
    const float* __restrict__ mp_t, int lane, float* dst)
{
#pragma unroll
  for (int i = 0; i < 4; ++i)
    gload_lds16(mp_t + i * 256 + lane * 4, dst + i * 256);  // fully contiguous 1KB
}

__global__ __launch_bounds__(512) void k_flash_pre(
    const unsigned short* __restrict__ qws,
    const unsigned short* __restrict__ kws,
    const unsigned short* __restrict__ vfrag,
    const float* __restrict__ pmask,
    const unsigned short* __restrict__ lepe,
    unsigned short* __restrict__ attn)
{
  __shared__ __align__(16) float smem[8][2048];
  const int lane = threadIdx.x & 63;
  const int wid  = threadIdx.x >> 6;          // 0..7
  const int c    = lane & 15, quad = lane >> 4;
  const int u    = blockIdx.x;               // 0..3199
  const int xcd  = u & 7;
  const int slot = u >> 3;                   // 0..399
  const int h    = slot & 7;
  const int p    = (slot >> 3) * 8 + xcd;    // 0..399 = b*200 + strip
  const int b    = p / 200;
  const int strip = p - b * 200;
  const int qrow = strip * 16 + c;
  const size_t bh = (size_t)(b * HEADS + h);

  const bf16x8 qf = *(const bf16x8*)(qws + (bh * SP + qrow) * HD + quad * 8);
  const unsigned short* kb = kws + bh * SP * HD;
  const unsigned short* vb = vfrag + bh * (size_t)(50 * 2048);
  const float* mpb = pmask + (size_t)(b * 200 + strip) * (50 * 1024);
  float* mt = &smem[wid][0];

  float l_run = 0.f;
  floatx4 o0 = (floatx4){0.f,0.f,0.f,0.f};
  floatx4 o1 = (floatx4){0.f,0.f,0.f,0.f};

  // tiles: wave w -> t = w*6 .. w*6+5; leftovers 48 -> wave0, 49 -> wave1
  // (tile 49's pad region carries lm=-1e30 -> p=0, so it's a NORMAL tile).
  const int tbase = wid * 6;
  const int nt = (wid < 2) ? 7 : 6;

  stage_pre(mpb + tbase * 1024, lane, mt);    // prologue -> buf0

  for (int it = 0; it < nt; ++it) {
    const int t = (it < 6) ? tbase + it : 48 + wid;
    if (it + 1 < nt) {
      const int tn = (it + 1 < 6) ? tbase + it + 1 : 48 + wid;
      stage_pre(mpb + tn * 1024, lane, mt + ((it + 1) & 1) * 1024);
      FENCE4();   // retire THIS tile's 4 staging loads; keep next 4 in flight
    } else {
      FENCE0();
    }
    proc_tile_pre(t, kb, vb, mt + (it & 1) * 1024, c, quad, lane, qf, o0, o1, l_run);
  }

  // ---- cross-wave reduction (smem reused: each wave writes only its region) ----
#pragma unroll
  for (int r = 0; r < 4; ++r) {
    smem[wid][lane * 9 + r]     = o0[r];
    smem[wid][lane * 9 + 4 + r] = o1[r];
  }
  smem[wid][lane * 9 + 8] = l_run;
  __syncthreads();

  if (wid == 0) {
#pragma unroll
    for (int w = 1; w < 8; ++w) {
#pragma unroll
      for (int r = 0; r < 4; ++r) {
        o0[r] += smem[w][lane * 9 + r];
        o1[r] += smem[w][lane * 9 + 4 + r];
      }
      l_run += smem[w][lane * 9 + 8];
    }
    l_run += __shfl_xor(l_run, 16);
    l_run += __shfl_xor(l_run, 32);
    const float rl = 1.f / l_run;

    if (qrow < S_LEN) {
      const size_t obase = ((size_t)b * S_LEN + qrow) * 256 + h * 32;
      const size_t lbase = (qrow >= 8) ? (((size_t)b * NPIX + (qrow - 8)) * 256 + h * 32) : 0;
#pragma unroll
      for (int mt2 = 0; mt2 < 2; ++mt2) {
        floatx4 ov = mt2 ? o1 : o0;
#pragma unroll
        for (int r = 0; r < 4; ++r) {
          const int d = mt2 * 16 + quad * 4 + r;
          float val = ov[r] * rl;
          if (qrow >= 8) val += bf2f(lepe[lbase + d]);
          attn[obase + d] = f2bf(val);
        }
      }
    }
  }
}

// ============ K3 (fallback, R3 verbatim): used when ws_size too small ============
template<bool TAIL>
static __device__ __forceinline__ void proc_tile_fb(
    int t, const unsigned short* __restrict__ kb,
    const unsigned short* __restrict__ vb,
    const float* __restrict__ mb,
    int c, int quad, int lane, const bf16x8 qf,
    floatx4& o0, floatx4& o1, float& l_run)
{
  const int k0 = t * 64;
  bf16x8 kf[4]; shortx4 v0[4], v1[4];
  const unsigned short* tb = vb + (size_t)t * 2048;
#pragma unroll
  for (int ct = 0; ct < 4; ++ct) {
    kf[ct] = *(const bf16x8*)(kb + (size_t)(k0 + ct * 16 + c) * HD + quad * 8);
    v0[ct] = *(const shortx4*)(tb + (ct * 2 + 0) * 256 + lane * 4);
    v1[ct] = *(const shortx4*)(tb + (ct * 2 + 1) * 256 + lane * 4);
  }
  floatx4 s[4];
#pragma unroll
  for (int ct = 0; ct < 4; ++ct)
    s[ct] = __builtin_amdgcn_mfma_f32_16x16x32_bf16(kf[ct], qf,
               (floatx4){0.f,0.f,0.f,0.f}, 0, 0, 0);
  float ls = 0.f;
  shortx4 pf[4];
#pragma unroll
  for (int ct = 0; ct < 4; ++ct) {
    const float4 mv = *(const float4*)(mb + c * 64 + (((ct * 4 + quad) ^ c) * 4));
    float pr[4];
    pr[0] = (mv.x + 1e-6f) * __builtin_amdgcn_exp2f(s[ct][0]);
    pr[1] = (mv.y + 1e-6f) * __builtin_amdgcn_exp2f(s[ct][1]);
    pr[2] = (mv.z + 1e-6f) * __builtin_amdgcn_exp2f(s[ct][2]);
    pr[3] = (mv.w + 1e-6f) * __builtin_amdgcn_exp2f(s[ct][3]);
    if (TAIL) {
      const int kk = k0 + ct * 16 + quad * 4;
#pragma unroll
      for (int r = 0; r < 4; ++r) if (kk + r >= S_LEN) pr[r] = 0.f;
    }
    ls += (pr[0] + pr[1]) + (pr[2] + pr[3]);
    union { bf16x4 b4; shortx4 s4; } u;
    u.b4[0]=(__bf16)pr[0]; u.b4[1]=(__bf16)pr[1]; u.b4[2]=(__bf16)pr[2]; u.b4[3]=(__bf16)pr[3];
    pf[ct] = u.s4;
  }
  l_run += ls;
#pragma unroll
  for (int ct = 0; ct < 4; ++ct) {
    o0 = __builtin_amdgcn_mfma_f32_16x16x16bf16_1k(v0[ct], pf[ct], o0, 0, 0, 0);
    o1 = __builtin_amdgcn_mfma_f32_16x16x16bf16_1k(v1[ct], pf[ct], o1, 0, 0, 0);
  }
}

static __device__ __forceinline__ void stage_mask_fb(
    const float* const (&msrc)[4], const int (&goff4)[4], int k0, float* dst)
{
#pragma unroll
  for (int i = 0; i < 4; ++i)
    gload_lds16(msrc[i] + (k0 + goff4[i]), dst + i * 256);
}

static __device__ __forceinline__ void stage_mask_tail_fb(
    const float* const (&msrc)[4], const int (&goff4)[4], int k0, float* dst)
{
#pragma unroll
  for (int i = 0; i < 4; ++i) {
    int kk = k0 + goff4[i];
    if (kk > S_LEN - 4) kk = S_LEN - 4;
    gload_lds16(msrc[i] + kk, dst + i * 256);
  }
}

__global__ __launch_bounds__(512) void k_flash_fb(
    const unsigned short* __restrict__ qws,
    const unsigned short* __restrict__ kws,
    const unsigned short* __restrict__ vfrag,
    const float* __restrict__ mask,
    const unsigned short* __restrict__ lepe,
    unsigned short* __restrict__ attn)
{
  __shared__ __align__(16) float smem[8][2048];
  const int lane = threadIdx.x & 63;
  const int wid  = threadIdx.x >> 6;
  const int c    = lane & 15, quad = lane >> 4;
  const int u    = blockIdx.x;
  const int xcd  = u & 7;
  const int slot = u >> 3;
  const int h    = slot & 7;
  const int p    = (slot >> 3) * 8 + xcd;
  const int b    = p / 200;
  const int strip = p - b * 200;
  const int qrow = strip * 16 + c;
  const size_t bh = (size_t)(b * HEADS + h);

  const bf16x8 qf = *(const bf16x8*)(qws + (bh * SP + qrow) * HD + quad * 8);
  const unsigned short* kb = kws + bh * SP * HD;
  const unsigned short* vb = vfrag + bh * (size_t)(50 * 2048);
  float* mt = &smem[wid][0];

  const float* msrc[4];
  int goff4[4];
#pragma unroll
  for (int i = 0; i < 4; ++i) {
    const int rq = i * 4 + (lane >> 4);
    int mr = strip * 16 + rq; if (mr >= S_LEN) mr = S_LEN - 1;
    msrc[i] = mask + ((size_t)b * S_LEN + mr) * S_LEN;
    goff4[i] = ((lane & 15) ^ rq) * 4;
  }

  float l_run = 0.f;
  floatx4 o0 = (floatx4){0.f,0.f,0.f,0.f};
  floatx4 o1 = (floatx4){0.f,0.f,0.f,0.f};

  const int tbase = wid * 6;
  const int nt = (wid < 2) ? 7 : 6;

  stage_mask_fb(msrc, goff4, tbase * 64, mt);

  for (int it = 0; it < nt; ++it) {
    const int t = (it < 6) ? tbase + it : 48 + wid;
    if (it + 1 < nt) {
      const int tn = (it + 1 < 6) ? tbase + it + 1 : 48 + wid;
      float* dst = mt + ((it + 1) & 1) * 1024;
      if (tn == 49) stage_mask_tail_fb(msrc, goff4, 49 * 64, dst);
      else          stage_mask_fb(msrc, goff4, tn * 64, dst);
      FENCE4();
    } else {
      FENCE0();
    }
    const float* mb = mt + (it & 1) * 1024;
    if (wid == 1 && it == 6)
      proc_tile_fb<true >(t, kb, vb, mb, c, quad, lane, qf, o0, o1, l_run);
    else
      proc_tile_fb<false>(t, kb, vb, mb, c, quad, lane, qf, o0, o1, l_run);
  }

#pragma unroll
  for (int r = 0; r < 4; ++r) {
    smem[wid][lane * 9 + r]     = o0[r];
    smem[wid][lane * 9 + 4 + r] = o1[r];
  }
  smem[wid][lane * 9 + 8] = l_run;
  __syncthreads();

  if (wid == 0) {
#pragma unroll
    for (int w = 1; w < 8; ++w) {
#pragma unroll
      for (int r = 0; r < 4; ++r) {
        o0[r] += smem[w][lane * 9 + r];
        o1[r] += smem[w][lane * 9 + 4 + r];
      }
      l_run += smem[w][lane * 9 + 8];
    }
    l_run += __shfl_xor(l_run, 16);
    l_run += __shfl_xor(l_run, 32);
    const float rl = 1.f / l_run;

    if (qrow < S_LEN) {
      const size_t obase = ((size_t)b * S_LEN + qrow) * 256 + h * 32;
      const size_t lbase = (qrow >= 8) ? (((size_t)b * NPIX + (qrow - 8)) * 256 + h * 32) : 0;
#pragma unroll
      for (int mt2 = 0; mt2 < 2; ++mt2) {
        floatx4 ov = mt2 ? o1 : o0;
#pragma unroll
        for (int r = 0; r < 4; ++r) {
          const int d = mt2 * 16 + quad * 4 + r;
          float val = ov[r] * rl;
          if (qrow >= 8) val += bf2f(lepe[lbase + d]);
          attn[obase + d] = f2bf(val);
        }
      }
    }
  }
}

// ---------------- K4: output projection (attn bf16, wo/bo f32 -> f32 out) ----------------
__global__ __launch_bounds__(256) void k_oproj(
    const unsigned short* __restrict__ attn,
    const float* __restrict__ wop,
    const float* __restrict__ bop,
    float* __restrict__ out)
{
  const int lane = threadIdx.x & 63;
  const int wid  = threadIdx.x >> 6;
  const int c = lane & 15, quad = lane >> 4;
  const int row0 = blockIdx.x * 64 + wid * 16;
  const int col0 = blockIdx.y * 64;

  int arow = row0 + c; if (arow >= MROWS) arow = 0;
  const unsigned short* ap = attn + (size_t)arow * 256 + quad * 8;
  const float* bp = wop + (size_t)(col0 + c) * 256 + quad * 8;

  floatx4 acc[4];
#pragma unroll
  for (int ct = 0; ct < 4; ++ct) acc[ct] = (floatx4){0.f,0.f,0.f,0.f};
#pragma unroll
  for (int ks = 0; ks < 8; ++ks) {
    bf16x8 af = *(const bf16x8*)(ap + ks * 32);
#pragma unroll
    for (int ct = 0; ct < 4; ++ct) {
      bf16x8 bf = ldcvt8(bp + (size_t)ct * 16 * 256 + ks * 32);
      acc[ct] = __builtin_amdgcn_mfma_f32_16x16x32_bf16(af, bf, acc[ct], 0, 0, 0);
    }
  }
#pragma unroll
  for (int ct = 0; ct < 4; ++ct) {
    const int col = col0 + ct * 16 + c;
    const float bias = bop[col];
#pragma unroll
    for (int r = 0; r < 4; ++r) {
      const int row = row0 + quad * 4 + r;
      if (row >= MROWS) continue;
      out[(size_t)row * 256 + col] = acc[ct][r] + bias;
    }
  }
}

// ---------------- workspace layout (bytes) ----------------
#define QW_OFF 0u                        // 2*8*3200*32*2 = 3,276,800
#define KW_OFF 3276800u
#define VF_OFF 6553600u                  // vfrag, 3,276,800
#define LE_OFF 9830400u                  // w3b (384KB) until k_lepe overwrites with lepe
#define AT_OFF 13041664u                 // 6288*256*2    = 3,219,456
#define PM_OFF 16261120u                 // relayouted mask: 400*50*4096 = 81,920,000
#define PM_NEED (16261120u + 81920000u)  // 98,181,120

extern "C" void kernel_launch(void* const* d_in, const int* in_sizes, int n_in,
                              void* d_out, int out_size, void* d_ws, size_t ws_size,
                              hipStream_t stream) {
  const float* x    = (const float*)d_in[0];
  const float* mask = (const float*)d_in[1];
  const float* wq   = (const float*)d_in[2];
  const float* bq   = (const float*)d_in[3];
  const float* wk   = (const float*)d_in[4];
  const float* bk   = (const float*)d_in[5];
  const float* wv   = (const float*)d_in[6];
  const float* bv   = (const float*)d_in[7];
  const float* lw   = (const float*)d_in[8];
  const float* lb   = (const float*)d_in[9];
  const float* wo   = (const float*)d_in[10];
  const float* bo   = (const float*)d_in[11];

  char* ws = (char*)d_ws;
  unsigned short* qws = (unsigned short*)(ws + QW_OFF);
  unsigned short* kws = (unsigned short*)(ws + KW_OFF);
  unsigned short* vfr = (unsigned short*)(ws + VF_OFF);
  unsigned short* w3b = (unsigned short*)(ws + LE_OFF);   // dead before k_lepe
  unsigned short* lpe = (unsigned short*)(ws + LE_OFF);
  unsigned short* atb = (unsigned short*)(ws + AT_OFF);
  unsigned short* vst = (unsigned short*)d_out;             // low 3.22MB of d_out
  unsigned short* xb  = (unsigned short*)d_out + 1609728;   // high 3.22MB of d_out
  float*          outf = (float*)d_out;

  const bool use_pre = (ws_size >= (size_t)PM_NEED);

  k_cvt<<<882, 256, 0, stream>>>(x, wq, wk, wv, xb, w3b);
  if (use_pre) {
    float* pm = (float*)(ws + PM_OFF);
    k_mprep<<<dim3(400, 5), 256, 0, stream>>>(mask, pm);
    k_qkv<<<dim3(100, 12), 256, 0, stream>>>(xb, w3b, bq, bk, bv, qws, kws, vfr, vst);
    k_lepe<<<784, 256, 0, stream>>>(vst, lw, lb, lpe);
    k_flash_pre<<<3200, 512, 0, stream>>>(qws, kws, vfr, pm, lpe, atb);
  } else {
    k_qkv<<<dim3(100, 12), 256, 0, stream>>>(xb, w3b, bq, bk, bv, qws, kws, vfr, vst);
    k_lepe<<<784, 256, 0, stream>>>(vst, lw, lb, lpe);
    k_flash_fb<<<3200, 512, 0, stream>>>(qws, kws, vfr, mask, lpe, atb);
  }
  k_oproj<<<dim3(99, 4), 256, 0, stream>>>(atb, wo, bo, outf);
}

// Round 7
// 312.246 us; speedup vs baseline: 1.1079x; 1.0464x over previous
//
#include <hip/hip_runtime.h>

// MaskAttention: B=2,S=3144,C=256,H=8,HD=32, mask-softmax attention with vh=kh,
// LePE 5x5 depthwise conv on v[:,8:], output projection.
// I/O: ALL float32. Internal: bf16 MFMA, f32 accum.
//
// softmax(qk + log(m+eps)) == normalize((m+eps)*exp(qk)); |qk| tiny -> fixed
// shift M=0, no online max; k-range partials additive => split-K.
//
// R7 changes vs R6 (k_flash_pre 122us, Occupancy 22% = ~7 waves/CU, latency-bound):
//  - pm stored as fp16 (m+1e-6), multiply form: mask HBM 82->41MB, and per-wave
//    LDS mask dbuf 8KB->4KB => block LDS 64->32KB => blocks/CU 2->3-4
//    (waves/CU ~16 -> 24-32). Stage = 2 global_load_lds per tile, vmcnt(2).
//  - fp16 error budget: delta(m)/m <= 2^-11 -> |delta out| ~1.5e-5, noise vs
//    the stable 9.77e-4 absmax. S_LEN%8==0 -> pad granules exactly 0 -> tail
//    P=0 with no TAIL path.
//  - pm layout bakes XOR swizzle at 8B granules: dest granule d of row r holds
//    source granule d^r -> 8B LDS readback bank-spread, staging contiguous.
//  - k_mprep rewritten for the fp16 packed layout (writes halved, ~24us).
//  - everything else (k_cvt/k_qkv/k_lepe/k_oproj, R3-fallback) unchanged.

#define S_LEN 3144
#define SP    3200            // S padded to 64 (50 k-tiles; 0..48 fully valid)
#define HEADS 8
#define HD    32
#define BATCH 2
#define MROWS (BATCH*S_LEN)   // 6288
#define NPIX  3136            // 56*56
#define SCALE_F 0.17677669529663687f   // 32^-0.5
#define KQ_SC   0.25504472665352026f   // SCALE_F * log2(e)

typedef __bf16 bf16x8  __attribute__((ext_vector_type(8)));
typedef __bf16 bf16x4  __attribute__((ext_vector_type(4)));
typedef float  floatx4 __attribute__((ext_vector_type(4)));
typedef short  shortx4 __attribute__((ext_vector_type(4)));
typedef _Float16 halfx4 __attribute__((ext_vector_type(4)));
typedef _Float16 halfx8 __attribute__((ext_vector_type(8)));

static __device__ __forceinline__ float bf2f(unsigned int h) {
  union { unsigned int u; float f; } v; v.u = h << 16; return v.f;
}
static __device__ __forceinline__ unsigned short f2bf(float f) {
  union { __bf16 b; unsigned short u; } v; v.b = (__bf16)f; return v.u;
}
static __device__ __forceinline__ bf16x8 ldcvt8(const float* __restrict__ p) {
  float4 a = *(const float4*)p;
  float4 b = *(const float4*)(p + 4);
  bf16x8 r;
  r[0]=(__bf16)a.x; r[1]=(__bf16)a.y; r[2]=(__bf16)a.z; r[3]=(__bf16)a.w;
  r[4]=(__bf16)b.x; r[5]=(__bf16)b.y; r[6]=(__bf16)b.z; r[7]=(__bf16)b.w;
  return r;
}

#define GLOBAL_AS __attribute__((address_space(1)))
#define LDS_AS    __attribute__((address_space(3)))
static __device__ __forceinline__ void gload_lds16(const void* g, void* l) {
  __builtin_amdgcn_global_load_lds((const GLOBAL_AS void*)g, (LDS_AS void*)l, 16, 0, 0);
}

#define FENCE4() asm volatile("s_waitcnt vmcnt(4)" ::: "memory")
#define FENCE2() asm volatile("s_waitcnt vmcnt(2)" ::: "memory")
#define FENCE0() asm volatile("s_waitcnt vmcnt(0)" ::: "memory")

// ---------------- K0: one-time f32 -> bf16 conversion (x, wq, wk, wv) ----------------
__global__ __launch_bounds__(256) void k_cvt(
    const float* __restrict__ x, const float* __restrict__ wq,
    const float* __restrict__ wk, const float* __restrict__ wv,
    unsigned short* __restrict__ xb, unsigned short* __restrict__ w3b)
{
  const int i = blockIdx.x * 256 + threadIdx.x;   // unit of 8 floats
  const int NX = MROWS * 32;                      // 201216
  const int NW = 8192;                            // 65536/8
  const float* src;
  unsigned short* dst;
  if (i < NX) { src = x + (size_t)i * 8; dst = xb + (size_t)i * 8; }
  else {
    const int j = i - NX;
    if (j >= 3 * NW) return;
    src = (j < NW) ? wq + (size_t)j * 8
        : (j < 2 * NW) ? wk + (size_t)(j - NW) * 8
                       : wv + (size_t)(j - 2 * NW) * 8;
    dst = w3b + (size_t)j * 8;
  }
  bf16x8 v = ldcvt8(src);
  *(bf16x8*)dst = v;
}

// ---------------- K0b: mask relayout prepass (fp16, packed+swizzled) ----------------
// pm tile block = 16 rows x 64 cols fp16 = 2KB, laid out so the LINEAR
// global_load_lds staging (2 instrs x 64 lanes x 16B) lands as:
//   LDS 8B-granule d of row r  =  fp16(mask_row[granule d^r] + 1e-6)
// Dest 16B unit n (0..127): row = n>>3, dest granules {2k, 2k+1} (k=n&7),
// source granules {(2k)^r, (2k+1)^r} = one contiguous 8-float block, possibly
// internally swapped (when r is odd). Pad cols (>= S_LEN) store 0 -> P=0.
__global__ __launch_bounds__(256) void k_mprep(const float* __restrict__ mask,
                                               _Float16* __restrict__ pm)
{
  const int bs = blockIdx.x;            // 0..399 = b*200 + strip
  const int b  = bs / 200, strip = bs % 200;
  const int t  = threadIdx.x;
  const int n  = t & 127;               // 16B dest unit within tile
  const int tsel = t >> 7;              // 2 tiles per iteration
  const int row = n >> 3;               // 0..15
  const int k2  = n & 7;                // dest granule pair index
  const int g0  = (2 * k2) ^ (row & 15);
  const int gbase = g0 & ~1;            // contiguous source block of 8 floats
  const bool swp = (g0 & 1);            // row odd -> dest order swapped

  int mr = strip * 16 + row; if (mr >= S_LEN) mr = S_LEN - 1;
  const float* src = mask + ((size_t)b * S_LEN + mr) * S_LEN;
  _Float16* dst0 = pm + ((size_t)bs * 50) * 1024 + n * 8;

#pragma unroll 1
  for (int tt = 0; tt < 5; ++tt) {
    const int tile = blockIdx.y * 10 + tt * 2 + tsel;
    const int c0 = tile * 64 + gbase * 4;      // multiple of 8; S_LEN%8==0
    float4 a = make_float4(-1e-6f, -1e-6f, -1e-6f, -1e-6f);
    float4 c = a;
    if (c0 < S_LEN) {
      a = *(const float4*)(src + c0);
      c = *(const float4*)(src + c0 + 4);
    }
    const float4 fst = swp ? c : a;
    const float4 snd = swp ? a : c;
    halfx8 o;
    o[0] = (_Float16)(fst.x + 1e-6f); o[1] = (_Float16)(fst.y + 1e-6f);
    o[2] = (_Float16)(fst.z + 1e-6f); o[3] = (_Float16)(fst.w + 1e-6f);
    o[4] = (_Float16)(snd.x + 1e-6f); o[5] = (_Float16)(snd.y + 1e-6f);
    o[6] = (_Float16)(snd.z + 1e-6f); o[7] = (_Float16)(snd.w + 1e-6f);
    *(halfx8*)(dst0 + (size_t)tile * 1024) = o;
  }
}

// ---------------- K1: fused q/k/v projection (bf16 in -> bf16 out) ----------------
// Grid (100, 12): blockIdx.x = bsel*50 + stile. Pad rows (s>=S_LEN) store 0.
__global__ __launch_bounds__(256) void k_qkv(
    const unsigned short* __restrict__ xb, const unsigned short* __restrict__ w3b,
    const float* __restrict__ bqp, const float* __restrict__ bkp,
    const float* __restrict__ bvp,
    unsigned short* __restrict__ qws, unsigned short* __restrict__ kws,
    unsigned short* __restrict__ vfrag, unsigned short* __restrict__ vstage)
{
  __shared__ unsigned short lds_t[64 * 65];   // transpose staging (k blocks only)
  const int lane = threadIdx.x & 63;
  const int wid  = threadIdx.x >> 6;
  const int c    = lane & 15, quad = lane >> 4;
  const int bsel  = blockIdx.x / 50;
  const int stile = blockIdx.x % 50;
  const int srow0 = stile * 64;
  const int ncol = blockIdx.y * 64;           // 0..767
  const int wsel = ncol >> 8;
  const int col0 = ncol & 255;

  const float* bptr = (wsel == 0) ? bqp : (wsel == 1) ? bkp : bvp;

  const int srow = srow0 + wid * 16 + c;
  const int arow = bsel * S_LEN + ((srow < S_LEN) ? srow : 0);  // clamp pad rows
  const unsigned short* ap = xb  + (size_t)arow * 256 + quad * 8;
  const unsigned short* bp = w3b + (size_t)(ncol + c) * 256 + quad * 8;

  floatx4 acc[4];
#pragma unroll
  for (int ct = 0; ct < 4; ++ct) acc[ct] = (floatx4){0.f, 0.f, 0.f, 0.f};

#pragma unroll
  for (int ks = 0; ks < 8; ++ks) {
    bf16x8 af = *(const bf16x8*)(ap + ks * 32);
#pragma unroll
    for (int ct = 0; ct < 4; ++ct) {
      bf16x8 bf = *(const bf16x8*)(bp + (size_t)ct * 16 * 256 + ks * 32);
      acc[ct] = __builtin_amdgcn_mfma_f32_16x16x32_bf16(af, bf, acc[ct], 0, 0, 0);
    }
  }

#pragma unroll
  for (int ct = 0; ct < 4; ++ct) {
    const int col = col0 + ct * 16 + c;
    const float bias = bptr[col];
#pragma unroll
    for (int r = 0; r < 4; ++r) {
      const int s = srow0 + wid * 16 + quad * 4 + r;   // 0..3199 within batch
      const int valid = (s < S_LEN);
      const float v = acc[ct][r] + bias;
      if (wsel == 0) {
        qws[(((size_t)(bsel * HEADS + (col >> 5))) * SP + s) * HD + (col & 31)] =
            valid ? f2bf(v) : (unsigned short)0;
      } else if (wsel == 1) {
        // QK-side copy carries log2e; V-side copy (lds_t->vfrag) does NOT.
        kws[(((size_t)(bsel * HEADS + (col >> 5))) * SP + s) * HD + (col & 31)] =
            valid ? f2bf(v * KQ_SC) : (unsigned short)0;
        lds_t[(ct * 16 + c) * 65 + (wid * 16 + quad * 4 + r)] =
            valid ? f2bf(v * SCALE_F) : (unsigned short)0;
      } else {
        if (valid) vstage[(size_t)(bsel * S_LEN + s) * 256 + col] = f2bf(v);
      }
    }
  }

  if (wsel == 1) {
    // vfrag: PV A-operand fragments in exact MFMA lane order.
    __syncthreads();
    const int tid = threadIdx.x;
#pragma unroll
    for (int j = 0; j < 4; ++j) {
      const int grp  = j * 4 + (tid >> 6);   // 0..15, wave-uniform
      const int l    = tid & 63;
      const int ct2  = grp & 3;
      const int half = (grp >> 2) & 1;
      const int hsel = grp >> 3;
      const int cc = l & 15, qq = l >> 4;
      const int cl = hsel * 32 + half * 16 + cc;
      const int rb = ct2 * 16 + qq * 4;
      union { shortx4 s4; unsigned short u[4]; } pk;
#pragma unroll
      for (int e = 0; e < 4; ++e) pk.u[e] = lds_t[cl * 65 + rb + e];
      const int hglob = (col0 >> 5) + hsel;
      const size_t off =
          ((((size_t)(bsel * HEADS + hglob) * 50 + stile) * 4 + ct2) * 2 + half) * 64 + l;
      *(shortx4*)(vfrag + off * 4) = pk.s4;
    }
  }
}

// ---------------- K2: LePE 5x5 depthwise conv on v[:,8:] ----------------
__global__ __launch_bounds__(256) void k_lepe(const unsigned short* __restrict__ vws,
                                              const float* __restrict__ cw,
                                              const float* __restrict__ cb,
                                              unsigned short* __restrict__ lepe)
{
  int idx = blockIdx.x * 256 + threadIdx.x;
  if (idx >= BATCH * NPIX * 32) return;
  const int cg = idx & 31;
  const int p  = (idx >> 5) % NPIX;
  const int b  = idx / (NPIX * 32);
  const int y  = p / 56, xx = p - y * 56;

  float acc[8];
  {
    float4 b0 = *(const float4*)(cb + cg * 8);
    float4 b1 = *(const float4*)(cb + cg * 8 + 4);
    acc[0]=b0.x; acc[1]=b0.y; acc[2]=b0.z; acc[3]=b0.w;
    acc[4]=b1.x; acc[5]=b1.y; acc[6]=b1.z; acc[7]=b1.w;
  }
#pragma unroll
  for (int dy = -2; dy <= 2; ++dy) {
    const int yy = y + dy;
    if ((unsigned)yy >= 56u) continue;
#pragma unroll
    for (int dx = -2; dx <= 2; ++dx) {
      const int xs = xx + dx;
      if ((unsigned)xs >= 56u) continue;
      uint4 vv = *(const uint4*)(vws + (size_t)(b * S_LEN + 8 + yy * 56 + xs) * 256 + cg * 8);
      const float* wp = cw + (size_t)((dy + 2) * 5 + (dx + 2)) * 256 + cg * 8;
      float4 w0 = *(const float4*)wp;
      float4 w1 = *(const float4*)(wp + 4);
      unsigned int va[4] = {vv.x, vv.y, vv.z, vv.w};
      acc[0] += bf2f(va[0] & 0xFFFFu) * w0.x;  acc[1] += bf2f(va[0] >> 16) * w0.y;
      acc[2] += bf2f(va[1] & 0xFFFFu) * w0.z;  acc[3] += bf2f(va[1] >> 16) * w0.w;
      acc[4] += bf2f(va[2] & 0xFFFFu) * w1.x;  acc[5] += bf2f(va[2] >> 16) * w1.y;
      acc[6] += bf2f(va[3] & 0xFFFFu) * w1.z;  acc[7] += bf2f(va[3] >> 16) * w1.w;
    }
  }
  unsigned int o[4];
#pragma unroll
  for (int j = 0; j < 4; ++j)
    o[j] = (unsigned int)f2bf(acc[2*j]) | ((unsigned int)f2bf(acc[2*j+1]) << 16);
  *((uint4*)(lepe + (size_t)(b * NPIX + p) * 256 + cg * 8)) = make_uint4(o[0], o[1], o[2], o[3]);
}

// ============ K3 (pre path): flash attention, fp16 relayouted mask ============
static __device__ __forceinline__ void proc_tile_pre(
    int t, const unsigned short* __restrict__ kb,
    const unsigned short* __restrict__ vb,
    const _Float16* __restrict__ mb,
    int c, int quad, int lane, const bf16x8 qf,
    floatx4& o0, floatx4& o1, float& l_run)
{
  const int k0 = t * 64;
  bf16x8 kf[4]; shortx4 v0[4], v1[4];
  const unsigned short* tb = vb + (size_t)t * 2048;
#pragma unroll
  for (int ct = 0; ct < 4; ++ct) {
    kf[ct] = *(const bf16x8*)(kb + (size_t)(k0 + ct * 16 + c) * HD + quad * 8);
    v0[ct] = *(const shortx4*)(tb + (ct * 2 + 0) * 256 + lane * 4);
    v1[ct] = *(const shortx4*)(tb + (ct * 2 + 1) * 256 + lane * 4);
  }
  floatx4 s[4];
#pragma unroll
  for (int ct = 0; ct < 4; ++ct)
    s[ct] = __builtin_amdgcn_mfma_f32_16x16x32_bf16(kf[ct], qf,
               (floatx4){0.f,0.f,0.f,0.f}, 0, 0, 0);
  float ls = 0.f;
  shortx4 pf[4];
#pragma unroll
  for (int ct = 0; ct < 4; ++ct) {
    // LDS 8B-granule d of row c holds source granule d^c -> read d=(ct*4+quad)^c
    const halfx4 mv = *(const halfx4*)(mb + c * 64 + (((ct * 4 + quad) ^ c) * 4));
    float pr[4];
    pr[0] = (float)mv[0] * __builtin_amdgcn_exp2f(s[ct][0]);
    pr[1] = (float)mv[1] * __builtin_amdgcn_exp2f(s[ct][1]);
    pr[2] = (float)mv[2] * __builtin_amdgcn_exp2f(s[ct][2]);
    pr[3] = (float)mv[3] * __builtin_amdgcn_exp2f(s[ct][3]);
    ls += (pr[0] + pr[1]) + (pr[2] + pr[3]);
    union { bf16x4 b4; shortx4 s4; } u;
    u.b4[0]=(__bf16)pr[0]; u.b4[1]=(__bf16)pr[1]; u.b4[2]=(__bf16)pr[2]; u.b4[3]=(__bf16)pr[3];
    pf[ct] = u.s4;
  }
  l_run += ls;
#pragma unroll
  for (int ct = 0; ct < 4; ++ct) {
    o0 = __builtin_amdgcn_mfma_f32_16x16x16bf16_1k(v0[ct], pf[ct], o0, 0, 0, 0);
    o1 = __builtin_amdgcn_mfma_f32_16x16x16bf16_1k(v1[ct], pf[ct], o1, 0, 0, 0);
  }
}

static __device__ __forceinline__ void stage_pre(
    const _Float16* __restrict__ mp_t, int lane, _Float16* dst)
{
#pragma unroll
  for (int i = 0; i < 2; ++i)   // 2 x (64 lanes x 16B) = 2KB tile, contiguous
    gload_lds16(mp_t + i * 512 + lane * 8, dst + i * 512);
}

__global__ __launch_bounds__(512) void k_flash_pre(
    const unsigned short* __restrict__ qws,
    const unsigned short* __restrict__ kws,
    const unsigned short* __restrict__ vfrag,
    const _Float16* __restrict__ pmask,
    const unsigned short* __restrict__ lepe,
    unsigned short* __restrict__ attn)
{
  // Per-wave 4KB region: 2 x 2KB fp16 mask dbuf during the loop; first 576
  // floats reused as reduction scratch AFTER the wave's loop. Total 32KB.
  __shared__ __align__(16) float smem[8][1024];
  const int lane = threadIdx.x & 63;
  const int wid  = threadIdx.x >> 6;          // 0..7
  const int c    = lane & 15, quad = lane >> 4;
  const int u    = blockIdx.x;               // 0..3199
  const int xcd  = u & 7;
  const int slot = u >> 3;                   // 0..399
  const int h    = slot & 7;
  const int p    = (slot >> 3) * 8 + xcd;    // 0..399 = b*200 + strip
  const int b    = p / 200;
  const int strip = p - b * 200;
  const int qrow = strip * 16 + c;
  const size_t bh = (size_t)(b * HEADS + h);

  const bf16x8 qf = *(const bf16x8*)(qws + (bh * SP + qrow) * HD + quad * 8);
  const unsigned short* kb = kws + bh * SP * HD;
  const unsigned short* vb = vfrag + bh * (size_t)(50 * 2048);
  const _Float16* mpb = pmask + (size_t)(b * 200 + strip) * (50 * 1024);
  _Float16* mt = (_Float16*)&smem[wid][0];

  float l_run = 0.f;
  floatx4 o0 = (floatx4){0.f,0.f,0.f,0.f};
  floatx4 o1 = (floatx4){0.f,0.f,0.f,0.f};

  // tiles: wave w -> t = w*6 .. w*6+5; leftovers 48 -> wave0, 49 -> wave1
  // (tile 49's pad cols carry hm=0 -> P=0, so it's a NORMAL tile).
  const int tbase = wid * 6;
  const int nt = (wid < 2) ? 7 : 6;

  stage_pre(mpb + tbase * 1024, lane, mt);    // prologue -> buf0

  for (int it = 0; it < nt; ++it) {
    const int t = (it < 6) ? tbase + it : 48 + wid;
    if (it + 1 < nt) {
      const int tn = (it + 1 < 6) ? tbase + it + 1 : 48 + wid;
      stage_pre(mpb + tn * 1024, lane, mt + ((it + 1) & 1) * 1024);
      FENCE2();   // retire THIS tile's 2 staging loads; keep next 2 in flight
    } else {
      FENCE0();
    }
    proc_tile_pre(t, kb, vb, mt + (it & 1) * 1024, c, quad, lane, qf, o0, o1, l_run);
  }

  // ---- cross-wave reduction (smem reused: each wave writes only its region) ----
#pragma unroll
  for (int r = 0; r < 4; ++r) {
    smem[wid][lane * 9 + r]     = o0[r];
    smem[wid][lane * 9 + 4 + r] = o1[r];
  }
  smem[wid][lane * 9 + 8] = l_run;
  __syncthreads();

  if (wid == 0) {
#pragma unroll
    for (int w = 1; w < 8; ++w) {
#pragma unroll
      for (int r = 0; r < 4; ++r) {
        o0[r] += smem[w][lane * 9 + r];
        o1[r] += smem[w][lane * 9 + 4 + r];
      }
      l_run += smem[w][lane * 9 + 8];
    }
    l_run += __shfl_xor(l_run, 16);
    l_run += __shfl_xor(l_run, 32);
    const float rl = 1.f / l_run;

    if (qrow < S_LEN) {
      const size_t obase = ((size_t)b * S_LEN + qrow) * 256 + h * 32;
      const size_t lbase = (qrow >= 8) ? (((size_t)b * NPIX + (qrow - 8)) * 256 + h * 32) : 0;
#pragma unroll
      for (int mt2 = 0; mt2 < 2; ++mt2) {
        floatx4 ov = mt2 ? o1 : o0;
#pragma unroll
        for (int r = 0; r < 4; ++r) {
          const int d = mt2 * 16 + quad * 4 + r;
          float val = ov[r] * rl;
          if (qrow >= 8) val += bf2f(lepe[lbase + d]);
          attn[obase + d] = f2bf(val);
        }
      }
    }
  }
}

// ============ K3 (fallback, R3 verbatim): used when ws_size too small ============
template<bool TAIL>
static __device__ __forceinline__ void proc_tile_fb(
    int t, const unsigned short* __restrict__ kb,
    const unsigned short* __restrict__ vb,
    const float* __restrict__ mb,
    int c, int quad, int lane, const bf16x8 qf,
    floatx4& o0, floatx4& o1, float& l_run)
{
  const int k0 = t * 64;
  bf16x8 kf[4]; shortx4 v0[4], v1[4];
  const unsigned short* tb = vb + (size_t)t * 2048;
#pragma unroll
  for (int ct = 0; ct < 4; ++ct) {
    kf[ct] = *(const bf16x8*)(kb + (size_t)(k0 + ct * 16 + c) * HD + quad * 8);
    v0[ct] = *(const shortx4*)(tb + (ct * 2 + 0) * 256 + lane * 4);
    v1[ct] = *(const shortx4*)(tb + (ct * 2 + 1) * 256 + lane * 4);
  }
  floatx4 s[4];
#pragma unroll
  for (int ct = 0; ct < 4; ++ct)
    s[ct] = __builtin_amdgcn_mfma_f32_16x16x32_bf16(kf[ct], qf,
               (floatx4){0.f,0.f,0.f,0.f}, 0, 0, 0);
  float ls = 0.f;
  shortx4 pf[4];
#pragma unroll
  for (int ct = 0; ct < 4; ++ct) {
    const float4 mv = *(const float4*)(mb + c * 64 + (((ct * 4 + quad) ^ c) * 4));
    float pr[4];
    pr[0] = (mv.x + 1e-6f) * __builtin_amdgcn_exp2f(s[ct][0]);
    pr[1] = (mv.y + 1e-6f) * __builtin_amdgcn_exp2f(s[ct][1]);
    pr[2] = (mv.z + 1e-6f) * __builtin_amdgcn_exp2f(s[ct][2]);
    pr[3] = (mv.w + 1e-6f) * __builtin_amdgcn_exp2f(s[ct][3]);
    if (TAIL) {
      const int kk = k0 + ct * 16 + quad * 4;
#pragma unroll
      for (int r = 0; r < 4; ++r) if (kk + r >= S_LEN) pr[r] = 0.f;
    }
    ls += (pr[0] + pr[1]) + (pr[2] + pr[3]);
    union { bf16x4 b4; shortx4 s4; } u;
    u.b4[0]=(__bf16)pr[0]; u.b4[1]=(__bf16)pr[1]; u.b4[2]=(__bf16)pr[2]; u.b4[3]=(__bf16)pr[3];
    pf[ct] = u.s4;
  }
  l_run += ls;
#pragma unroll
  for (int ct = 0; ct < 4; ++ct) {
    o0 = __builtin_amdgcn_mfma_f32_16x16x16bf16_1k(v0[ct], pf[ct], o0, 0, 0, 0);
    o1 = __builtin_amdgcn_mfma_f32_16x16x16bf16_1k(v1[ct], pf[ct], o1, 0, 0, 0);
  }
}

static __device__ __forceinline__ void stage_mask_fb(
    const float* const (&msrc)[4], const int (&goff4)[4], int k0, float* dst)
{
#pragma unroll
  for (int i = 0; i < 4; ++i)
    gload_lds16(msrc[i] + (k0 + goff4[i]), dst + i * 256);
}

static __device__ __forceinline__ void stage_mask_tail_fb(
    const float* const (&msrc)[4], const int (&goff4)[4], int k0, float* dst)
{
#pragma unroll
  for (int i = 0; i < 4; ++i) {
    int kk = k0 + goff4[i];
    if (kk > S_LEN - 4) kk = S_LEN - 4;
    gload_lds16(msrc[i] + kk, dst + i * 256);
  }
}

__global__ __launch_bounds__(512) void k_flash_fb(
    const unsigned short* __restrict__ qws,
    const unsigned short* __restrict__ kws,
    const unsigned short* __restrict__ vfrag,
    const float* __restrict__ mask,
    const unsigned short* __restrict__ lepe,
    unsigned short* __restrict__ attn)
{
  __shared__ __align__(16) float smem[8][2048];
  const int lane = threadIdx.x & 63;
  const int wid  = threadIdx.x >> 6;
  const int c    = lane & 15, quad = lane >> 4;
  const int u    = blockIdx.x;
  const int xcd  = u & 7;
  const int slot = u >> 3;
  const int h    = slot & 7;
  const int p    = (slot >> 3) * 8 + xcd;
  const int b    = p / 200;
  const int strip = p - b * 200;
  const int qrow = strip * 16 + c;
  const size_t bh = (size_t)(b * HEADS + h);

  const bf16x8 qf = *(const bf16x8*)(qws + (bh * SP + qrow) * HD + quad * 8);
  const unsigned short* kb = kws + bh * SP * HD;
  const unsigned short* vb = vfrag + bh * (size_t)(50 * 2048);
  float* mt = &smem[wid][0];

  const float* msrc[4];
  int goff4[4];
#pragma unroll
  for (int i = 0; i < 4; ++i) {
    const int rq = i * 4 + (lane >> 4);
    int mr = strip * 16 + rq; if (mr >= S_LEN) mr = S_LEN - 1;
    msrc[i] = mask + ((size_t)b * S_LEN + mr) * S_LEN;
    goff4[i] = ((lane & 15) ^ rq) * 4;
  }

  float l_run = 0.f;
  floatx4 o0 = (floatx4){0.f,0.f,0.f,0.f};
  floatx4 o1 = (floatx4){0.f,0.f,0.f,0.f};

  const int tbase = wid * 6;
  const int nt = (wid < 2) ? 7 : 6;

  stage_mask_fb(msrc, goff4, tbase * 64, mt);

  for (int it = 0; it < nt; ++it) {
    const int t = (it < 6) ? tbase + it : 48 + wid;
    if (it + 1 < nt) {
      const int tn = (it + 1 < 6) ? tbase + it + 1 : 48 + wid;
      float* dst = mt + ((it + 1) & 1) * 1024;
      if (tn == 49) stage_mask_tail_fb(msrc, goff4, 49 * 64, dst);
      else          stage_mask_fb(msrc, goff4, tn * 64, dst);
      FENCE4();
    } else {
      FENCE0();
    }
    const float* mb = mt + (it & 1) * 1024;
    if (wid == 1 && it == 6)
      proc_tile_fb<true >(t, kb, vb, mb, c, quad, lane, qf, o0, o1, l_run);
    else
      proc_tile_fb<false>(t, kb, vb, mb, c, quad, lane, qf, o0, o1, l_run);
  }

#pragma unroll
  for (int r = 0; r < 4; ++r) {
    smem[wid][lane * 9 + r]     = o0[r];
    smem[wid][lane * 9 + 4 + r] = o1[r];
  }
  smem[wid][lane * 9 + 8] = l_run;
  __syncthreads();

  if (wid == 0) {
#pragma unroll
    for (int w = 1; w < 8; ++w) {
#pragma unroll
      for (int r = 0; r < 4; ++r) {
        o0[r] += smem[w][lane * 9 + r];
        o1[r] += smem[w][lane * 9 + 4 + r];
      }
      l_run += smem[w][lane * 9 + 8];
    }
    l_run += __shfl_xor(l_run, 16);
    l_run += __shfl_xor(l_run, 32);
    const float rl = 1.f / l_run;

    if (qrow < S_LEN) {
      const size_t obase = ((size_t)b * S_LEN + qrow) * 256 + h * 32;
      const size_t lbase = (qrow >= 8) ? (((size_t)b * NPIX + (qrow - 8)) * 256 + h * 32) : 0;
#pragma unroll
      for (int mt2 = 0; mt2 < 2; ++mt2) {
        floatx4 ov = mt2 ? o1 : o0;
#pragma unroll
        for (int r = 0; r < 4; ++r) {
          const int d = mt2 * 16 + quad * 4 + r;
          float val = ov[r] * rl;
          if (qrow >= 8) val += bf2f(lepe[lbase + d]);
          attn[obase + d] = f2bf(val);
        }
      }
    }
  }
}

// ---------------- K4: output projection (attn bf16, wo/bo f32 -> f32 out) ----------------
__global__ __launch_bounds__(256) void k_oproj(
    const unsigned short* __restrict__ attn,
    const float* __restrict__ wop,
    const float* __restrict__ bop,
    float* __restrict__ out)
{
  const int lane = threadIdx.x & 63;
  const int wid  = threadIdx.x >> 6;
  const int c = lane & 15, quad = lane >> 4;
  const int row0 = blockIdx.x * 64 + wid * 16;
  const int col0 = blockIdx.y * 64;

  int arow = row0 + c; if (arow >= MROWS) arow = 0;
  const unsigned short* ap = attn + (size_t)arow * 256 + quad * 8;
  const float* bp = wop + (size_t)(col0 + c) * 256 + quad * 8;

  floatx4 acc[4];
#pragma unroll
  for (int ct = 0; ct < 4; ++ct) acc[ct] = (floatx4){0.f,0.f,0.f,0.f};
#pragma unroll
  for (int ks = 0; ks < 8; ++ks) {
    bf16x8 af = *(const bf16x8*)(ap + ks * 32);
#pragma unroll
    for (int ct = 0; ct < 4; ++ct) {
      bf16x8 bf = ldcvt8(bp + (size_t)ct * 16 * 256 + ks * 32);
      acc[ct] = __builtin_amdgcn_mfma_f32_16x16x32_bf16(af, bf, acc[ct], 0, 0, 0);
    }
  }
#pragma unroll
  for (int ct = 0; ct < 4; ++ct) {
    const int col = col0 + ct * 16 + c;
    const float bias = bop[col];
#pragma unroll
    for (int r = 0; r < 4; ++r) {
      const int row = row0 + quad * 4 + r;
      if (row >= MROWS) continue;
      out[(size_t)row * 256 + col] = acc[ct][r] + bias;
    }
  }
}

// ---------------- workspace layout (bytes) ----------------
#define QW_OFF 0u                        // 2*8*3200*32*2 = 3,276,800
#define KW_OFF 3276800u
#define VF_OFF 6553600u                  // vfrag, 3,276,800
#define LE_OFF 9830400u                  // w3b (384KB) until k_lepe overwrites with lepe
#define AT_OFF 13041664u                 // 6288*256*2    = 3,219,456
#define PM_OFF 16261120u                 // relayouted fp16 mask: 400*50*2048 = 40,960,000
#define PM_NEED (16261120u + 40960000u)  // 57,221,120

extern "C" void kernel_launch(void* const* d_in, const int* in_sizes, int n_in,
                              void* d_out, int out_size, void* d_ws, size_t ws_size,
                              hipStream_t stream) {
  const float* x    = (const float*)d_in[0];
  const float* mask = (const float*)d_in[1];
  const float* wq   = (const float*)d_in[2];
  const float* bq   = (const float*)d_in[3];
  const float* wk   = (const float*)d_in[4];
  const float* bk   = (const float*)d_in[5];
  const float* wv   = (const float*)d_in[6];
  const float* bv   = (const float*)d_in[7];
  const float* lw   = (const float*)d_in[8];
  const float* lb   = (const float*)d_in[9];
  const float* wo   = (const float*)d_in[10];
  const float* bo   = (const float*)d_in[11];

  char* ws = (char*)d_ws;
  unsigned short* qws = (unsigned short*)(ws + QW_OFF);
  unsigned short* kws = (unsigned short*)(ws + KW_OFF);
  unsigned short* vfr = (unsigned short*)(ws + VF_OFF);
  unsigned short* w3b = (unsigned short*)(ws + LE_OFF);   // dead before k_lepe
  unsigned short* lpe = (unsigned short*)(ws + LE_OFF);
  unsigned short* atb = (unsigned short*)(ws + AT_OFF);
  unsigned short* vst = (unsigned short*)d_out;             // low 3.22MB of d_out
  unsigned short* xb  = (unsigned short*)d_out + 1609728;   // high 3.22MB of d_out
  float*          outf = (float*)d_out;

  const bool use_pre = (ws_size >= (size_t)PM_NEED);

  k_cvt<<<882, 256, 0, stream>>>(x, wq, wk, wv, xb, w3b);
  if (use_pre) {
    _Float16* pm = (_Float16*)(ws + PM_OFF);
    k_mprep<<<dim3(400, 5), 256, 0, stream>>>(mask, pm);
    k_qkv<<<dim3(100, 12), 256, 0, stream>>>(xb, w3b, bq, bk, bv, qws, kws, vfr, vst);
    k_lepe<<<784, 256, 0, stream>>>(vst, lw, lb, lpe);
    k_flash_pre<<<3200, 512, 0, stream>>>(qws, kws, vfr, pm, lpe, atb);
  } else {
    k_qkv<<<dim3(100, 12), 256, 0, stream>>>(xb, w3b, bq, bk, bv, qws, kws, vfr, vst);
    k_lepe<<<784, 256, 0, stream>>>(vst, lw, lb, lpe);
    k_flash_fb<<<3200, 512, 0, stream>>>(qws, kws, vfr, mask, lpe, atb);
  }
  k_oproj<<<dim3(99, 4), 256, 0, stream>>>(atb, wo, bo, outf);
}

// Round 8
// 301.782 us; speedup vs baseline: 1.1463x; 1.0347x over previous
//
#include <hip/hip_runtime.h>

// MaskAttention: B=2,S=3144,C=256,H=8,HD=32, mask-softmax attention with vh=kh,
// LePE 5x5 depthwise conv on v[:,8:], output projection.
// I/O: ALL float32. Internal: bf16 MFMA, f32 accum.
//
// softmax(qk + log(m+eps)) == normalize((m+eps)*exp(qk)); |qk| tiny -> fixed
// shift M=0, no online max; k-range partials additive => split-K.
//
// R8 changes vs R7 (k_flash_pre 111.7us @22% occ; non-flash ~200us):
//  - k_flash_pre: 256-thread blocks (4 waves x 12-13 tiles). Block LDS 16KB
//    (4 x 4KB fp16 mask dbuf) -> blocks/CU thread-capped at 8 (was 4 at 512thr)
//    -> wave ceiling 32/CU. Same proven tile loop + fp16 pm staging.
//  - k_prep: k_cvt and k_mprep fused into ONE fat launch (block-range split);
//    the two independent BW streams overlap and one launch gap disappears.
//  - k_oproj: 32-col blocks, grid (99,8) = 792 blocks (was 396) for 2x TLP on
//    the latency-bound output GEMM.
//  - k_qkv / k_lepe / fallback flash unchanged.

#define S_LEN 3144
#define SP    3200            // S padded to 64 (50 k-tiles; 0..48 fully valid)
#define HEADS 8
#define HD    32
#define BATCH 2
#define MROWS (BATCH*S_LEN)   // 6288
#define NPIX  3136            // 56*56
#define SCALE_F 0.17677669529663687f   // 32^-0.5
#define KQ_SC   0.25504472665352026f   // SCALE_F * log2(e)

typedef __bf16 bf16x8  __attribute__((ext_vector_type(8)));
typedef __bf16 bf16x4  __attribute__((ext_vector_type(4)));
typedef float  floatx4 __attribute__((ext_vector_type(4)));
typedef short  shortx4 __attribute__((ext_vector_type(4)));
typedef _Float16 halfx4 __attribute__((ext_vector_type(4)));
typedef _Float16 halfx8 __attribute__((ext_vector_type(8)));

static __device__ __forceinline__ float bf2f(unsigned int h) {
  union { unsigned int u; float f; } v; v.u = h << 16; return v.f;
}
static __device__ __forceinline__ unsigned short f2bf(float f) {
  union { __bf16 b; unsigned short u; } v; v.b = (__bf16)f; return v.u;
}
static __device__ __forceinline__ bf16x8 ldcvt8(const float* __restrict__ p) {
  float4 a = *(const float4*)p;
  float4 b = *(const float4*)(p + 4);
  bf16x8 r;
  r[0]=(__bf16)a.x; r[1]=(__bf16)a.y; r[2]=(__bf16)a.z; r[3]=(__bf16)a.w;
  r[4]=(__bf16)b.x; r[5]=(__bf16)b.y; r[6]=(__bf16)b.z; r[7]=(__bf16)b.w;
  return r;
}

#define GLOBAL_AS __attribute__((address_space(1)))
#define LDS_AS    __attribute__((address_space(3)))
static __device__ __forceinline__ void gload_lds16(const void* g, void* l) {
  __builtin_amdgcn_global_load_lds((const GLOBAL_AS void*)g, (LDS_AS void*)l, 16, 0, 0);
}

#define FENCE4() asm volatile("s_waitcnt vmcnt(4)" ::: "memory")
#define FENCE2() asm volatile("s_waitcnt vmcnt(2)" ::: "memory")
#define FENCE0() asm volatile("s_waitcnt vmcnt(0)" ::: "memory")

// ---------------- K0: fused prep — f32->bf16 cvt (x,wq,wk,wv) + mask relayout ----------------
// blocks 0..881: cvt. blocks 882..2881: mprep (2000 blocks = old grid 400x5).
// pm tile block = 16 rows x 64 cols fp16 = 2KB, laid out so the LINEAR
// global_load_lds staging (2 instrs x 64 lanes x 16B) lands as:
//   LDS 8B-granule d of row r  =  fp16(mask_row[granule d^r] + 1e-6)
// Pad cols (>= S_LEN) store 0 -> P=0 (no TAIL path needed downstream).
__global__ __launch_bounds__(256) void k_prep(
    const float* __restrict__ x, const float* __restrict__ wq,
    const float* __restrict__ wk, const float* __restrict__ wv,
    unsigned short* __restrict__ xb, unsigned short* __restrict__ w3b,
    const float* __restrict__ mask, _Float16* __restrict__ pm)
{
  const int blk = blockIdx.x;
  if (blk < 882) {
    const int i = blk * 256 + threadIdx.x;   // unit of 8 floats
    const int NX = MROWS * 32;               // 201216
    const int NW = 8192;                     // 65536/8
    const float* src;
    unsigned short* dst;
    if (i < NX) { src = x + (size_t)i * 8; dst = xb + (size_t)i * 8; }
    else {
      const int j = i - NX;
      if (j >= 3 * NW) return;
      src = (j < NW) ? wq + (size_t)j * 8
          : (j < 2 * NW) ? wk + (size_t)(j - NW) * 8
                         : wv + (size_t)(j - 2 * NW) * 8;
      dst = w3b + (size_t)j * 8;
    }
    bf16x8 v = ldcvt8(src);
    *(bf16x8*)dst = v;
    return;
  }
  // ---- mprep part ----
  const int mp = blk - 882;             // 0..1999
  const int bs = mp % 400;              // b*200 + strip
  const int by = mp / 400;              // 0..4
  const int b  = bs / 200, strip = bs % 200;
  const int t  = threadIdx.x;
  const int n  = t & 127;               // 16B dest unit within tile
  const int tsel = t >> 7;              // 2 tiles per iteration
  const int row = n >> 3;               // 0..15
  const int k2  = n & 7;                // dest granule pair index
  const int g0  = (2 * k2) ^ (row & 15);
  const int gbase = g0 & ~1;            // contiguous source block of 8 floats
  const bool swp = (g0 & 1);            // odd row -> dest order swapped

  int mr = strip * 16 + row; if (mr >= S_LEN) mr = S_LEN - 1;
  const float* src = mask + ((size_t)b * S_LEN + mr) * S_LEN;
  _Float16* dst0 = pm + ((size_t)bs * 50) * 1024 + n * 8;

#pragma unroll 1
  for (int tt = 0; tt < 5; ++tt) {
    const int tile = by * 10 + tt * 2 + tsel;
    const int c0 = tile * 64 + gbase * 4;      // multiple of 8; S_LEN%8==0
    float4 a = make_float4(-1e-6f, -1e-6f, -1e-6f, -1e-6f);
    float4 c = a;
    if (c0 < S_LEN) {
      a = *(const float4*)(src + c0);
      c = *(const float4*)(src + c0 + 4);
    }
    const float4 fst = swp ? c : a;
    const float4 snd = swp ? a : c;
    halfx8 o;
    o[0] = (_Float16)(fst.x + 1e-6f); o[1] = (_Float16)(fst.y + 1e-6f);
    o[2] = (_Float16)(fst.z + 1e-6f); o[3] = (_Float16)(fst.w + 1e-6f);
    o[4] = (_Float16)(snd.x + 1e-6f); o[5] = (_Float16)(snd.y + 1e-6f);
    o[6] = (_Float16)(snd.z + 1e-6f); o[7] = (_Float16)(snd.w + 1e-6f);
    *(halfx8*)(dst0 + (size_t)tile * 1024) = o;
  }
}

// ---------------- K1: fused q/k/v projection (bf16 in -> bf16 out) ----------------
// Grid (100, 12): blockIdx.x = bsel*50 + stile. Pad rows (s>=S_LEN) store 0.
__global__ __launch_bounds__(256) void k_qkv(
    const unsigned short* __restrict__ xb, const unsigned short* __restrict__ w3b,
    const float* __restrict__ bqp, const float* __restrict__ bkp,
    const float* __restrict__ bvp,
    unsigned short* __restrict__ qws, unsigned short* __restrict__ kws,
    unsigned short* __restrict__ vfrag, unsigned short* __restrict__ vstage)
{
  __shared__ unsigned short lds_t[64 * 65];   // transpose staging (k blocks only)
  const int lane = threadIdx.x & 63;
  const int wid  = threadIdx.x >> 6;
  const int c    = lane & 15, quad = lane >> 4;
  const int bsel  = blockIdx.x / 50;
  const int stile = blockIdx.x % 50;
  const int srow0 = stile * 64;
  const int ncol = blockIdx.y * 64;           // 0..767
  const int wsel = ncol >> 8;
  const int col0 = ncol & 255;

  const float* bptr = (wsel == 0) ? bqp : (wsel == 1) ? bkp : bvp;

  const int srow = srow0 + wid * 16 + c;
  const int arow = bsel * S_LEN + ((srow < S_LEN) ? srow : 0);  // clamp pad rows
  const unsigned short* ap = xb  + (size_t)arow * 256 + quad * 8;
  const unsigned short* bp = w3b + (size_t)(ncol + c) * 256 + quad * 8;

  floatx4 acc[4];
#pragma unroll
  for (int ct = 0; ct < 4; ++ct) acc[ct] = (floatx4){0.f, 0.f, 0.f, 0.f};

#pragma unroll
  for (int ks = 0; ks < 8; ++ks) {
    bf16x8 af = *(const bf16x8*)(ap + ks * 32);
#pragma unroll
    for (int ct = 0; ct < 4; ++ct) {
      bf16x8 bf = *(const bf16x8*)(bp + (size_t)ct * 16 * 256 + ks * 32);
      acc[ct] = __builtin_amdgcn_mfma_f32_16x16x32_bf16(af, bf, acc[ct], 0, 0, 0);
    }
  }

#pragma unroll
  for (int ct = 0; ct < 4; ++ct) {
    const int col = col0 + ct * 16 + c;
    const float bias = bptr[col];
#pragma unroll
    for (int r = 0; r < 4; ++r) {
      const int s = srow0 + wid * 16 + quad * 4 + r;   // 0..3199 within batch
      const int valid = (s < S_LEN);
      const float v = acc[ct][r] + bias;
      if (wsel == 0) {
        qws[(((size_t)(bsel * HEADS + (col >> 5))) * SP + s) * HD + (col & 31)] =
            valid ? f2bf(v) : (unsigned short)0;
      } else if (wsel == 1) {
        // QK-side copy carries log2e; V-side copy (lds_t->vfrag) does NOT.
        kws[(((size_t)(bsel * HEADS + (col >> 5))) * SP + s) * HD + (col & 31)] =
            valid ? f2bf(v * KQ_SC) : (unsigned short)0;
        lds_t[(ct * 16 + c) * 65 + (wid * 16 + quad * 4 + r)] =
            valid ? f2bf(v * SCALE_F) : (unsigned short)0;
      } else {
        if (valid) vstage[(size_t)(bsel * S_LEN + s) * 256 + col] = f2bf(v);
      }
    }
  }

  if (wsel == 1) {
    // vfrag: PV A-operand fragments in exact MFMA lane order.
    __syncthreads();
    const int tid = threadIdx.x;
#pragma unroll
    for (int j = 0; j < 4; ++j) {
      const int grp  = j * 4 + (tid >> 6);   // 0..15, wave-uniform
      const int l    = tid & 63;
      const int ct2  = grp & 3;
      const int half = (grp >> 2) & 1;
      const int hsel = grp >> 3;
      const int cc = l & 15, qq = l >> 4;
      const int cl = hsel * 32 + half * 16 + cc;
      const int rb = ct2 * 16 + qq * 4;
      union { shortx4 s4; unsigned short u[4]; } pk;
#pragma unroll
      for (int e = 0; e < 4; ++e) pk.u[e] = lds_t[cl * 65 + rb + e];
      const int hglob = (col0 >> 5) + hsel;
      const size_t off =
          ((((size_t)(bsel * HEADS + hglob) * 50 + stile) * 4 + ct2) * 2 + half) * 64 + l;
      *(shortx4*)(vfrag + off * 4) = pk.s4;
    }
  }
}

// ---------------- K2: LePE 5x5 depthwise conv on v[:,8:] ----------------
__global__ __launch_bounds__(256) void k_lepe(const unsigned short* __restrict__ vws,
                                              const float* __restrict__ cw,
                                              const float* __restrict__ cb,
                                              unsigned short* __restrict__ lepe)
{
  int idx = blockIdx.x * 256 + threadIdx.x;
  if (idx >= BATCH * NPIX * 32) return;
  const int cg = idx & 31;
  const int p  = (idx >> 5) % NPIX;
  const int b  = idx / (NPIX * 32);
  const int y  = p / 56, xx = p - y * 56;

  float acc[8];
  {
    float4 b0 = *(const float4*)(cb + cg * 8);
    float4 b1 = *(const float4*)(cb + cg * 8 + 4);
    acc[0]=b0.x; acc[1]=b0.y; acc[2]=b0.z; acc[3]=b0.w;
    acc[4]=b1.x; acc[5]=b1.y; acc[6]=b1.z; acc[7]=b1.w;
  }
#pragma unroll
  for (int dy = -2; dy <= 2; ++dy) {
    const int yy = y + dy;
    if ((unsigned)yy >= 56u) continue;
#pragma unroll
    for (int dx = -2; dx <= 2; ++dx) {
      const int xs = xx + dx;
      if ((unsigned)xs >= 56u) continue;
      uint4 vv = *(const uint4*)(vws + (size_t)(b * S_LEN + 8 + yy * 56 + xs) * 256 + cg * 8);
      const float* wp = cw + (size_t)((dy + 2) * 5 + (dx + 2)) * 256 + cg * 8;
      float4 w0 = *(const float4*)wp;
      float4 w1 = *(const float4*)(wp + 4);
      unsigned int va[4] = {vv.x, vv.y, vv.z, vv.w};
      acc[0] += bf2f(va[0] & 0xFFFFu) * w0.x;  acc[1] += bf2f(va[0] >> 16) * w0.y;
      acc[2] += bf2f(va[1] & 0xFFFFu) * w0.z;  acc[3] += bf2f(va[1] >> 16) * w0.w;
      acc[4] += bf2f(va[2] & 0xFFFFu) * w1.x;  acc[5] += bf2f(va[2] >> 16) * w1.y;
      acc[6] += bf2f(va[3] & 0xFFFFu) * w1.z;  acc[7] += bf2f(va[3] >> 16) * w1.w;
    }
  }
  unsigned int o[4];
#pragma unroll
  for (int j = 0; j < 4; ++j)
    o[j] = (unsigned int)f2bf(acc[2*j]) | ((unsigned int)f2bf(acc[2*j+1]) << 16);
  *((uint4*)(lepe + (size_t)(b * NPIX + p) * 256 + cg * 8)) = make_uint4(o[0], o[1], o[2], o[3]);
}

// ============ K3 (pre path): flash attention, fp16 relayouted mask, 4 waves ============
static __device__ __forceinline__ void proc_tile_pre(
    int t, const unsigned short* __restrict__ kb,
    const unsigned short* __restrict__ vb,
    const _Float16* __restrict__ mb,
    int c, int quad, int lane, const bf16x8 qf,
    floatx4& o0, floatx4& o1, float& l_run)
{
  const int k0 = t * 64;
  bf16x8 kf[4]; shortx4 v0[4], v1[4];
  const unsigned short* tb = vb + (size_t)t * 2048;
#pragma unroll
  for (int ct = 0; ct < 4; ++ct) {
    kf[ct] = *(const bf16x8*)(kb + (size_t)(k0 + ct * 16 + c) * HD + quad * 8);
    v0[ct] = *(const shortx4*)(tb + (ct * 2 + 0) * 256 + lane * 4);
    v1[ct] = *(const shortx4*)(tb + (ct * 2 + 1) * 256 + lane * 4);
  }
  floatx4 s[4];
#pragma unroll
  for (int ct = 0; ct < 4; ++ct)
    s[ct] = __builtin_amdgcn_mfma_f32_16x16x32_bf16(kf[ct], qf,
               (floatx4){0.f,0.f,0.f,0.f}, 0, 0, 0);
  float ls = 0.f;
  shortx4 pf[4];
#pragma unroll
  for (int ct = 0; ct < 4; ++ct) {
    // LDS 8B-granule d of row c holds source granule d^c -> read d=(ct*4+quad)^c
    const halfx4 mv = *(const halfx4*)(mb + c * 64 + (((ct * 4 + quad) ^ c) * 4));
    float pr[4];
    pr[0] = (float)mv[0] * __builtin_amdgcn_exp2f(s[ct][0]);
    pr[1] = (float)mv[1] * __builtin_amdgcn_exp2f(s[ct][1]);
    pr[2] = (float)mv[2] * __builtin_amdgcn_exp2f(s[ct][2]);
    pr[3] = (float)mv[3] * __builtin_amdgcn_exp2f(s[ct][3]);
    ls += (pr[0] + pr[1]) + (pr[2] + pr[3]);
    union { bf16x4 b4; shortx4 s4; } u;
    u.b4[0]=(__bf16)pr[0]; u.b4[1]=(__bf16)pr[1]; u.b4[2]=(__bf16)pr[2]; u.b4[3]=(__bf16)pr[3];
    pf[ct] = u.s4;
  }
  l_run += ls;
#pragma unroll
  for (int ct = 0; ct < 4; ++ct) {
    o0 = __builtin_amdgcn_mfma_f32_16x16x16bf16_1k(v0[ct], pf[ct], o0, 0, 0, 0);
    o1 = __builtin_amdgcn_mfma_f32_16x16x16bf16_1k(v1[ct], pf[ct], o1, 0, 0, 0);
  }
}

static __device__ __forceinline__ void stage_pre(
    const _Float16* __restrict__ mp_t, int lane, _Float16* dst)
{
#pragma unroll
  for (int i = 0; i < 2; ++i)   // 2 x (64 lanes x 16B) = 2KB tile, contiguous
    gload_lds16(mp_t + i * 512 + lane * 8, dst + i * 512);
}

__global__ __launch_bounds__(256) void k_flash_pre(
    const unsigned short* __restrict__ qws,
    const unsigned short* __restrict__ kws,
    const unsigned short* __restrict__ vfrag,
    const _Float16* __restrict__ pmask,
    const unsigned short* __restrict__ lepe,
    unsigned short* __restrict__ attn)
{
  // Per-wave 4KB region: 2 x 2KB fp16 mask dbuf in the loop; first 576 floats
  // reused as reduction scratch after. Block LDS 16KB -> thread-capped 8
  // blocks/CU (32-wave ceiling).
  __shared__ __align__(16) float smem[4][1024];
  const int lane = threadIdx.x & 63;
  const int wid  = threadIdx.x >> 6;          // 0..3
  const int c    = lane & 15, quad = lane >> 4;
  const int u    = blockIdx.x;               // 0..3199
  const int xcd  = u & 7;
  const int slot = u >> 3;                   // 0..399
  const int h    = slot & 7;
  const int p    = (slot >> 3) * 8 + xcd;    // 0..399 = b*200 + strip
  const int b    = p / 200;
  const int strip = p - b * 200;
  const int qrow = strip * 16 + c;
  const size_t bh = (size_t)(b * HEADS + h);

  const bf16x8 qf = *(const bf16x8*)(qws + (bh * SP + qrow) * HD + quad * 8);
  const unsigned short* kb = kws + bh * SP * HD;
  const unsigned short* vb = vfrag + bh * (size_t)(50 * 2048);
  const _Float16* mpb = pmask + (size_t)(b * 200 + strip) * (50 * 1024);
  _Float16* mt = (_Float16*)&smem[wid][0];

  float l_run = 0.f;
  floatx4 o0 = (floatx4){0.f,0.f,0.f,0.f};
  floatx4 o1 = (floatx4){0.f,0.f,0.f,0.f};

  // tiles: wave w -> t = w*12 .. w*12+11; leftovers 48 -> wave0, 49 -> wave1
  // (tile 49's pad cols carry hm=0 -> P=0, normal tile).
  const int tbase = wid * 12;
  const int nt = (wid < 2) ? 13 : 12;

  stage_pre(mpb + tbase * 1024, lane, mt);    // prologue -> buf0

  for (int it = 0; it < nt; ++it) {
    const int t = (it < 12) ? tbase + it : 48 + wid;
    if (it + 1 < nt) {
      const int tn = (it + 1 < 12) ? tbase + it + 1 : 48 + wid;
      stage_pre(mpb + tn * 1024, lane, mt + ((it + 1) & 1) * 1024);
      FENCE2();   // retire THIS tile's 2 staging loads; keep next 2 in flight
    } else {
      FENCE0();
    }
    proc_tile_pre(t, kb, vb, mt + (it & 1) * 1024, c, quad, lane, qf, o0, o1, l_run);
  }

  // ---- cross-wave reduction (smem reused: each wave writes only its region) ----
#pragma unroll
  for (int r = 0; r < 4; ++r) {
    smem[wid][lane * 9 + r]     = o0[r];
    smem[wid][lane * 9 + 4 + r] = o1[r];
  }
  smem[wid][lane * 9 + 8] = l_run;
  __syncthreads();

  if (wid == 0) {
#pragma unroll
    for (int w = 1; w < 4; ++w) {
#pragma unroll
      for (int r = 0; r < 4; ++r) {
        o0[r] += smem[w][lane * 9 + r];
        o1[r] += smem[w][lane * 9 + 4 + r];
      }
      l_run += smem[w][lane * 9 + 8];
    }
    l_run += __shfl_xor(l_run, 16);
    l_run += __shfl_xor(l_run, 32);
    const float rl = 1.f / l_run;

    if (qrow < S_LEN) {
      const size_t obase = ((size_t)b * S_LEN + qrow) * 256 + h * 32;
      const size_t lbase = (qrow >= 8) ? (((size_t)b * NPIX + (qrow - 8)) * 256 + h * 32) : 0;
#pragma unroll
      for (int mt2 = 0; mt2 < 2; ++mt2) {
        floatx4 ov = mt2 ? o1 : o0;
#pragma unroll
        for (int r = 0; r < 4; ++r) {
          const int d = mt2 * 16 + quad * 4 + r;
          float val = ov[r] * rl;
          if (qrow >= 8) val += bf2f(lepe[lbase + d]);
          attn[obase + d] = f2bf(val);
        }
      }
    }
  }
}

// ============ K3 (fallback, R3 verbatim): used when ws_size too small ============
template<bool TAIL>
static __device__ __forceinline__ void proc_tile_fb(
    int t, const unsigned short* __restrict__ kb,
    const unsigned short* __restrict__ vb,
    const float* __restrict__ mb,
    int c, int quad, int lane, const bf16x8 qf,
    floatx4& o0, floatx4& o1, float& l_run)
{
  const int k0 = t * 64;
  bf16x8 kf[4]; shortx4 v0[4], v1[4];
  const unsigned short* tb = vb + (size_t)t * 2048;
#pragma unroll
  for (int ct = 0; ct < 4; ++ct) {
    kf[ct] = *(const bf16x8*)(kb + (size_t)(k0 + ct * 16 + c) * HD + quad * 8);
    v0[ct] = *(const shortx4*)(tb + (ct * 2 + 0) * 256 + lane * 4);
    v1[ct] = *(const shortx4*)(tb + (ct * 2 + 1) * 256 + lane * 4);
  }
  floatx4 s[4];
#pragma unroll
  for (int ct = 0; ct < 4; ++ct)
    s[ct] = __builtin_amdgcn_mfma_f32_16x16x32_bf16(kf[ct], qf,
               (floatx4){0.f,0.f,0.f,0.f}, 0, 0, 0);
  float ls = 0.f;
  shortx4 pf[4];
#pragma unroll
  for (int ct = 0; ct < 4; ++ct) {
    const float4 mv = *(const float4*)(mb + c * 64 + (((ct * 4 + quad) ^ c) * 4));
    float pr[4];
    pr[0] = (mv.x + 1e-6f) * __builtin_amdgcn_exp2f(s[ct][0]);
    pr[1] = (mv.y + 1e-6f) * __builtin_amdgcn_exp2f(s[ct][1]);
    pr[2] = (mv.z + 1e-6f) * __builtin_amdgcn_exp2f(s[ct][2]);
    pr[3] = (mv.w + 1e-6f) * __builtin_amdgcn_exp2f(s[ct][3]);
    if (TAIL) {
      const int kk = k0 + ct * 16 + quad * 4;
#pragma unroll
      for (int r = 0; r < 4; ++r) if (kk + r >= S_LEN) pr[r] = 0.f;
    }
    ls += (pr[0] + pr[1]) + (pr[2] + pr[3]);
    union { bf16x4 b4; shortx4 s4; } u;
    u.b4[0]=(__bf16)pr[0]; u.b4[1]=(__bf16)pr[1]; u.b4[2]=(__bf16)pr[2]; u.b4[3]=(__bf16)pr[3];
    pf[ct] = u.s4;
  }
  l_run += ls;
#pragma unroll
  for (int ct = 0; ct < 4; ++ct) {
    o0 = __builtin_amdgcn_mfma_f32_16x16x16bf16_1k(v0[ct], pf[ct], o0, 0, 0, 0);
    o1 = __builtin_amdgcn_mfma_f32_16x16x16bf16_1k(v1[ct], pf[ct], o1, 0, 0, 0);
  }
}

static __device__ __forceinline__ void stage_mask_fb(
    const float* const (&msrc)[4], const int (&goff4)[4], int k0, float* dst)
{
#pragma unroll
  for (int i = 0; i < 4; ++i)
    gload_lds16(msrc[i] + (k0 + goff4[i]), dst + i * 256);
}

static __device__ __forceinline__ void stage_mask_tail_fb(
    const float* const (&msrc)[4], const int (&goff4)[4], int k0, float* dst)
{
#pragma unroll
  for (int i = 0; i < 4; ++i) {
    int kk = k0 + goff4[i];
    if (kk > S_LEN - 4) kk = S_LEN - 4;
    gload_lds16(msrc[i] + kk, dst + i * 256);
  }
}

__global__ __launch_bounds__(512) void k_flash_fb(
    const unsigned short* __restrict__ qws,
    const unsigned short* __restrict__ kws,
    const unsigned short* __restrict__ vfrag,
    const float* __restrict__ mask,
    const unsigned short* __restrict__ lepe,
    unsigned short* __restrict__ attn)
{
  __shared__ __align__(16) float smem[8][2048];
  const int lane = threadIdx.x & 63;
  const int wid  = threadIdx.x >> 6;
  const int c    = lane & 15, quad = lane >> 4;
  const int u    = blockIdx.x;
  const int xcd  = u & 7;
  const int slot = u >> 3;
  const int h    = slot & 7;
  const int p    = (slot >> 3) * 8 + xcd;
  const int b    = p / 200;
  const int strip = p - b * 200;
  const int qrow = strip * 16 + c;
  const size_t bh = (size_t)(b * HEADS + h);

  const bf16x8 qf = *(const bf16x8*)(qws + (bh * SP + qrow) * HD + quad * 8);
  const unsigned short* kb = kws + bh * SP * HD;
  const unsigned short* vb = vfrag + bh * (size_t)(50 * 2048);
  float* mt = &smem[wid][0];

  const float* msrc[4];
  int goff4[4];
#pragma unroll
  for (int i = 0; i < 4; ++i) {
    const int rq = i * 4 + (lane >> 4);
    int mr = strip * 16 + rq; if (mr >= S_LEN) mr = S_LEN - 1;
    msrc[i] = mask + ((size_t)b * S_LEN + mr) * S_LEN;
    goff4[i] = ((lane & 15) ^ rq) * 4;
  }

  float l_run = 0.f;
  floatx4 o0 = (floatx4){0.f,0.f,0.f,0.f};
  floatx4 o1 = (floatx4){0.f,0.f,0.f,0.f};

  const int tbase = wid * 6;
  const int nt = (wid < 2) ? 7 : 6;

  stage_mask_fb(msrc, goff4, tbase * 64, mt);

  for (int it = 0; it < nt; ++it) {
    const int t = (it < 6) ? tbase + it : 48 + wid;
    if (it + 1 < nt) {
      const int tn = (it + 1 < 6) ? tbase + it + 1 : 48 + wid;
      float* dst = mt + ((it + 1) & 1) * 1024;
      if (tn == 49) stage_mask_tail_fb(msrc, goff4, 49 * 64, dst);
      else          stage_mask_fb(msrc, goff4, tn * 64, dst);
      FENCE4();
    } else {
      FENCE0();
    }
    const float* mb = mt + (it & 1) * 1024;
    if (wid == 1 && it == 6)
      proc_tile_fb<true >(t, kb, vb, mb, c, quad, lane, qf, o0, o1, l_run);
    else
      proc_tile_fb<false>(t, kb, vb, mb, c, quad, lane, qf, o0, o1, l_run);
  }

#pragma unroll
  for (int r = 0; r < 4; ++r) {
    smem[wid][lane * 9 + r]     = o0[r];
    smem[wid][lane * 9 + 4 + r] = o1[r];
  }
  smem[wid][lane * 9 + 8] = l_run;
  __syncthreads();

  if (wid == 0) {
#pragma unroll
    for (int w = 1; w < 8; ++w) {
#pragma unroll
      for (int r = 0; r < 4; ++r) {
        o0[r] += smem[w][lane * 9 + r];
        o1[r] += smem[w][lane * 9 + 4 + r];
      }
      l_run += smem[w][lane * 9 + 8];
    }
    l_run += __shfl_xor(l_run, 16);
    l_run += __shfl_xor(l_run, 32);
    const float rl = 1.f / l_run;

    if (qrow < S_LEN) {
      const size_t obase = ((size_t)b * S_LEN + qrow) * 256 + h * 32;
      const size_t lbase = (qrow >= 8) ? (((size_t)b * NPIX + (qrow - 8)) * 256 + h * 32) : 0;
#pragma unroll
      for (int mt2 = 0; mt2 < 2; ++mt2) {
        floatx4 ov = mt2 ? o1 : o0;
#pragma unroll
        for (int r = 0; r < 4; ++r) {
          const int d = mt2 * 16 + quad * 4 + r;
          float val = ov[r] * rl;
          if (qrow >= 8) val += bf2f(lepe[lbase + d]);
          attn[obase + d] = f2bf(val);
        }
      }
    }
  }
}

// ---------------- K4: output projection (attn bf16, wo/bo f32 -> f32 out) ----------------
// Grid (99, 8): 32-col blocks for 2x block-level parallelism.
__global__ __launch_bounds__(256) void k_oproj(
    const unsigned short* __restrict__ attn,
    const float* __restrict__ wop,
    const float* __restrict__ bop,
    float* __restrict__ out)
{
  const int lane = threadIdx.x & 63;
  const int wid  = threadIdx.x >> 6;
  const int c = lane & 15, quad = lane >> 4;
  const int row0 = blockIdx.x * 64 + wid * 16;
  const int col0 = blockIdx.y * 32;

  int arow = row0 + c; if (arow >= MROWS) arow = 0;
  const unsigned short* ap = attn + (size_t)arow * 256 + quad * 8;
  const float* bp = wop + (size_t)(col0 + c) * 256 + quad * 8;

  floatx4 acc[2];
#pragma unroll
  for (int ct = 0; ct < 2; ++ct) acc[ct] = (floatx4){0.f,0.f,0.f,0.f};
#pragma unroll
  for (int ks = 0; ks < 8; ++ks) {
    bf16x8 af = *(const bf16x8*)(ap + ks * 32);
#pragma unroll
    for (int ct = 0; ct < 2; ++ct) {
      bf16x8 bf = ldcvt8(bp + (size_t)ct * 16 * 256 + ks * 32);
      acc[ct] = __builtin_amdgcn_mfma_f32_16x16x32_bf16(af, bf, acc[ct], 0, 0, 0);
    }
  }
#pragma unroll
  for (int ct = 0; ct < 2; ++ct) {
    const int col = col0 + ct * 16 + c;
    const float bias = bop[col];
#pragma unroll
    for (int r = 0; r < 4; ++r) {
      const int row = row0 + quad * 4 + r;
      if (row >= MROWS) continue;
      out[(size_t)row * 256 + col] = acc[ct][r] + bias;
    }
  }
}

// ---------------- workspace layout (bytes) ----------------
#define QW_OFF 0u                        // 2*8*3200*32*2 = 3,276,800
#define KW_OFF 3276800u
#define VF_OFF 6553600u                  // vfrag, 3,276,800
#define LE_OFF 9830400u                  // w3b (384KB) until k_lepe overwrites with lepe
#define AT_OFF 13041664u                 // 6288*256*2    = 3,219,456
#define PM_OFF 16261120u                 // relayouted fp16 mask: 400*50*2048 = 40,960,000
#define PM_NEED (16261120u + 40960000u)  // 57,221,120

extern "C" void kernel_launch(void* const* d_in, const int* in_sizes, int n_in,
                              void* d_out, int out_size, void* d_ws, size_t ws_size,
                              hipStream_t stream) {
  const float* x    = (const float*)d_in[0];
  const float* mask = (const float*)d_in[1];
  const float* wq   = (const float*)d_in[2];
  const float* bq   = (const float*)d_in[3];
  const float* wk   = (const float*)d_in[4];
  const float* bk   = (const float*)d_in[5];
  const float* wv   = (const float*)d_in[6];
  const float* bv   = (const float*)d_in[7];
  const float* lw   = (const float*)d_in[8];
  const float* lb   = (const float*)d_in[9];
  const float* wo   = (const float*)d_in[10];
  const float* bo   = (const float*)d_in[11];

  char* ws = (char*)d_ws;
  unsigned short* qws = (unsigned short*)(ws + QW_OFF);
  unsigned short* kws = (unsigned short*)(ws + KW_OFF);
  unsigned short* vfr = (unsigned short*)(ws + VF_OFF);
  unsigned short* w3b = (unsigned short*)(ws + LE_OFF);   // dead before k_lepe
  unsigned short* lpe = (unsigned short*)(ws + LE_OFF);
  unsigned short* atb = (unsigned short*)(ws + AT_OFF);
  unsigned short* vst = (unsigned short*)d_out;             // low 3.22MB of d_out
  unsigned short* xb  = (unsigned short*)d_out + 1609728;   // high 3.22MB of d_out
  float*          outf = (float*)d_out;

  const bool use_pre = (ws_size >= (size_t)PM_NEED);

  if (use_pre) {
    _Float16* pm = (_Float16*)(ws + PM_OFF);
    k_prep<<<2882, 256, 0, stream>>>(x, wq, wk, wv, xb, w3b, mask, pm);
    k_qkv<<<dim3(100, 12), 256, 0, stream>>>(xb, w3b, bq, bk, bv, qws, kws, vfr, vst);
    k_lepe<<<784, 256, 0, stream>>>(vst, lw, lb, lpe);
    k_flash_pre<<<3200, 256, 0, stream>>>(qws, kws, vfr, pm, lpe, atb);
  } else {
    k_prep<<<882, 256, 0, stream>>>(x, wq, wk, wv, xb, w3b, mask, (_Float16*)nullptr);
    k_qkv<<<dim3(100, 12), 256, 0, stream>>>(xb, w3b, bq, bk, bv, qws, kws, vfr, vst);
    k_lepe<<<784, 256, 0, stream>>>(vst, lw, lb, lpe);
    k_flash_fb<<<3200, 512, 0, stream>>>(qws, kws, vfr, mask, lpe, atb);
  }
  k_oproj<<<dim3(99, 8), 256, 0, stream>>>(atb, wo, bo, outf);
}

// Round 9
// 295.759 us; speedup vs baseline: 1.1696x; 1.0204x over previous
//
#include <hip/hip_runtime.h>

// MaskAttention: B=2,S=3144,C=256,H=8,HD=32, mask-softmax attention with vh=kh,
// LePE 5x5 depthwise conv on v[:,8:], output projection.
// I/O: ALL float32. Internal: bf16 MFMA, f32 accum.
//
// softmax(qk + log(m+eps)) == normalize((m+eps)*exp(qk)); |qk| tiny -> fixed
// shift M=0, no online max; k-range partials additive => split-K.
//
// R9 changes vs R8 (total 301.8us; flash 104us; non-flash ~198us over 5 serial
// launches):
//  - launch graph fused 5 -> 4:
//      L1 k_cvt (tiny), L2 k_qkv_mp = qkv(1200 blk) + mask-relayout(2000 blk),
//      L3 k_flash_lepe = flash(3200 blk) + lepe(784 blk), L4 k_oproj.
//    mprep streams hide under qkv; lepe fills flash's tail.
//  - flash->lepe dependency broken: flash writes o*rl as F32 to atb (no lepe
//    read); k_oproj adds bf2f(lepe) in f32 then rounds ONCE to bf16 for MFMA
//    -> bit-identical to R8's path.
//  - atb is f32 (6.44MB); pm moved up (PM_NEED 60.4MB; ws>=98MB proven in R6).
//  - flash inner loop byte-identical to R8's proven 104us structure.

#define S_LEN 3144
#define SP    3200            // S padded to 64 (50 k-tiles; 0..48 fully valid)
#define HEADS 8
#define HD    32
#define BATCH 2
#define MROWS (BATCH*S_LEN)   // 6288
#define NPIX  3136            // 56*56
#define SCALE_F 0.17677669529663687f   // 32^-0.5
#define KQ_SC   0.25504472665352026f   // SCALE_F * log2(e)

typedef __bf16 bf16x8  __attribute__((ext_vector_type(8)));
typedef __bf16 bf16x4  __attribute__((ext_vector_type(4)));
typedef float  floatx4 __attribute__((ext_vector_type(4)));
typedef short  shortx4 __attribute__((ext_vector_type(4)));
typedef _Float16 halfx4 __attribute__((ext_vector_type(4)));
typedef _Float16 halfx8 __attribute__((ext_vector_type(8)));

static __device__ __forceinline__ float bf2f(unsigned int h) {
  union { unsigned int u; float f; } v; v.u = h << 16; return v.f;
}
static __device__ __forceinline__ unsigned short f2bf(float f) {
  union { __bf16 b; unsigned short u; } v; v.b = (__bf16)f; return v.u;
}
static __device__ __forceinline__ bf16x8 ldcvt8(const float* __restrict__ p) {
  float4 a = *(const float4*)p;
  float4 b = *(const float4*)(p + 4);
  bf16x8 r;
  r[0]=(__bf16)a.x; r[1]=(__bf16)a.y; r[2]=(__bf16)a.z; r[3]=(__bf16)a.w;
  r[4]=(__bf16)b.x; r[5]=(__bf16)b.y; r[6]=(__bf16)b.z; r[7]=(__bf16)b.w;
  return r;
}

#define GLOBAL_AS __attribute__((address_space(1)))
#define LDS_AS    __attribute__((address_space(3)))
static __device__ __forceinline__ void gload_lds16(const void* g, void* l) {
  __builtin_amdgcn_global_load_lds((const GLOBAL_AS void*)g, (LDS_AS void*)l, 16, 0, 0);
}

#define FENCE4() asm volatile("s_waitcnt vmcnt(4)" ::: "memory")
#define FENCE2() asm volatile("s_waitcnt vmcnt(2)" ::: "memory")
#define FENCE0() asm volatile("s_waitcnt vmcnt(0)" ::: "memory")

// ---------------- K0: one-time f32 -> bf16 conversion (x, wq, wk, wv) ----------------
__global__ __launch_bounds__(256) void k_cvt(
    const float* __restrict__ x, const float* __restrict__ wq,
    const float* __restrict__ wk, const float* __restrict__ wv,
    unsigned short* __restrict__ xb, unsigned short* __restrict__ w3b)
{
  const int i = blockIdx.x * 256 + threadIdx.x;   // unit of 8 floats
  const int NX = MROWS * 32;                      // 201216
  const int NW = 8192;                            // 65536/8
  const float* src;
  unsigned short* dst;
  if (i < NX) { src = x + (size_t)i * 8; dst = xb + (size_t)i * 8; }
  else {
    const int j = i - NX;
    if (j >= 3 * NW) return;
    src = (j < NW) ? wq + (size_t)j * 8
        : (j < 2 * NW) ? wk + (size_t)(j - NW) * 8
                       : wv + (size_t)(j - 2 * NW) * 8;
    dst = w3b + (size_t)j * 8;
  }
  bf16x8 v = ldcvt8(src);
  *(bf16x8*)dst = v;
}

// ---------------- L2: fused qkv (blocks 0..1199) + mask relayout (1200..3199) ----------------
// qkv: bf16 projections -> qws/kws/vfrag/vstage (pad rows store 0).
// mprep: pm tile block = 16x64 fp16 = 2KB laid out so LINEAR global_load_lds
// staging lands as: LDS 8B-granule d of row r = fp16(mask_row[granule d^r]+1e-6).
// Pad cols (>= S_LEN) store 0 -> P=0 downstream, no TAIL path.
__global__ __launch_bounds__(256) void k_qkv_mp(
    const unsigned short* __restrict__ xb, const unsigned short* __restrict__ w3b,
    const float* __restrict__ bqp, const float* __restrict__ bkp,
    const float* __restrict__ bvp,
    unsigned short* __restrict__ qws, unsigned short* __restrict__ kws,
    unsigned short* __restrict__ vfrag, unsigned short* __restrict__ vstage,
    const float* __restrict__ mask, _Float16* __restrict__ pm)
{
  __shared__ unsigned short lds_t[64 * 65];   // qkv transpose staging (k blocks only)
  const int blk = blockIdx.x;

  if (blk >= 1200) {
    // ---- mask relayout part ----
    const int mp = blk - 1200;            // 0..1999
    const int bs = mp % 400;              // b*200 + strip
    const int by = mp / 400;              // 0..4
    const int b  = bs / 200, strip = bs % 200;
    const int t  = threadIdx.x;
    const int n  = t & 127;               // 16B dest unit within tile
    const int tsel = t >> 7;              // 2 tiles per iteration
    const int row = n >> 3;               // 0..15
    const int k2  = n & 7;                // dest granule pair index
    const int g0  = (2 * k2) ^ (row & 15);
    const int gbase = g0 & ~1;            // contiguous source block of 8 floats
    const bool swp = (g0 & 1);            // odd row -> dest order swapped

    int mr = strip * 16 + row; if (mr >= S_LEN) mr = S_LEN - 1;
    const float* src = mask + ((size_t)b * S_LEN + mr) * S_LEN;
    _Float16* dst0 = pm + ((size_t)bs * 50) * 1024 + n * 8;

#pragma unroll 1
    for (int tt = 0; tt < 5; ++tt) {
      const int tile = by * 10 + tt * 2 + tsel;
      const int c0 = tile * 64 + gbase * 4;    // multiple of 8; S_LEN%8==0
      float4 a = make_float4(-1e-6f, -1e-6f, -1e-6f, -1e-6f);
      float4 c = a;
      if (c0 < S_LEN) {
        a = *(const float4*)(src + c0);
        c = *(const float4*)(src + c0 + 4);
      }
      const float4 fst = swp ? c : a;
      const float4 snd = swp ? a : c;
      halfx8 o;
      o[0] = (_Float16)(fst.x + 1e-6f); o[1] = (_Float16)(fst.y + 1e-6f);
      o[2] = (_Float16)(fst.z + 1e-6f); o[3] = (_Float16)(fst.w + 1e-6f);
      o[4] = (_Float16)(snd.x + 1e-6f); o[5] = (_Float16)(snd.y + 1e-6f);
      o[6] = (_Float16)(snd.z + 1e-6f); o[7] = (_Float16)(snd.w + 1e-6f);
      *(halfx8*)(dst0 + (size_t)tile * 1024) = o;
    }
    return;
  }

  // ---- qkv part (blk = yi*100 + xi; xi = bsel*50+stile, yi -> ncol) ----
  const int xi = blk % 100;
  const int yi = blk / 100;                   // 0..11
  const int lane = threadIdx.x & 63;
  const int wid  = threadIdx.x >> 6;
  const int c    = lane & 15, quad = lane >> 4;
  const int bsel  = xi / 50;
  const int stile = xi % 50;
  const int srow0 = stile * 64;
  const int ncol = yi * 64;                   // 0..767
  const int wsel = ncol >> 8;
  const int col0 = ncol & 255;

  const float* bptr = (wsel == 0) ? bqp : (wsel == 1) ? bkp : bvp;

  const int srow = srow0 + wid * 16 + c;
  const int arow = bsel * S_LEN + ((srow < S_LEN) ? srow : 0);  // clamp pad rows
  const unsigned short* ap = xb  + (size_t)arow * 256 + quad * 8;
  const unsigned short* bp = w3b + (size_t)(ncol + c) * 256 + quad * 8;

  floatx4 acc[4];
#pragma unroll
  for (int ct = 0; ct < 4; ++ct) acc[ct] = (floatx4){0.f, 0.f, 0.f, 0.f};

#pragma unroll
  for (int ks = 0; ks < 8; ++ks) {
    bf16x8 af = *(const bf16x8*)(ap + ks * 32);
#pragma unroll
    for (int ct = 0; ct < 4; ++ct) {
      bf16x8 bf = *(const bf16x8*)(bp + (size_t)ct * 16 * 256 + ks * 32);
      acc[ct] = __builtin_amdgcn_mfma_f32_16x16x32_bf16(af, bf, acc[ct], 0, 0, 0);
    }
  }

#pragma unroll
  for (int ct = 0; ct < 4; ++ct) {
    const int col = col0 + ct * 16 + c;
    const float bias = bptr[col];
#pragma unroll
    for (int r = 0; r < 4; ++r) {
      const int s = srow0 + wid * 16 + quad * 4 + r;   // 0..3199 within batch
      const int valid = (s < S_LEN);
      const float v = acc[ct][r] + bias;
      if (wsel == 0) {
        qws[(((size_t)(bsel * HEADS + (col >> 5))) * SP + s) * HD + (col & 31)] =
            valid ? f2bf(v) : (unsigned short)0;
      } else if (wsel == 1) {
        // QK-side copy carries log2e; V-side copy (lds_t->vfrag) does NOT.
        kws[(((size_t)(bsel * HEADS + (col >> 5))) * SP + s) * HD + (col & 31)] =
            valid ? f2bf(v * KQ_SC) : (unsigned short)0;
        lds_t[(ct * 16 + c) * 65 + (wid * 16 + quad * 4 + r)] =
            valid ? f2bf(v * SCALE_F) : (unsigned short)0;
      } else {
        if (valid) vstage[(size_t)(bsel * S_LEN + s) * 256 + col] = f2bf(v);
      }
    }
  }

  if (wsel == 1) {
    // vfrag: PV A-operand fragments in exact MFMA lane order.
    __syncthreads();
    const int tid = threadIdx.x;
#pragma unroll
    for (int j = 0; j < 4; ++j) {
      const int grp  = j * 4 + (tid >> 6);   // 0..15, wave-uniform
      const int l    = tid & 63;
      const int ct2  = grp & 3;
      const int half = (grp >> 2) & 1;
      const int hsel = grp >> 3;
      const int cc = l & 15, qq = l >> 4;
      const int cl = hsel * 32 + half * 16 + cc;
      const int rb = ct2 * 16 + qq * 4;
      union { shortx4 s4; unsigned short u[4]; } pk;
#pragma unroll
      for (int e = 0; e < 4; ++e) pk.u[e] = lds_t[cl * 65 + rb + e];
      const int hglob = (col0 >> 5) + hsel;
      const size_t off =
          ((((size_t)(bsel * HEADS + hglob) * 50 + stile) * 4 + ct2) * 2 + half) * 64 + l;
      *(shortx4*)(vfrag + off * 4) = pk.s4;
    }
  }
}

// ---------------- LePE device body (5x5 depthwise conv on v[:,8:]) ----------------
static __device__ void lepe_block(int idx,
                                  const unsigned short* __restrict__ vws,
                                  const float* __restrict__ cw,
                                  const float* __restrict__ cb,
                                  unsigned short* __restrict__ lepe)
{
  if (idx >= BATCH * NPIX * 32) return;
  const int cg = idx & 31;
  const int p  = (idx >> 5) % NPIX;
  const int b  = idx / (NPIX * 32);
  const int y  = p / 56, xx = p - y * 56;

  float acc[8];
  {
    float4 b0 = *(const float4*)(cb + cg * 8);
    float4 b1 = *(const float4*)(cb + cg * 8 + 4);
    acc[0]=b0.x; acc[1]=b0.y; acc[2]=b0.z; acc[3]=b0.w;
    acc[4]=b1.x; acc[5]=b1.y; acc[6]=b1.z; acc[7]=b1.w;
  }
#pragma unroll
  for (int dy = -2; dy <= 2; ++dy) {
    const int yy = y + dy;
    if ((unsigned)yy >= 56u) continue;
#pragma unroll
    for (int dx = -2; dx <= 2; ++dx) {
      const int xs = xx + dx;
      if ((unsigned)xs >= 56u) continue;
      uint4 vv = *(const uint4*)(vws + (size_t)(b * S_LEN + 8 + yy * 56 + xs) * 256 + cg * 8);
      const float* wp = cw + (size_t)((dy + 2) * 5 + (dx + 2)) * 256 + cg * 8;
      float4 w0 = *(const float4*)wp;
      float4 w1 = *(const float4*)(wp + 4);
      unsigned int va[4] = {vv.x, vv.y, vv.z, vv.w};
      acc[0] += bf2f(va[0] & 0xFFFFu) * w0.x;  acc[1] += bf2f(va[0] >> 16) * w0.y;
      acc[2] += bf2f(va[1] & 0xFFFFu) * w0.z;  acc[3] += bf2f(va[1] >> 16) * w0.w;
      acc[4] += bf2f(va[2] & 0xFFFFu) * w1.x;  acc[5] += bf2f(va[2] >> 16) * w1.y;
      acc[6] += bf2f(va[3] & 0xFFFFu) * w1.z;  acc[7] += bf2f(va[3] >> 16) * w1.w;
    }
  }
  unsigned int o[4];
#pragma unroll
  for (int j = 0; j < 4; ++j)
    o[j] = (unsigned int)f2bf(acc[2*j]) | ((unsigned int)f2bf(acc[2*j+1]) << 16);
  *((uint4*)(lepe + (size_t)(b * NPIX + p) * 256 + cg * 8)) = make_uint4(o[0], o[1], o[2], o[3]);
}

// ============ flash tile machinery (fp16 relayouted mask, R8-proven) ============
static __device__ __forceinline__ void proc_tile_pre(
    int t, const unsigned short* __restrict__ kb,
    const unsigned short* __restrict__ vb,
    const _Float16* __restrict__ mb,
    int c, int quad, int lane, const bf16x8 qf,
    floatx4& o0, floatx4& o1, float& l_run)
{
  const int k0 = t * 64;
  bf16x8 kf[4]; shortx4 v0[4], v1[4];
  const unsigned short* tb = vb + (size_t)t * 2048;
#pragma unroll
  for (int ct = 0; ct < 4; ++ct) {
    kf[ct] = *(const bf16x8*)(kb + (size_t)(k0 + ct * 16 + c) * HD + quad * 8);
    v0[ct] = *(const shortx4*)(tb + (ct * 2 + 0) * 256 + lane * 4);
    v1[ct] = *(const shortx4*)(tb + (ct * 2 + 1) * 256 + lane * 4);
  }
  floatx4 s[4];
#pragma unroll
  for (int ct = 0; ct < 4; ++ct)
    s[ct] = __builtin_amdgcn_mfma_f32_16x16x32_bf16(kf[ct], qf,
               (floatx4){0.f,0.f,0.f,0.f}, 0, 0, 0);
  float ls = 0.f;
  shortx4 pf[4];
#pragma unroll
  for (int ct = 0; ct < 4; ++ct) {
    // LDS 8B-granule d of row c holds source granule d^c -> read d=(ct*4+quad)^c
    const halfx4 mv = *(const halfx4*)(mb + c * 64 + (((ct * 4 + quad) ^ c) * 4));
    float pr[4];
    pr[0] = (float)mv[0] * __builtin_amdgcn_exp2f(s[ct][0]);
    pr[1] = (float)mv[1] * __builtin_amdgcn_exp2f(s[ct][1]);
    pr[2] = (float)mv[2] * __builtin_amdgcn_exp2f(s[ct][2]);
    pr[3] = (float)mv[3] * __builtin_amdgcn_exp2f(s[ct][3]);
    ls += (pr[0] + pr[1]) + (pr[2] + pr[3]);
    union { bf16x4 b4; shortx4 s4; } u;
    u.b4[0]=(__bf16)pr[0]; u.b4[1]=(__bf16)pr[1]; u.b4[2]=(__bf16)pr[2]; u.b4[3]=(__bf16)pr[3];
    pf[ct] = u.s4;
  }
  l_run += ls;
#pragma unroll
  for (int ct = 0; ct < 4; ++ct) {
    o0 = __builtin_amdgcn_mfma_f32_16x16x16bf16_1k(v0[ct], pf[ct], o0, 0, 0, 0);
    o1 = __builtin_amdgcn_mfma_f32_16x16x16bf16_1k(v1[ct], pf[ct], o1, 0, 0, 0);
  }
}

static __device__ __forceinline__ void stage_pre(
    const _Float16* __restrict__ mp_t, int lane, _Float16* dst)
{
#pragma unroll
  for (int i = 0; i < 2; ++i)   // 2 x (64 lanes x 16B) = 2KB tile, contiguous
    gload_lds16(mp_t + i * 512 + lane * 8, dst + i * 512);
}

// ---------------- L3: fused flash (blocks 0..3199) + lepe (3200..3983) ----------------
// flash writes o*rl as F32 to atbf (no lepe read here).
__global__ __launch_bounds__(256) void k_flash_lepe(
    const unsigned short* __restrict__ qws,
    const unsigned short* __restrict__ kws,
    const unsigned short* __restrict__ vfrag,
    const _Float16* __restrict__ pmask,
    const unsigned short* __restrict__ vws,
    const float* __restrict__ cw, const float* __restrict__ cb,
    unsigned short* __restrict__ lepe_out,
    float* __restrict__ atbf)
{
  __shared__ __align__(16) float smem[4][1024];
  if (blockIdx.x >= 3200) {
    lepe_block((blockIdx.x - 3200) * 256 + threadIdx.x, vws, cw, cb, lepe_out);
    return;
  }
  const int lane = threadIdx.x & 63;
  const int wid  = threadIdx.x >> 6;          // 0..3
  const int c    = lane & 15, quad = lane >> 4;
  const int u    = blockIdx.x;               // 0..3199
  const int xcd  = u & 7;
  const int slot = u >> 3;                   // 0..399
  const int h    = slot & 7;
  const int p    = (slot >> 3) * 8 + xcd;    // 0..399 = b*200 + strip
  const int b    = p / 200;
  const int strip = p - b * 200;
  const int qrow = strip * 16 + c;
  const size_t bh = (size_t)(b * HEADS + h);

  const bf16x8 qf = *(const bf16x8*)(qws + (bh * SP + qrow) * HD + quad * 8);
  const unsigned short* kb = kws + bh * SP * HD;
  const unsigned short* vb = vfrag + bh * (size_t)(50 * 2048);
  const _Float16* mpb = pmask + (size_t)(b * 200 + strip) * (50 * 1024);
  _Float16* mt = (_Float16*)&smem[wid][0];

  float l_run = 0.f;
  floatx4 o0 = (floatx4){0.f,0.f,0.f,0.f};
  floatx4 o1 = (floatx4){0.f,0.f,0.f,0.f};

  // tiles: wave w -> t = w*12 .. w*12+11; leftovers 48 -> wave0, 49 -> wave1
  // (tile 49's pad cols carry hm=0 -> P=0, normal tile).
  const int tbase = wid * 12;
  const int nt = (wid < 2) ? 13 : 12;

  stage_pre(mpb + tbase * 1024, lane, mt);    // prologue -> buf0

  for (int it = 0; it < nt; ++it) {
    const int t = (it < 12) ? tbase + it : 48 + wid;
    if (it + 1 < nt) {
      const int tn = (it + 1 < 12) ? tbase + it + 1 : 48 + wid;
      stage_pre(mpb + tn * 1024, lane, mt + ((it + 1) & 1) * 1024);
      FENCE2();   // retire THIS tile's 2 staging loads; keep next 2 in flight
    } else {
      FENCE0();
    }
    proc_tile_pre(t, kb, vb, mt + (it & 1) * 1024, c, quad, lane, qf, o0, o1, l_run);
  }

  // ---- cross-wave reduction (smem reused: each wave writes only its region) ----
#pragma unroll
  for (int r = 0; r < 4; ++r) {
    smem[wid][lane * 9 + r]     = o0[r];
    smem[wid][lane * 9 + 4 + r] = o1[r];
  }
  smem[wid][lane * 9 + 8] = l_run;
  __syncthreads();

  if (wid == 0) {
#pragma unroll
    for (int w = 1; w < 4; ++w) {
#pragma unroll
      for (int r = 0; r < 4; ++r) {
        o0[r] += smem[w][lane * 9 + r];
        o1[r] += smem[w][lane * 9 + 4 + r];
      }
      l_run += smem[w][lane * 9 + 8];
    }
    l_run += __shfl_xor(l_run, 16);
    l_run += __shfl_xor(l_run, 32);
    const float rl = 1.f / l_run;

    if (qrow < S_LEN) {
      float* op = atbf + ((size_t)b * S_LEN + qrow) * 256 + h * 32;
      float4 s0 = make_float4(o0[0]*rl, o0[1]*rl, o0[2]*rl, o0[3]*rl);
      float4 s1 = make_float4(o1[0]*rl, o1[1]*rl, o1[2]*rl, o1[3]*rl);
      *(float4*)(op + quad * 4)      = s0;
      *(float4*)(op + 16 + quad * 4) = s1;
    }
  }
}

// ---------------- L4: output projection (atb f32 + lepe bf16 -> f32 out) ----------------
// Grid (99, 8): 32-col blocks. af = bf16(atb_f32 + bf2f(lepe)) -- the sum is
// rounded to bf16 exactly once, bit-identical to R8's stored-attn path.
__global__ __launch_bounds__(256) void k_oproj(
    const float* __restrict__ atbf,
    const unsigned short* __restrict__ lepe,
    const float* __restrict__ wop,
    const float* __restrict__ bop,
    float* __restrict__ out)
{
  const int lane = threadIdx.x & 63;
  const int wid  = threadIdx.x >> 6;
  const int c = lane & 15, quad = lane >> 4;
  const int row0 = blockIdx.x * 64 + wid * 16;
  const int col0 = blockIdx.y * 32;

  int arow = row0 + c; if (arow >= MROWS) arow = 0;
  const int bb = (arow >= S_LEN) ? 1 : 0;
  const int sr = arow - bb * S_LEN;
  const bool hasl = (sr >= 8);
  const float* ap = atbf + (size_t)arow * 256 + quad * 8;
  const unsigned short* lp =
      lepe + (hasl ? (((size_t)bb * NPIX + (sr - 8)) * 256 + quad * 8) : 0);
  const float* bp = wop + (size_t)(col0 + c) * 256 + quad * 8;

  floatx4 acc[2];
#pragma unroll
  for (int ct = 0; ct < 2; ++ct) acc[ct] = (floatx4){0.f,0.f,0.f,0.f};
#pragma unroll
  for (int ks = 0; ks < 8; ++ks) {
    float4 a0 = *(const float4*)(ap + ks * 32);
    float4 a1 = *(const float4*)(ap + ks * 32 + 4);
    if (hasl) {
      uint4 lv = *(const uint4*)(lp + ks * 32);
      a0.x += bf2f(lv.x & 0xFFFFu); a0.y += bf2f(lv.x >> 16);
      a0.z += bf2f(lv.y & 0xFFFFu); a0.w += bf2f(lv.y >> 16);
      a1.x += bf2f(lv.z & 0xFFFFu); a1.y += bf2f(lv.z >> 16);
      a1.z += bf2f(lv.w & 0xFFFFu); a1.w += bf2f(lv.w >> 16);
    }
    bf16x8 af;
    af[0]=(__bf16)a0.x; af[1]=(__bf16)a0.y; af[2]=(__bf16)a0.z; af[3]=(__bf16)a0.w;
    af[4]=(__bf16)a1.x; af[5]=(__bf16)a1.y; af[6]=(__bf16)a1.z; af[7]=(__bf16)a1.w;
#pragma unroll
    for (int ct = 0; ct < 2; ++ct) {
      bf16x8 bf = ldcvt8(bp + (size_t)ct * 16 * 256 + ks * 32);
      acc[ct] = __builtin_amdgcn_mfma_f32_16x16x32_bf16(af, bf, acc[ct], 0, 0, 0);
    }
  }
#pragma unroll
  for (int ct = 0; ct < 2; ++ct) {
    const int col = col0 + ct * 16 + c;
    const float bias = bop[col];
#pragma unroll
    for (int r = 0; r < 4; ++r) {
      const int row = row0 + quad * 4 + r;
      if (row >= MROWS) continue;
      out[(size_t)row * 256 + col] = acc[ct][r] + bias;
    }
  }
}

// ============ fallback flash (f32 atb write, no lepe read) + standalone lepe ============
__global__ __launch_bounds__(256) void k_lepe_sa(const unsigned short* __restrict__ vws,
                                                 const float* __restrict__ cw,
                                                 const float* __restrict__ cb,
                                                 unsigned short* __restrict__ lepe)
{
  lepe_block(blockIdx.x * 256 + threadIdx.x, vws, cw, cb, lepe);
}

template<bool TAIL>
static __device__ __forceinline__ void proc_tile_fb(
    int t, const unsigned short* __restrict__ kb,
    const unsigned short* __restrict__ vb,
    const float* __restrict__ mb,
    int c, int quad, int lane, const bf16x8 qf,
    floatx4& o0, floatx4& o1, float& l_run)
{
  const int k0 = t * 64;
  bf16x8 kf[4]; shortx4 v0[4], v1[4];
  const unsigned short* tb = vb + (size_t)t * 2048;
#pragma unroll
  for (int ct = 0; ct < 4; ++ct) {
    kf[ct] = *(const bf16x8*)(kb + (size_t)(k0 + ct * 16 + c) * HD + quad * 8);
    v0[ct] = *(const shortx4*)(tb + (ct * 2 + 0) * 256 + lane * 4);
    v1[ct] = *(const shortx4*)(tb + (ct * 2 + 1) * 256 + lane * 4);
  }
  floatx4 s[4];
#pragma unroll
  for (int ct = 0; ct < 4; ++ct)
    s[ct] = __builtin_amdgcn_mfma_f32_16x16x32_bf16(kf[ct], qf,
               (floatx4){0.f,0.f,0.f,0.f}, 0, 0, 0);
  float ls = 0.f;
  shortx4 pf[4];
#pragma unroll
  for (int ct = 0; ct < 4; ++ct) {
    const float4 mv = *(const float4*)(mb + c * 64 + (((ct * 4 + quad) ^ c) * 4));
    float pr[4];
    pr[0] = (mv.x + 1e-6f) * __builtin_amdgcn_exp2f(s[ct][0]);
    pr[1] = (mv.y + 1e-6f) * __builtin_amdgcn_exp2f(s[ct][1]);
    pr[2] = (mv.z + 1e-6f) * __builtin_amdgcn_exp2f(s[ct][2]);
    pr[3] = (mv.w + 1e-6f) * __builtin_amdgcn_exp2f(s[ct][3]);
    if (TAIL) {
      const int kk = k0 + ct * 16 + quad * 4;
#pragma unroll
      for (int r = 0; r < 4; ++r) if (kk + r >= S_LEN) pr[r] = 0.f;
    }
    ls += (pr[0] + pr[1]) + (pr[2] + pr[3]);
    union { bf16x4 b4; shortx4 s4; } u;
    u.b4[0]=(__bf16)pr[0]; u.b4[1]=(__bf16)pr[1]; u.b4[2]=(__bf16)pr[2]; u.b4[3]=(__bf16)pr[3];
    pf[ct] = u.s4;
  }
  l_run += ls;
#pragma unroll
  for (int ct = 0; ct < 4; ++ct) {
    o0 = __builtin_amdgcn_mfma_f32_16x16x16bf16_1k(v0[ct], pf[ct], o0, 0, 0, 0);
    o1 = __builtin_amdgcn_mfma_f32_16x16x16bf16_1k(v1[ct], pf[ct], o1, 0, 0, 0);
  }
}

static __device__ __forceinline__ void stage_mask_fb(
    const float* const (&msrc)[4], const int (&goff4)[4], int k0, float* dst)
{
#pragma unroll
  for (int i = 0; i < 4; ++i)
    gload_lds16(msrc[i] + (k0 + goff4[i]), dst + i * 256);
}

static __device__ __forceinline__ void stage_mask_tail_fb(
    const float* const (&msrc)[4], const int (&goff4)[4], int k0, float* dst)
{
#pragma unroll
  for (int i = 0; i < 4; ++i) {
    int kk = k0 + goff4[i];
    if (kk > S_LEN - 4) kk = S_LEN - 4;
    gload_lds16(msrc[i] + kk, dst + i * 256);
  }
}

__global__ __launch_bounds__(512) void k_flash_fb(
    const unsigned short* __restrict__ qws,
    const unsigned short* __restrict__ kws,
    const unsigned short* __restrict__ vfrag,
    const float* __restrict__ mask,
    float* __restrict__ atbf)
{
  __shared__ __align__(16) float smem[8][2048];
  const int lane = threadIdx.x & 63;
  const int wid  = threadIdx.x >> 6;
  const int c    = lane & 15, quad = lane >> 4;
  const int u    = blockIdx.x;
  const int xcd  = u & 7;
  const int slot = u >> 3;
  const int h    = slot & 7;
  const int p    = (slot >> 3) * 8 + xcd;
  const int b    = p / 200;
  const int strip = p - b * 200;
  const int qrow = strip * 16 + c;
  const size_t bh = (size_t)(b * HEADS + h);

  const bf16x8 qf = *(const bf16x8*)(qws + (bh * SP + qrow) * HD + quad * 8);
  const unsigned short* kb = kws + bh * SP * HD;
  const unsigned short* vb = vfrag + bh * (size_t)(50 * 2048);
  float* mt = &smem[wid][0];

  const float* msrc[4];
  int goff4[4];
#pragma unroll
  for (int i = 0; i < 4; ++i) {
    const int rq = i * 4 + (lane >> 4);
    int mr = strip * 16 + rq; if (mr >= S_LEN) mr = S_LEN - 1;
    msrc[i] = mask + ((size_t)b * S_LEN + mr) * S_LEN;
    goff4[i] = ((lane & 15) ^ rq) * 4;
  }

  float l_run = 0.f;
  floatx4 o0 = (floatx4){0.f,0.f,0.f,0.f};
  floatx4 o1 = (floatx4){0.f,0.f,0.f,0.f};

  const int tbase = wid * 6;
  const int nt = (wid < 2) ? 7 : 6;

  stage_mask_fb(msrc, goff4, tbase * 64, mt);

  for (int it = 0; it < nt; ++it) {
    const int t = (it < 6) ? tbase + it : 48 + wid;
    if (it + 1 < nt) {
      const int tn = (it + 1 < 6) ? tbase + it + 1 : 48 + wid;
      float* dst = mt + ((it + 1) & 1) * 1024;
      if (tn == 49) stage_mask_tail_fb(msrc, goff4, 49 * 64, dst);
      else          stage_mask_fb(msrc, goff4, tn * 64, dst);
      FENCE4();
    } else {
      FENCE0();
    }
    const float* mb = mt + (it & 1) * 1024;
    if (wid == 1 && it == 6)
      proc_tile_fb<true >(t, kb, vb, mb, c, quad, lane, qf, o0, o1, l_run);
    else
      proc_tile_fb<false>(t, kb, vb, mb, c, quad, lane, qf, o0, o1, l_run);
  }

#pragma unroll
  for (int r = 0; r < 4; ++r) {
    smem[wid][lane * 9 + r]     = o0[r];
    smem[wid][lane * 9 + 4 + r] = o1[r];
  }
  smem[wid][lane * 9 + 8] = l_run;
  __syncthreads();

  if (wid == 0) {
#pragma unroll
    for (int w = 1; w < 8; ++w) {
#pragma unroll
      for (int r = 0; r < 4; ++r) {
        o0[r] += smem[w][lane * 9 + r];
        o1[r] += smem[w][lane * 9 + 4 + r];
      }
      l_run += smem[w][lane * 9 + 8];
    }
    l_run += __shfl_xor(l_run, 16);
    l_run += __shfl_xor(l_run, 32);
    const float rl = 1.f / l_run;

    if (qrow < S_LEN) {
      float* op = atbf + ((size_t)b * S_LEN + qrow) * 256 + h * 32;
      float4 s0 = make_float4(o0[0]*rl, o0[1]*rl, o0[2]*rl, o0[3]*rl);
      float4 s1 = make_float4(o1[0]*rl, o1[1]*rl, o1[2]*rl, o1[3]*rl);
      *(float4*)(op + quad * 4)      = s0;
      *(float4*)(op + 16 + quad * 4) = s1;
    }
  }
}

// ---------------- workspace layout (bytes) ----------------
#define QW_OFF 0u                        // 2*8*3200*32*2 = 3,276,800
#define KW_OFF 3276800u
#define VF_OFF 6553600u                  // vfrag, 3,276,800
#define LE_OFF 9830400u                  // w3b (384KB, dead after qkv) then lpe (3,211,264)
#define AT_OFF 13041664u                 // atb F32: 6288*256*4 = 6,438,912
#define PM_OFF 19480576u                 // relayouted fp16 mask: 40,960,000
#define PM_NEED (19480576u + 40960000u)  // 60,440,576 (ws >= 98MB proven in R6)

extern "C" void kernel_launch(void* const* d_in, const int* in_sizes, int n_in,
                              void* d_out, int out_size, void* d_ws, size_t ws_size,
                              hipStream_t stream) {
  const float* x    = (const float*)d_in[0];
  const float* mask = (const float*)d_in[1];
  const float* wq   = (const float*)d_in[2];
  const float* bq   = (const float*)d_in[3];
  const float* wk   = (const float*)d_in[4];
  const float* bk   = (const float*)d_in[5];
  const float* wv   = (const float*)d_in[6];
  const float* bv   = (const float*)d_in[7];
  const float* lw   = (const float*)d_in[8];
  const float* lb   = (const float*)d_in[9];
  const float* wo   = (const float*)d_in[10];
  const float* bo   = (const float*)d_in[11];

  char* ws = (char*)d_ws;
  unsigned short* qws = (unsigned short*)(ws + QW_OFF);
  unsigned short* kws = (unsigned short*)(ws + KW_OFF);
  unsigned short* vfr = (unsigned short*)(ws + VF_OFF);
  unsigned short* w3b = (unsigned short*)(ws + LE_OFF);   // dead after qkv
  unsigned short* lpe = (unsigned short*)(ws + LE_OFF);
  float*          atf = (float*)(ws + AT_OFF);
  unsigned short* vst = (unsigned short*)d_out;             // low 3.22MB of d_out
  unsigned short* xb  = (unsigned short*)d_out + 1609728;   // high 3.22MB of d_out
  float*          outf = (float*)d_out;

  const bool use_pre = (ws_size >= (size_t)PM_NEED);

  k_cvt<<<882, 256, 0, stream>>>(x, wq, wk, wv, xb, w3b);
  if (use_pre) {
    _Float16* pm = (_Float16*)(ws + PM_OFF);
    k_qkv_mp<<<3200, 256, 0, stream>>>(xb, w3b, bq, bk, bv, qws, kws, vfr, vst, mask, pm);
    k_flash_lepe<<<3984, 256, 0, stream>>>(qws, kws, vfr, pm, vst, lw, lb, lpe, atf);
  } else {
    k_qkv_mp<<<1200, 256, 0, stream>>>(xb, w3b, bq, bk, bv, qws, kws, vfr, vst,
                                       mask, (_Float16*)nullptr);
    k_lepe_sa<<<784, 256, 0, stream>>>(vst, lw, lb, lpe);
    k_flash_fb<<<3200, 512, 0, stream>>>(qws, kws, vfr, mask, atf);
  }
  k_oproj<<<dim3(99, 8), 256, 0, stream>>>(atf, lpe, wo, bo, outf);
}

// Round 11
// 282.520 us; speedup vs baseline: 1.2244x; 1.0469x over previous
//
#include <hip/hip_runtime.h>

// MaskAttention: B=2,S=3144,C=256,H=8,HD=32, mask-softmax attention with vh=kh,
// LePE 5x5 depthwise conv on v[:,8:], output projection.
// I/O: ALL float32. Internal: bf16 MFMA, f32 accum.
//
// softmax(qk + log(m+eps)) == normalize((m+eps)*exp(qk)); |qk| tiny -> fixed
// shift M=0, no online max; k-range partials additive => split-K.
//
// R11 = R10 resubmit (container infra failure, no measurement) + one defensive
// fix: __align__(16) on k_qkv_mp's LDS arrays (lds_a is accessed via 16B
// ds_read_b128/ds_write_b128; a 2B-aligned base would be UB and can fault).
//
// R10 changes vs R9 (295.8us; flash_lepe 108us; non-flash ~187us):
//  - qkv restructured: block = 16 rows x ALL 768 cols. A staged once (f32->bf16
//    in LDS), 8 A-frags in regs, 12 n-tiles with B from L2-resident w3b.
//    x read ONCE as f32 -> xb buffer + its conversion launch eliminated.
//    vfrag transpose via LDS [col][row] + cooperative 16-unit write (layout
//    identical to R9). Grid: 400 qkv + 2000 mprep fused.
//  - k_cvtw: weights only (wq/wk/wv -> w3b, wo -> wob bf16), 128 blocks.
//  - k_oproj reads wob bf16 directly (no per-block f32->bf16 re-conversion).
//  - flash_lepe / mprep / oproj structure byte-identical to R9.

#define S_LEN 3144
#define SP    3200            // S padded to 64 (50 k-tiles; 0..48 fully valid)
#define HEADS 8
#define HD    32
#define BATCH 2
#define MROWS (BATCH*S_LEN)   // 6288
#define NPIX  3136            // 56*56
#define SCALE_F 0.17677669529663687f   // 32^-0.5
#define KQ_SC   0.25504472665352026f   // SCALE_F * log2(e)

typedef __bf16 bf16x8  __attribute__((ext_vector_type(8)));
typedef __bf16 bf16x4  __attribute__((ext_vector_type(4)));
typedef float  floatx4 __attribute__((ext_vector_type(4)));
typedef short  shortx4 __attribute__((ext_vector_type(4)));
typedef _Float16 halfx4 __attribute__((ext_vector_type(4)));
typedef _Float16 halfx8 __attribute__((ext_vector_type(8)));

static __device__ __forceinline__ float bf2f(unsigned int h) {
  union { unsigned int u; float f; } v; v.u = h << 16; return v.f;
}
static __device__ __forceinline__ unsigned short f2bf(float f) {
  union { __bf16 b; unsigned short u; } v; v.b = (__bf16)f; return v.u;
}
static __device__ __forceinline__ bf16x8 ldcvt8(const float* __restrict__ p) {
  float4 a = *(const float4*)p;
  float4 b = *(const float4*)(p + 4);
  bf16x8 r;
  r[0]=(__bf16)a.x; r[1]=(__bf16)a.y; r[2]=(__bf16)a.z; r[3]=(__bf16)a.w;
  r[4]=(__bf16)b.x; r[5]=(__bf16)b.y; r[6]=(__bf16)b.z; r[7]=(__bf16)b.w;
  return r;
}

#define GLOBAL_AS __attribute__((address_space(1)))
#define LDS_AS    __attribute__((address_space(3)))
static __device__ __forceinline__ void gload_lds16(const void* g, void* l) {
  __builtin_amdgcn_global_load_lds((const GLOBAL_AS void*)g, (LDS_AS void*)l, 16, 0, 0);
}

#define FENCE4() asm volatile("s_waitcnt vmcnt(4)" ::: "memory")
#define FENCE2() asm volatile("s_waitcnt vmcnt(2)" ::: "memory")
#define FENCE0() asm volatile("s_waitcnt vmcnt(0)" ::: "memory")

// ---------------- K0: weight conversion (wq,wk,wv -> w3b; wo -> wob) ----------------
__global__ __launch_bounds__(256) void k_cvtw(
    const float* __restrict__ wq, const float* __restrict__ wk,
    const float* __restrict__ wv, const float* __restrict__ wo,
    unsigned short* __restrict__ w3b, unsigned short* __restrict__ wob)
{
  const int i = blockIdx.x * 256 + threadIdx.x;   // unit of 8 floats
  const int NW = 8192;                            // 65536/8
  if (i < 3 * NW) {
    const float* src = (i < NW) ? wq + (size_t)i * 8
                     : (i < 2 * NW) ? wk + (size_t)(i - NW) * 8
                                    : wv + (size_t)(i - 2 * NW) * 8;
    *(bf16x8*)(w3b + (size_t)i * 8) = ldcvt8(src);
  } else if (i < 4 * NW) {
    const int j = i - 3 * NW;
    *(bf16x8*)(wob + (size_t)j * 8) = ldcvt8(wo + (size_t)j * 8);
  }
}

// ---------------- L2: fused qkv (blocks 0..399) + mask relayout (400..2399) ----------------
// qkv block = (bsel, 16-row tile): stages A once, computes all 768 cols.
// mprep: pm tile block = 16x64 fp16 = 2KB laid out so LINEAR global_load_lds
// staging lands as: LDS 8B-granule d of row r = fp16(mask_row[granule d^r]+1e-6).
// Pad cols (>= S_LEN) store 0 -> P=0 downstream, no TAIL path.
__global__ __launch_bounds__(256) void k_qkv_mp(
    const float* __restrict__ x, const unsigned short* __restrict__ w3b,
    const float* __restrict__ bqp, const float* __restrict__ bkp,
    const float* __restrict__ bvp,
    unsigned short* __restrict__ qws, unsigned short* __restrict__ kws,
    unsigned short* __restrict__ vfrag, unsigned short* __restrict__ vstage,
    const float* __restrict__ mask, _Float16* __restrict__ pm)
{
  __shared__ __align__(16) unsigned short lds_a[16][264];  // A tile bf16 (+pad/row)
  __shared__ __align__(16) unsigned short lds_k[256][17];  // k*SCALE transpose [col][row]
  const int blk = blockIdx.x;

  if (blk >= 400) {
    // ---- mask relayout part (identical to R9) ----
    const int mp = blk - 400;             // 0..1999
    const int bs = mp % 400;              // b*200 + strip
    const int by = mp / 400;              // 0..4
    const int b  = bs / 200, strip = bs % 200;
    const int t  = threadIdx.x;
    const int n  = t & 127;               // 16B dest unit within tile
    const int tsel = t >> 7;              // 2 tiles per iteration
    const int row = n >> 3;               // 0..15
    const int k2  = n & 7;                // dest granule pair index
    const int g0  = (2 * k2) ^ (row & 15);
    const int gbase = g0 & ~1;            // contiguous source block of 8 floats
    const bool swp = (g0 & 1);            // odd row -> dest order swapped

    int mr = strip * 16 + row; if (mr >= S_LEN) mr = S_LEN - 1;
    const float* src = mask + ((size_t)b * S_LEN + mr) * S_LEN;
    _Float16* dst0 = pm + ((size_t)bs * 50) * 1024 + n * 8;

#pragma unroll 1
    for (int tt = 0; tt < 5; ++tt) {
      const int tile = by * 10 + tt * 2 + tsel;
      const int c0 = tile * 64 + gbase * 4;    // multiple of 8; S_LEN%8==0
      float4 a = make_float4(-1e-6f, -1e-6f, -1e-6f, -1e-6f);
      float4 c = a;
      if (c0 < S_LEN) {
        a = *(const float4*)(src + c0);
        c = *(const float4*)(src + c0 + 4);
      }
      const float4 fst = swp ? c : a;
      const float4 snd = swp ? a : c;
      halfx8 o;
      o[0] = (_Float16)(fst.x + 1e-6f); o[1] = (_Float16)(fst.y + 1e-6f);
      o[2] = (_Float16)(fst.z + 1e-6f); o[3] = (_Float16)(fst.w + 1e-6f);
      o[4] = (_Float16)(snd.x + 1e-6f); o[5] = (_Float16)(snd.y + 1e-6f);
      o[6] = (_Float16)(snd.z + 1e-6f); o[7] = (_Float16)(snd.w + 1e-6f);
      *(halfx8*)(dst0 + (size_t)tile * 1024) = o;
    }
    return;
  }

  // ---- qkv part: blk = bsel*200 + b16 (16-row tile, 0..199 in padded batch) ----
  const int bsel = blk / 200;
  const int b16  = blk % 200;
  const int srow0 = b16 * 16;                 // 0..3199 batch-local
  const int tid  = threadIdx.x;
  const int lane = tid & 63;
  const int wid  = tid >> 6;                  // 0..3
  const int c    = lane & 15, quad = lane >> 4;

  // stage A: 16 rows x 256 k, f32 -> bf16 (pad rows zero)
  {
    const int row = tid >> 4;                 // 0..15
    const int seg = tid & 15;                 // 16 f32 each
    const int s   = srow0 + row;
    if (s < S_LEN) {
      const float* xp = x + ((size_t)bsel * S_LEN + s) * 256 + seg * 16;
      *(bf16x8*)&lds_a[row][seg * 16]     = ldcvt8(xp);
      *(bf16x8*)&lds_a[row][seg * 16 + 8] = ldcvt8(xp + 8);
    } else {
      bf16x8 z = {};
      *(bf16x8*)&lds_a[row][seg * 16]     = z;
      *(bf16x8*)&lds_a[row][seg * 16 + 8] = z;
    }
  }
  __syncthreads();

  // per-wave A fragments (row=c, k=ks*32+quad*8), reused across all 12 n-tiles
  bf16x8 af[8];
#pragma unroll
  for (int ks = 0; ks < 8; ++ks)
    af[ks] = *(const bf16x8*)&lds_a[c][ks * 32 + quad * 8];

#pragma unroll 1
  for (int j = 0; j < 12; ++j) {
    const int gcol = wid * 192 + j * 16;      // 0..767
    const int wsel = gcol >> 8;
    const int col0 = gcol & 255;
    const unsigned short* bp = w3b + (size_t)(gcol + c) * 256 + quad * 8;

    floatx4 acc = (floatx4){0.f, 0.f, 0.f, 0.f};
#pragma unroll
    for (int ks = 0; ks < 8; ++ks) {
      bf16x8 bf = *(const bf16x8*)(bp + ks * 32);
      acc = __builtin_amdgcn_mfma_f32_16x16x32_bf16(af[ks], bf, acc, 0, 0, 0);
    }

    const float* bptr = (wsel == 0) ? bqp : (wsel == 1) ? bkp : bvp;
    const int col = col0 + c;
    const float bias = bptr[col];
#pragma unroll
    for (int r = 0; r < 4; ++r) {
      const int s = srow0 + quad * 4 + r;
      const int valid = (s < S_LEN);
      const float v = acc[r] + bias;
      if (wsel == 0) {
        qws[(((size_t)(bsel * HEADS + (col >> 5))) * SP + s) * HD + (col & 31)] =
            valid ? f2bf(v) : (unsigned short)0;
      } else if (wsel == 1) {
        kws[(((size_t)(bsel * HEADS + (col >> 5))) * SP + s) * HD + (col & 31)] =
            valid ? f2bf(v * KQ_SC) : (unsigned short)0;
        lds_k[col][quad * 4 + r] = valid ? f2bf(v * SCALE_F) : (unsigned short)0;
      } else {
        if (valid) vstage[(size_t)(bsel * S_LEN + s) * 256 + col] = f2bf(v);
      }
    }
  }
  __syncthreads();

  // vfrag: 16 units (h, half) x 64 lanes; unit lane l holds
  // Kscaled[srow0 + (l>>4)*4 + e][h*32 + half*16 + (l&15)]  (same layout as R9:
  // srow0 = b16*16 = stile*64 + ct2*16)
  const int stile = b16 >> 2, ct2 = b16 & 3;
#pragma unroll
  for (int jj = 0; jj < 4; ++jj) {
    const int u = (tid >> 6) + jj * 4;        // 0..15, wave-uniform
    const int h = u >> 1, half = u & 1;
    const int l = tid & 63;
    union { shortx4 s4; unsigned short us[4]; } pk;
#pragma unroll
    for (int e = 0; e < 4; ++e)
      pk.us[e] = lds_k[h * 32 + half * 16 + (l & 15)][(l >> 4) * 4 + e];
    const size_t off =
        ((((size_t)(bsel * HEADS + h) * 50 + stile) * 4 + ct2) * 2 + half) * 64 + l;
    *(shortx4*)(vfrag + off * 4) = pk.s4;
  }
}

// ---------------- LePE device body (5x5 depthwise conv on v[:,8:]) ----------------
static __device__ void lepe_block(int idx,
                                  const unsigned short* __restrict__ vws,
                                  const float* __restrict__ cw,
                                  const float* __restrict__ cb,
                                  unsigned short* __restrict__ lepe)
{
  if (idx >= BATCH * NPIX * 32) return;
  const int cg = idx & 31;
  const int p  = (idx >> 5) % NPIX;
  const int b  = idx / (NPIX * 32);
  const int y  = p / 56, xx = p - y * 56;

  float acc[8];
  {
    float4 b0 = *(const float4*)(cb + cg * 8);
    float4 b1 = *(const float4*)(cb + cg * 8 + 4);
    acc[0]=b0.x; acc[1]=b0.y; acc[2]=b0.z; acc[3]=b0.w;
    acc[4]=b1.x; acc[5]=b1.y; acc[6]=b1.z; acc[7]=b1.w;
  }
#pragma unroll
  for (int dy = -2; dy <= 2; ++dy) {
    const int yy = y + dy;
    if ((unsigned)yy >= 56u) continue;
#pragma unroll
    for (int dx = -2; dx <= 2; ++dx) {
      const int xs = xx + dx;
      if ((unsigned)xs >= 56u) continue;
      uint4 vv = *(const uint4*)(vws + (size_t)(b * S_LEN + 8 + yy * 56 + xs) * 256 + cg * 8);
      const float* wp = cw + (size_t)((dy + 2) * 5 + (dx + 2)) * 256 + cg * 8;
      float4 w0 = *(const float4*)wp;
      float4 w1 = *(const float4*)(wp + 4);
      unsigned int va[4] = {vv.x, vv.y, vv.z, vv.w};
      acc[0] += bf2f(va[0] & 0xFFFFu) * w0.x;  acc[1] += bf2f(va[0] >> 16) * w0.y;
      acc[2] += bf2f(va[1] & 0xFFFFu) * w0.z;  acc[3] += bf2f(va[1] >> 16) * w0.w;
      acc[4] += bf2f(va[2] & 0xFFFFu) * w1.x;  acc[5] += bf2f(va[2] >> 16) * w1.y;
      acc[6] += bf2f(va[3] & 0xFFFFu) * w1.z;  acc[7] += bf2f(va[3] >> 16) * w1.w;
    }
  }
  unsigned int o[4];
#pragma unroll
  for (int j = 0; j < 4; ++j)
    o[j] = (unsigned int)f2bf(acc[2*j]) | ((unsigned int)f2bf(acc[2*j+1]) << 16);
  *((uint4*)(lepe + (size_t)(b * NPIX + p) * 256 + cg * 8)) = make_uint4(o[0], o[1], o[2], o[3]);
}

// ============ flash tile machinery (fp16 relayouted mask, R8-proven) ============
static __device__ __forceinline__ void proc_tile_pre(
    int t, const unsigned short* __restrict__ kb,
    const unsigned short* __restrict__ vb,
    const _Float16* __restrict__ mb,
    int c, int quad, int lane, const bf16x8 qf,
    floatx4& o0, floatx4& o1, float& l_run)
{
  const int k0 = t * 64;
  bf16x8 kf[4]; shortx4 v0[4], v1[4];
  const unsigned short* tb = vb + (size_t)t * 2048;
#pragma unroll
  for (int ct = 0; ct < 4; ++ct) {
    kf[ct] = *(const bf16x8*)(kb + (size_t)(k0 + ct * 16 + c) * HD + quad * 8);
    v0[ct] = *(const shortx4*)(tb + (ct * 2 + 0) * 256 + lane * 4);
    v1[ct] = *(const shortx4*)(tb + (ct * 2 + 1) * 256 + lane * 4);
  }
  floatx4 s[4];
#pragma unroll
  for (int ct = 0; ct < 4; ++ct)
    s[ct] = __builtin_amdgcn_mfma_f32_16x16x32_bf16(kf[ct], qf,
               (floatx4){0.f,0.f,0.f,0.f}, 0, 0, 0);
  float ls = 0.f;
  shortx4 pf[4];
#pragma unroll
  for (int ct = 0; ct < 4; ++ct) {
    // LDS 8B-granule d of row c holds source granule d^c -> read d=(ct*4+quad)^c
    const halfx4 mv = *(const halfx4*)(mb + c * 64 + (((ct * 4 + quad) ^ c) * 4));
    float pr[4];
    pr[0] = (float)mv[0] * __builtin_amdgcn_exp2f(s[ct][0]);
    pr[1] = (float)mv[1] * __builtin_amdgcn_exp2f(s[ct][1]);
    pr[2] = (float)mv[2] * __builtin_amdgcn_exp2f(s[ct][2]);
    pr[3] = (float)mv[3] * __builtin_amdgcn_exp2f(s[ct][3]);
    ls += (pr[0] + pr[1]) + (pr[2] + pr[3]);
    union { bf16x4 b4; shortx4 s4; } u;
    u.b4[0]=(__bf16)pr[0]; u.b4[1]=(__bf16)pr[1]; u.b4[2]=(__bf16)pr[2]; u.b4[3]=(__bf16)pr[3];
    pf[ct] = u.s4;
  }
  l_run += ls;
#pragma unroll
  for (int ct = 0; ct < 4; ++ct) {
    o0 = __builtin_amdgcn_mfma_f32_16x16x16bf16_1k(v0[ct], pf[ct], o0, 0, 0, 0);
    o1 = __builtin_amdgcn_mfma_f32_16x16x16bf16_1k(v1[ct], pf[ct], o1, 0, 0, 0);
  }
}

static __device__ __forceinline__ void stage_pre(
    const _Float16* __restrict__ mp_t, int lane, _Float16* dst)
{
#pragma unroll
  for (int i = 0; i < 2; ++i)   // 2 x (64 lanes x 16B) = 2KB tile, contiguous
    gload_lds16(mp_t + i * 512 + lane * 8, dst + i * 512);
}

// ---------------- L3: fused flash (blocks 0..3199) + lepe (3200..3983) ----------------
// flash writes o*rl as F32 to atbf (no lepe read here).
__global__ __launch_bounds__(256) void k_flash_lepe(
    const unsigned short* __restrict__ qws,
    const unsigned short* __restrict__ kws,
    const unsigned short* __restrict__ vfrag,
    const _Float16* __restrict__ pmask,
    const unsigned short* __restrict__ vws,
    const float* __restrict__ cw, const float* __restrict__ cb,
    unsigned short* __restrict__ lepe_out,
    float* __restrict__ atbf)
{
  __shared__ __align__(16) float smem[4][1024];
  if (blockIdx.x >= 3200) {
    lepe_block((blockIdx.x - 3200) * 256 + threadIdx.x, vws, cw, cb, lepe_out);
    return;
  }
  const int lane = threadIdx.x & 63;
  const int wid  = threadIdx.x >> 6;          // 0..3
  const int c    = lane & 15, quad = lane >> 4;
  const int u    = blockIdx.x;               // 0..3199
  const int xcd  = u & 7;
  const int slot = u >> 3;                   // 0..399
  const int h    = slot & 7;
  const int p    = (slot >> 3) * 8 + xcd;    // 0..399 = b*200 + strip
  const int b    = p / 200;
  const int strip = p - b * 200;
  const int qrow = strip * 16 + c;
  const size_t bh = (size_t)(b * HEADS + h);

  const bf16x8 qf = *(const bf16x8*)(qws + (bh * SP + qrow) * HD + quad * 8);
  const unsigned short* kb = kws + bh * SP * HD;
  const unsigned short* vb = vfrag + bh * (size_t)(50 * 2048);
  const _Float16* mpb = pmask + (size_t)(b * 200 + strip) * (50 * 1024);
  _Float16* mt = (_Float16*)&smem[wid][0];

  float l_run = 0.f;
  floatx4 o0 = (floatx4){0.f,0.f,0.f,0.f};
  floatx4 o1 = (floatx4){0.f,0.f,0.f,0.f};

  // tiles: wave w -> t = w*12 .. w*12+11; leftovers 48 -> wave0, 49 -> wave1
  // (tile 49's pad cols carry hm=0 -> P=0, normal tile).
  const int tbase = wid * 12;
  const int nt = (wid < 2) ? 13 : 12;

  stage_pre(mpb + tbase * 1024, lane, mt);    // prologue -> buf0

  for (int it = 0; it < nt; ++it) {
    const int t = (it < 12) ? tbase + it : 48 + wid;
    if (it + 1 < nt) {
      const int tn = (it + 1 < 12) ? tbase + it + 1 : 48 + wid;
      stage_pre(mpb + tn * 1024, lane, mt + ((it + 1) & 1) * 1024);
      FENCE2();   // retire THIS tile's 2 staging loads; keep next 2 in flight
    } else {
      FENCE0();
    }
    proc_tile_pre(t, kb, vb, mt + (it & 1) * 1024, c, quad, lane, qf, o0, o1, l_run);
  }

  // ---- cross-wave reduction (smem reused: each wave writes only its region) ----
#pragma unroll
  for (int r = 0; r < 4; ++r) {
    smem[wid][lane * 9 + r]     = o0[r];
    smem[wid][lane * 9 + 4 + r] = o1[r];
  }
  smem[wid][lane * 9 + 8] = l_run;
  __syncthreads();

  if (wid == 0) {
#pragma unroll
    for (int w = 1; w < 4; ++w) {
#pragma unroll
      for (int r = 0; r < 4; ++r) {
        o0[r] += smem[w][lane * 9 + r];
        o1[r] += smem[w][lane * 9 + 4 + r];
      }
      l_run += smem[w][lane * 9 + 8];
    }
    l_run += __shfl_xor(l_run, 16);
    l_run += __shfl_xor(l_run, 32);
    const float rl = 1.f / l_run;

    if (qrow < S_LEN) {
      float* op = atbf + ((size_t)b * S_LEN + qrow) * 256 + h * 32;
      float4 s0 = make_float4(o0[0]*rl, o0[1]*rl, o0[2]*rl, o0[3]*rl);
      float4 s1 = make_float4(o1[0]*rl, o1[1]*rl, o1[2]*rl, o1[3]*rl);
      *(float4*)(op + quad * 4)      = s0;
      *(float4*)(op + 16 + quad * 4) = s1;
    }
  }
}

// ---------------- L4: output projection (atb f32 + lepe bf16, wob bf16 -> f32 out) ----------------
// Grid (99, 8): 32-col blocks. af = bf16(atb_f32 + bf2f(lepe)) -- rounded to
// bf16 exactly once, bit-identical to R9's path.
__global__ __launch_bounds__(256) void k_oproj(
    const float* __restrict__ atbf,
    const unsigned short* __restrict__ lepe,
    const unsigned short* __restrict__ wob,
    const float* __restrict__ bop,
    float* __restrict__ out)
{
  const int lane = threadIdx.x & 63;
  const int wid  = threadIdx.x >> 6;
  const int c = lane & 15, quad = lane >> 4;
  const int row0 = blockIdx.x * 64 + wid * 16;
  const int col0 = blockIdx.y * 32;

  int arow = row0 + c; if (arow >= MROWS) arow = 0;
  const int bb = (arow >= S_LEN) ? 1 : 0;
  const int sr = arow - bb * S_LEN;
  const bool hasl = (sr >= 8);
  const float* ap = atbf + (size_t)arow * 256 + quad * 8;
  const unsigned short* lp =
      lepe + (hasl ? (((size_t)bb * NPIX + (sr - 8)) * 256 + quad * 8) : 0);
  const unsigned short* bp = wob + (size_t)(col0 + c) * 256 + quad * 8;

  floatx4 acc[2];
#pragma unroll
  for (int ct = 0; ct < 2; ++ct) acc[ct] = (floatx4){0.f,0.f,0.f,0.f};
#pragma unroll
  for (int ks = 0; ks < 8; ++ks) {
    float4 a0 = *(const float4*)(ap + ks * 32);
    float4 a1 = *(const float4*)(ap + ks * 32 + 4);
    if (hasl) {
      uint4 lv = *(const uint4*)(lp + ks * 32);
      a0.x += bf2f(lv.x & 0xFFFFu); a0.y += bf2f(lv.x >> 16);
      a0.z += bf2f(lv.y & 0xFFFFu); a0.w += bf2f(lv.y >> 16);
      a1.x += bf2f(lv.z & 0xFFFFu); a1.y += bf2f(lv.z >> 16);
      a1.z += bf2f(lv.w & 0xFFFFu); a1.w += bf2f(lv.w >> 16);
    }
    bf16x8 af;
    af[0]=(__bf16)a0.x; af[1]=(__bf16)a0.y; af[2]=(__bf16)a0.z; af[3]=(__bf16)a0.w;
    af[4]=(__bf16)a1.x; af[5]=(__bf16)a1.y; af[6]=(__bf16)a1.z; af[7]=(__bf16)a1.w;
#pragma unroll
    for (int ct = 0; ct < 2; ++ct) {
      bf16x8 bf = *(const bf16x8*)(bp + (size_t)ct * 16 * 256 + ks * 32);
      acc[ct] = __builtin_amdgcn_mfma_f32_16x16x32_bf16(af, bf, acc[ct], 0, 0, 0);
    }
  }
#pragma unroll
  for (int ct = 0; ct < 2; ++ct) {
    const int col = col0 + ct * 16 + c;
    const float bias = bop[col];
#pragma unroll
    for (int r = 0; r < 4; ++r) {
      const int row = row0 + quad * 4 + r;
      if (row >= MROWS) continue;
      out[(size_t)row * 256 + col] = acc[ct][r] + bias;
    }
  }
}

// ============ fallback flash (raw mask) + standalone lepe (ws too small) ============
__global__ __launch_bounds__(256) void k_lepe_sa(const unsigned short* __restrict__ vws,
                                                 const float* __restrict__ cw,
                                                 const float* __restrict__ cb,
                                                 unsigned short* __restrict__ lepe)
{
  lepe_block(blockIdx.x * 256 + threadIdx.x, vws, cw, cb, lepe);
}

template<bool TAIL>
static __device__ __forceinline__ void proc_tile_fb(
    int t, const unsigned short* __restrict__ kb,
    const unsigned short* __restrict__ vb,
    const float* __restrict__ mb,
    int c, int quad, int lane, const bf16x8 qf,
    floatx4& o0, floatx4& o1, float& l_run)
{
  const int k0 = t * 64;
  bf16x8 kf[4]; shortx4 v0[4], v1[4];
  const unsigned short* tb = vb + (size_t)t * 2048;
#pragma unroll
  for (int ct = 0; ct < 4; ++ct) {
    kf[ct] = *(const bf16x8*)(kb + (size_t)(k0 + ct * 16 + c) * HD + quad * 8);
    v0[ct] = *(const shortx4*)(tb + (ct * 2 + 0) * 256 + lane * 4);
    v1[ct] = *(const shortx4*)(tb + (ct * 2 + 1) * 256 + lane * 4);
  }
  floatx4 s[4];
#pragma unroll
  for (int ct = 0; ct < 4; ++ct)
    s[ct] = __builtin_amdgcn_mfma_f32_16x16x32_bf16(kf[ct], qf,
               (floatx4){0.f,0.f,0.f,0.f}, 0, 0, 0);
  float ls = 0.f;
  shortx4 pf[4];
#pragma unroll
  for (int ct = 0; ct < 4; ++ct) {
    const float4 mv = *(const float4*)(mb + c * 64 + (((ct * 4 + quad) ^ c) * 4));
    float pr[4];
    pr[0] = (mv.x + 1e-6f) * __builtin_amdgcn_exp2f(s[ct][0]);
    pr[1] = (mv.y + 1e-6f) * __builtin_amdgcn_exp2f(s[ct][1]);
    pr[2] = (mv.z + 1e-6f) * __builtin_amdgcn_exp2f(s[ct][2]);
    pr[3] = (mv.w + 1e-6f) * __builtin_amdgcn_exp2f(s[ct][3]);
    if (TAIL) {
      const int kk = k0 + ct * 16 + quad * 4;
#pragma unroll
      for (int r = 0; r < 4; ++r) if (kk + r >= S_LEN) pr[r] = 0.f;
    }
    ls += (pr[0] + pr[1]) + (pr[2] + pr[3]);
    union { bf16x4 b4; shortx4 s4; } u;
    u.b4[0]=(__bf16)pr[0]; u.b4[1]=(__bf16)pr[1]; u.b4[2]=(__bf16)pr[2]; u.b4[3]=(__bf16)pr[3];
    pf[ct] = u.s4;
  }
  l_run += ls;
#pragma unroll
  for (int ct = 0; ct < 4; ++ct) {
    o0 = __builtin_amdgcn_mfma_f32_16x16x16bf16_1k(v0[ct], pf[ct], o0, 0, 0, 0);
    o1 = __builtin_amdgcn_mfma_f32_16x16x16bf16_1k(v1[ct], pf[ct], o1, 0, 0, 0);
  }
}

static __device__ __forceinline__ void stage_mask_fb(
    const float* const (&msrc)[4], const int (&goff4)[4], int k0, float* dst)
{
#pragma unroll
  for (int i = 0; i < 4; ++i)
    gload_lds16(msrc[i] + (k0 + goff4[i]), dst + i * 256);
}

static __device__ __forceinline__ void stage_mask_tail_fb(
    const float* const (&msrc)[4], const int (&goff4)[4], int k0, float* dst)
{
#pragma unroll
  for (int i = 0; i < 4; ++i) {
    int kk = k0 + goff4[i];
    if (kk > S_LEN - 4) kk = S_LEN - 4;
    gload_lds16(msrc[i] + kk, dst + i * 256);
  }
}

__global__ __launch_bounds__(512) void k_flash_fb(
    const unsigned short* __restrict__ qws,
    const unsigned short* __restrict__ kws,
    const unsigned short* __restrict__ vfrag,
    const float* __restrict__ mask,
    float* __restrict__ atbf)
{
  __shared__ __align__(16) float smem[8][2048];
  const int lane = threadIdx.x & 63;
  const int wid  = threadIdx.x >> 6;
  const int c    = lane & 15, quad = lane >> 4;
  const int u    = blockIdx.x;
  const int xcd  = u & 7;
  const int slot = u >> 3;
  const int h    = slot & 7;
  const int p    = (slot >> 3) * 8 + xcd;
  const int b    = p / 200;
  const int strip = p - b * 200;
  const int qrow = strip * 16 + c;
  const size_t bh = (size_t)(b * HEADS + h);

  const bf16x8 qf = *(const bf16x8*)(qws + (bh * SP + qrow) * HD + quad * 8);
  const unsigned short* kb = kws + bh * SP * HD;
  const unsigned short* vb = vfrag + bh * (size_t)(50 * 2048);
  float* mt = &smem[wid][0];

  const float* msrc[4];
  int goff4[4];
#pragma unroll
  for (int i = 0; i < 4; ++i) {
    const int rq = i * 4 + (lane >> 4);
    int mr = strip * 16 + rq; if (mr >= S_LEN) mr = S_LEN - 1;
    msrc[i] = mask + ((size_t)b * S_LEN + mr) * S_LEN;
    goff4[i] = ((lane & 15) ^ rq) * 4;
  }

  float l_run = 0.f;
  floatx4 o0 = (floatx4){0.f,0.f,0.f,0.f};
  floatx4 o1 = (floatx4){0.f,0.f,0.f,0.f};

  const int tbase = wid * 6;
  const int nt = (wid < 2) ? 7 : 6;

  stage_mask_fb(msrc, goff4, tbase * 64, mt);

  for (int it = 0; it < nt; ++it) {
    const int t = (it < 6) ? tbase + it : 48 + wid;
    if (it + 1 < nt) {
      const int tn = (it + 1 < 6) ? tbase + it + 1 : 48 + wid;
      float* dst = mt + ((it + 1) & 1) * 1024;
      if (tn == 49) stage_mask_tail_fb(msrc, goff4, 49 * 64, dst);
      else          stage_mask_fb(msrc, goff4, tn * 64, dst);
      FENCE4();
    } else {
      FENCE0();
    }
    const float* mb = mt + (it & 1) * 1024;
    if (wid == 1 && it == 6)
      proc_tile_fb<true >(t, kb, vb, mb, c, quad, lane, qf, o0, o1, l_run);
    else
      proc_tile_fb<false>(t, kb, vb, mb, c, quad, lane, qf, o0, o1, l_run);
  }

#pragma unroll
  for (int r = 0; r < 4; ++r) {
    smem[wid][lane * 9 + r]     = o0[r];
    smem[wid][lane * 9 + 4 + r] = o1[r];
  }
  smem[wid][lane * 9 + 8] = l_run;
  __syncthreads();

  if (wid == 0) {
#pragma unroll
    for (int w = 1; w < 8; ++w) {
#pragma unroll
      for (int r = 0; r < 4; ++r) {
        o0[r] += smem[w][lane * 9 + r];
        o1[r] += smem[w][lane * 9 + 4 + r];
      }
      l_run += smem[w][lane * 9 + 8];
    }
    l_run += __shfl_xor(l_run, 16);
    l_run += __shfl_xor(l_run, 32);
    const float rl = 1.f / l_run;

    if (qrow < S_LEN) {
      float* op = atbf + ((size_t)b * S_LEN + qrow) * 256 + h * 32;
      float4 s0 = make_float4(o0[0]*rl, o0[1]*rl, o0[2]*rl, o0[3]*rl);
      float4 s1 = make_float4(o1[0]*rl, o1[1]*rl, o1[2]*rl, o1[3]*rl);
      *(float4*)(op + quad * 4)      = s0;
      *(float4*)(op + 16 + quad * 4) = s1;
    }
  }
}

// ---------------- workspace layout (bytes) ----------------
#define QW_OFF 0u                        // 2*8*3200*32*2 = 3,276,800
#define KW_OFF 3276800u
#define VF_OFF 6553600u                  // vfrag, 3,276,800
#define LE_OFF 9830400u                  // lpe 3,211,264
#define AT_OFF 13041664u                 // atb F32: 6288*256*4 = 6,438,912
#define WB_OFF 19480576u                 // w3b bf16: 3*65536*2 = 393,216
#define WO_OFF 19873792u                 // wob bf16: 65536*2 = 131,072
#define PM_OFF 20004864u                 // relayouted fp16 mask: 40,960,000
#define PM_NEED (20004864u + 40960000u)  // 60,964,864 (ws >= 98MB proven in R6)

extern "C" void kernel_launch(void* const* d_in, const int* in_sizes, int n_in,
                              void* d_out, int out_size, void* d_ws, size_t ws_size,
                              hipStream_t stream) {
  const float* x    = (const float*)d_in[0];
  const float* mask = (const float*)d_in[1];
  const float* wq   = (const float*)d_in[2];
  const float* bq   = (const float*)d_in[3];
  const float* wk   = (const float*)d_in[4];
  const float* bk   = (const float*)d_in[5];
  const float* wv   = (const float*)d_in[6];
  const float* bv   = (const float*)d_in[7];
  const float* lw   = (const float*)d_in[8];
  const float* lb   = (const float*)d_in[9];
  const float* wo   = (const float*)d_in[10];
  const float* bo   = (const float*)d_in[11];

  char* ws = (char*)d_ws;
  unsigned short* qws = (unsigned short*)(ws + QW_OFF);
  unsigned short* kws = (unsigned short*)(ws + KW_OFF);
  unsigned short* vfr = (unsigned short*)(ws + VF_OFF);
  unsigned short* lpe = (unsigned short*)(ws + LE_OFF);
  float*          atf = (float*)(ws + AT_OFF);
  unsigned short* w3b = (unsigned short*)(ws + WB_OFF);
  unsigned short* wob = (unsigned short*)(ws + WO_OFF);
  unsigned short* vst = (unsigned short*)d_out;             // low 3.22MB of d_out
  float*          outf = (float*)d_out;

  const bool use_pre = (ws_size >= (size_t)PM_NEED);

  k_cvtw<<<128, 256, 0, stream>>>(wq, wk, wv, wo, w3b, wob);
  if (use_pre) {
    _Float16* pm = (_Float16*)(ws + PM_OFF);
    k_qkv_mp<<<2400, 256, 0, stream>>>(x, w3b, bq, bk, bv, qws, kws, vfr, vst, mask, pm);
    k_flash_lepe<<<3984, 256, 0, stream>>>(qws, kws, vfr, pm, vst, lw, lb, lpe, atf);
  } else {
    k_qkv_mp<<<400, 256, 0, stream>>>(x, w3b, bq, bk, bv, qws, kws, vfr, vst,
                                      mask, (_Float16*)nullptr);
    k_lepe_sa<<<784, 256, 0, stream>>>(vst, lw, lb, lpe);
    k_flash_fb<<<3200, 512, 0, stream>>>(qws, kws, vfr, mask, atf);
  }
  k_oproj<<<dim3(99, 8), 256, 0, stream>>>(atf, lpe, wob, bo, outf);
}